// Round 1
// baseline (1488.130 us; speedup 1.0000x reference)
//
#include <hip/hip_runtime.h>
#include <hip/hip_bf16.h>

typedef __attribute__((ext_vector_type(8))) short short8;
typedef __attribute__((ext_vector_type(4))) float f32x4;

#define BSZ 4
#define LSEQ 1024
#define CCH 512
#define BL (BSZ*LSEQ)   // 4096 rows
#define DI 1024         // d_inner
#define NST 16
#define DTR 32

__device__ __forceinline__ float sigmoidf_(float x){ return 1.f/(1.f+__expf(-x)); }
__device__ __forceinline__ float softplus_(float x){ return x > 20.f ? x : log1pf(__expf(x)); }

// ---------------- prep / elementwise kernels ----------------

__global__ void k_cast_b(const float* __restrict__ s, __hip_bfloat16* __restrict__ d, int n){
  int i = blockIdx.x*256 + threadIdx.x;
  if (i < n) d[i] = __float2bfloat16(s[i]);
}

// conv_w [3][512][512][5] -> wt [3][512][2560], j = k*512 + ci  (matches contiguous patch)
__global__ void k_prep_convw(const float* __restrict__ cw, __hip_bfloat16* __restrict__ wt){
  int i = blockIdx.x*256 + threadIdx.x;
  const int total = 3*CCH*CCH*5;
  if (i >= total) return;
  int j = i % (CCH*5);
  int co = (i/(CCH*5)) % CCH;
  int layer = i/(CCH*5*CCH);
  int k = j >> 9, ci = j & 511;
  wt[i] = __float2bfloat16(cw[(((size_t)layer*CCH + co)*CCH + ci)*5 + k]);
}

// gather emb[x] into padded [B][L+4][C] bf16 (2 zero rows each side for K=5 conv)
__global__ void k_embed(const int* __restrict__ x, const float* __restrict__ emb,
                        __hip_bfloat16* __restrict__ xpad){
  int i = blockIdx.x*256 + threadIdx.x;
  const int total = BSZ*(LSEQ+4)*CCH;
  if (i >= total) return;
  int c = i & (CCH-1);
  int r = (i >> 9) % (LSEQ+4);
  int b = i / ((LSEQ+4)*CCH);
  float v = 0.f;
  if (r >= 2 && r < LSEQ+2){
    int tok = x[b*LSEQ + (r-2)];
    v = emb[(size_t)tok*CCH + c];
  }
  xpad[i] = __float2bfloat16(v);
}

// zero the 4 pad rows of a padded activation buffer (per batch)
__global__ void k_zero_pads(__hip_bfloat16* __restrict__ xpad){
  int i = blockIdx.x*256 + threadIdx.x;
  const int total = BSZ*4*CCH;
  if (i >= total) return;
  int c = i & (CCH-1);
  int pr = (i >> 9) & 3;
  int b = i >> 11;
  int r = (pr < 2) ? pr : (LSEQ+2) + (pr-2);
  xpad[((size_t)b*(LSEQ+4) + r)*CCH + c] = __float2bfloat16(0.f);
}

// per-(b,l) channel LayerNorm + scale/shift + LeakyReLU(0.2) + mask
// writes bf16 into next padded buffer (rows +2) and/or h_enc / h_rev (reversed per batch)
__global__ __launch_bounds__(256) void k_ln(
    const float* __restrict__ in, const float* __restrict__ g, const float* __restrict__ bb,
    const unsigned char* __restrict__ mask,
    __hip_bfloat16* __restrict__ xpad_next,
    __hip_bfloat16* __restrict__ h_enc, __hip_bfloat16* __restrict__ h_rev){
  int row = blockIdx.x;                 // b*1024 + l
  int b = row >> 10, l = row & 1023;
  const float* xr = in + (size_t)row*CCH;
  int t = threadIdx.x;
  float v0 = xr[t], v1 = xr[t+256];
  float s = v0+v1, s2 = v0*v0 + v1*v1;
  #pragma unroll
  for (int off=32; off>0; off>>=1){ s += __shfl_down(s,off); s2 += __shfl_down(s2,off); }
  __shared__ float ls[8];
  if ((t&63)==0){ ls[t>>6] = s; ls[(t>>6)+4] = s2; }
  __syncthreads();
  float S  = ls[0]+ls[1]+ls[2]+ls[3];
  float S2 = ls[4]+ls[5]+ls[6]+ls[7];
  float mu = S*(1.f/CCH);
  float var = S2*(1.f/CCH) - mu*mu;
  float rs = rsqrtf(var + 1e-5f);
  bool mk = mask[row] != 0;
  #pragma unroll
  for (int e=0; e<2; e++){
    int c = t + e*256;
    float v = e ? v1 : v0;
    float h = (v-mu)*rs*g[c] + bb[c];
    h = h > 0.f ? h : 0.2f*h;
    if (mk) h = 0.f;
    __hip_bfloat16 hb = __float2bfloat16(h);
    if (xpad_next) xpad_next[((size_t)b*(LSEQ+4) + (l+2))*CCH + c] = hb;
    if (h_enc) h_enc[(size_t)row*CCH + c] = hb;
    if (h_rev) h_rev[((size_t)(b<<10) + (1023-l))*CCH + c] = hb;
  }
}

// ---------------- MFMA wave-GEMM: C[m][n] = sum_k A[m][k]*W[n][k] (+bias, act, mask) ------
// 1 wave per block, 64x64 output tile, 16x16x32 bf16 MFMA, direct global loads.
// A row m maps to physical row m + padExtra*(m>>10)  (conv padded-buffer mode).
template<bool OUTBF>
__global__ __launch_bounds__(64) void k_gemm(
    const __hip_bfloat16* __restrict__ A, int lda, int padExtra,
    const __hip_bfloat16* __restrict__ W, void* __restrict__ Cout,
    int ldc, int coloff, int N, int K,
    const float* __restrict__ bias, int act,
    const unsigned char* __restrict__ mask){
  int tiles_n = N >> 6;
  int tn = blockIdx.x % tiles_n;
  int tm = blockIdx.x / tiles_n;
  int m0 = tm << 6, n0 = tn << 6;
  int lane = threadIdx.x;
  int r = lane & 15, kg = lane >> 4;

  const short* Ap[4];
  const short* Wp[4];
  #pragma unroll
  for (int mi=0; mi<4; mi++){
    int row = m0 + mi*16 + r;
    int phys = row + padExtra*(row >> 10);
    Ap[mi] = (const short*)A + (size_t)phys*lda + kg*8;
  }
  #pragma unroll
  for (int nj=0; nj<4; nj++){
    int col = n0 + nj*16 + r;
    Wp[nj] = (const short*)W + (size_t)col*K + kg*8;
  }
  f32x4 acc[4][4];
  #pragma unroll
  for (int mi=0;mi<4;mi++)
    #pragma unroll
    for (int nj=0;nj<4;nj++) acc[mi][nj] = (f32x4){0.f,0.f,0.f,0.f};

  for (int kk=0; kk<K; kk+=32){
    short8 a[4], w[4];
    #pragma unroll
    for (int mi=0;mi<4;mi++) a[mi] = *(const short8*)(Ap[mi] + kk);
    #pragma unroll
    for (int nj=0;nj<4;nj++) w[nj] = *(const short8*)(Wp[nj] + kk);
    #pragma unroll
    for (int mi=0;mi<4;mi++)
      #pragma unroll
      for (int nj=0;nj<4;nj++)
        acc[mi][nj] = __builtin_amdgcn_mfma_f32_16x16x32_bf16(a[mi], w[nj], acc[mi][nj], 0,0,0);
  }
  #pragma unroll
  for (int mi=0;mi<4;mi++){
    #pragma unroll
    for (int nj=0;nj<4;nj++){
      #pragma unroll
      for (int reg=0; reg<4; reg++){
        int row = m0 + mi*16 + kg*4 + reg;
        int col = n0 + nj*16 + r;
        float v = acc[mi][nj][reg];
        if (bias) v += bias[col];
        if (act == 1) v = softplus_(v);
        if (mask && mask[row]) v = 0.f;
        size_t o = (size_t)row*ldc + coloff + col;
        if (OUTBF) ((__hip_bfloat16*)Cout)[o] = __float2bfloat16(v);
        else       ((float*)Cout)[o] = v;
      }
    }
  }
}

// ---------------- mamba pieces ----------------

// causal depthwise conv (d_conv=4) + bias + silu; u from xz cols [0,1024)
__global__ void k_dwconv(const float* __restrict__ xz, const float* __restrict__ cw,
                         const float* __restrict__ cb, float* __restrict__ u,
                         __hip_bfloat16* __restrict__ ub){
  int i = blockIdx.x*256 + threadIdx.x;
  if (i >= BL*DI) return;
  int d = i & (DI-1);
  int row = i >> 10;
  int l = row & 1023;
  int rb = row & ~1023;
  float acc = cb[d];
  #pragma unroll
  for (int k=0;k<4;k++){
    int ll = l - 3 + k;
    if (ll >= 0) acc += cw[d*4 + k] * xz[(size_t)(rb + ll)*(2*DI) + d];
  }
  float s = acc * sigmoidf_(acc);
  u[i] = s;
  ub[i] = __float2bfloat16(s);
}

// extract dt (cols [0,32) of xdbc) as bf16 for dt_proj GEMM
__global__ void k_dtcast(const float* __restrict__ xdbc, __hip_bfloat16* __restrict__ dtb){
  int i = blockIdx.x*256 + threadIdx.x;
  if (i >= BL*DTR) return;
  int row = i >> 5, j = i & 31;
  dtb[i] = __float2bfloat16(xdbc[(size_t)row*64 + j]);
}

// selective scan: 16 lanes per (b,d) row, one lane per state n.
// dy holds delta on input; y is written in place (safe: each element touched
// only by its own row at its own step, read-before-write in program order).
__global__ __launch_bounds__(256) void k_scan(
    const float* __restrict__ A_log, float* __restrict__ dy,
    const float* __restrict__ u, const float* __restrict__ xdbc){
  int t = threadIdx.x;
  int n = t & 15;
  int row = blockIdx.x*16 + (t>>4);   // (b,d) row, 0..4095
  int b = row >> 10, d = row & 1023;
  float Af = -__expf(A_log[d*NST + n]);
  float h = 0.f;
  const size_t rowbase = (size_t)b*1024;
  for (int l=0; l<1024; l++){
    size_t bl = rowbase + l;
    float dv = dy[bl*DI + d];
    float uv = u[bl*DI + d];
    float Bv = xdbc[bl*64 + 32 + n];
    float Cv = xdbc[bl*64 + 48 + n];
    float dA = __expf(dv * Af);
    h = __fmaf_rn(dA, h, dv*Bv*uv);
    float p = h * Cv;
    p += __shfl_xor(p, 1);
    p += __shfl_xor(p, 2);
    p += __shfl_xor(p, 4);
    p += __shfl_xor(p, 8);
    if (n == 0) dy[bl*DI + d] = p;
  }
}

// y_final = (y + u*D) * silu(z), bf16 out for out_proj
__global__ void k_ygate(const float* __restrict__ y, const float* __restrict__ u,
                        const float* __restrict__ xz, const float* __restrict__ Dp,
                        __hip_bfloat16* __restrict__ yb){
  int i = blockIdx.x*256 + threadIdx.x;
  if (i >= BL*DI) return;
  int d = i & (DI-1);
  size_t row = (size_t)(i >> 10);
  float z = xz[row*(2*DI) + DI + d];
  float v = (y[i] + u[i]*Dp[d]) * (z * sigmoidf_(z));
  yb[i] = __float2bfloat16(v);
}

// ---------------- host ----------------

extern "C" void kernel_launch(void* const* d_in, const int* in_sizes, int n_in,
                              void* d_out, int out_size, void* d_ws, size_t ws_size,
                              hipStream_t stream){
  (void)in_sizes; (void)n_in; (void)out_size; (void)ws_size;
  const int*   x     = (const int*)d_in[0];
  const unsigned char* m = (const unsigned char*)d_in[2];   // bool mask [B][L]
  const float* emb   = (const float*)d_in[3];
  const float* convw = (const float*)d_in[4];
  const float* convb = (const float*)d_in[5];
  const float* lng   = (const float*)d_in[6];
  const float* lnb   = (const float*)d_in[7];
  const float* projw = (const float*)d_in[8];
  const float* projb = (const float*)d_in[9];

  char* ws = (char*)d_ws;
  size_t off = 0;
  auto alloc = [&](size_t bytes)->char*{
    char* p = ws + off; off += (bytes + 255) & ~((size_t)255); return p;
  };
  auto wt_conv = (__hip_bfloat16*)alloc((size_t)3*CCH*CCH*5*2);
  __hip_bfloat16 *w_in[2], *w_x[2], *w_dt[2], *w_out[2];
  for (int dir=0; dir<2; dir++){
    w_in[dir]  = (__hip_bfloat16*)alloc((size_t)2*DI*CCH*2);
    w_x[dir]   = (__hip_bfloat16*)alloc((size_t)64*DI*2);
    w_dt[dir]  = (__hip_bfloat16*)alloc((size_t)DI*DTR*2);
    w_out[dir] = (__hip_bfloat16*)alloc((size_t)CCH*DI*2);
  }
  auto w_proj  = (__hip_bfloat16*)alloc((size_t)CCH*1024*2);
  auto xpad0   = (__hip_bfloat16*)alloc((size_t)BSZ*(LSEQ+4)*CCH*2);
  auto xpad1   = (__hip_bfloat16*)alloc((size_t)BSZ*(LSEQ+4)*CCH*2);
  auto convtmp = (float*)alloc((size_t)BL*CCH*4);
  auto h_enc   = (__hip_bfloat16*)alloc((size_t)BL*CCH*2);
  auto h_rev   = (__hip_bfloat16*)alloc((size_t)BL*CCH*2);
  auto xz      = (float*)alloc((size_t)BL*2*DI*4);
  auto u       = (float*)alloc((size_t)BL*DI*4);
  auto ub      = (__hip_bfloat16*)alloc((size_t)BL*DI*2);
  auto xdbc    = (float*)alloc((size_t)BL*64*4);
  auto dtb     = (__hip_bfloat16*)alloc((size_t)BL*DTR*2);
  auto dy      = (float*)alloc((size_t)BL*DI*4);   // delta in, y out (in place)
  auto yb      = (__hip_bfloat16*)alloc((size_t)BL*DI*2);
  auto fob     = (__hip_bfloat16*)alloc((size_t)BL*DI*2);  // [fo|bo] bf16

  auto nb = [](size_t n){ return (unsigned)((n + 255)/256); };

  // --- weight prep (recomputed every call: stateless/deterministic) ---
  k_prep_convw<<<dim3(nb((size_t)3*CCH*CCH*5)), dim3(256), 0, stream>>>(convw, wt_conv);
  for (int dir=0; dir<2; dir++){
    int base = 10 + 9*dir;
    k_cast_b<<<dim3(nb((size_t)2*DI*CCH)), dim3(256), 0, stream>>>((const float*)d_in[base+0], w_in[dir], 2*DI*CCH);
    k_cast_b<<<dim3(nb((size_t)64*DI)),    dim3(256), 0, stream>>>((const float*)d_in[base+3], w_x[dir], 64*DI);
    k_cast_b<<<dim3(nb((size_t)DI*DTR)),   dim3(256), 0, stream>>>((const float*)d_in[base+4], w_dt[dir], DI*DTR);
    k_cast_b<<<dim3(nb((size_t)CCH*DI)),   dim3(256), 0, stream>>>((const float*)d_in[base+8], w_out[dir], CCH*DI);
  }
  k_cast_b<<<dim3(nb((size_t)CCH*1024)), dim3(256), 0, stream>>>(projw, w_proj, CCH*1024);

  auto gemm = [&](const void* A, int lda, int padE, const void* W, void* C, int ldc, int coloff,
                  int M, int N, int K, const float* bias, int act, const unsigned char* msk, bool outbf){
    int blocks = (M/64)*(N/64);
    if (outbf)
      k_gemm<true><<<dim3(blocks), dim3(64), 0, stream>>>((const __hip_bfloat16*)A, lda, padE,
          (const __hip_bfloat16*)W, C, ldc, coloff, N, K, bias, act, msk);
    else
      k_gemm<false><<<dim3(blocks), dim3(64), 0, stream>>>((const __hip_bfloat16*)A, lda, padE,
          (const __hip_bfloat16*)W, C, ldc, coloff, N, K, bias, act, msk);
  };

  // --- encoder: embed + 3x (conv-as-GEMM -> LN/leaky/mask) ---
  k_embed<<<dim3(nb((size_t)BSZ*(LSEQ+4)*CCH)), dim3(256), 0, stream>>>(x, emb, xpad0);
  k_zero_pads<<<dim3(nb((size_t)BSZ*4*CCH)), dim3(256), 0, stream>>>(xpad1);

  __hip_bfloat16* xp_in = xpad0;
  __hip_bfloat16* xp_out = xpad1;
  for (int layer=0; layer<3; layer++){
    gemm(xp_in, CCH, 4, wt_conv + (size_t)layer*CCH*CCH*5, convtmp, CCH, 0,
         BL, CCH, CCH*5, convb + layer*CCH, 0, nullptr, false);
    bool last = (layer==2);
    k_ln<<<dim3(BL), dim3(256), 0, stream>>>(convtmp, lng + layer*CCH, lnb + layer*CCH, m,
        last ? nullptr : xp_out, last ? h_enc : nullptr, last ? h_rev : nullptr);
    __hip_bfloat16* t2 = xp_in; xp_in = xp_out; xp_out = t2;
  }

  // --- bidirectional mamba ---
  for (int dir=0; dir<2; dir++){
    int base = 10 + 9*dir;
    const float* mcw    = (const float*)d_in[base+1];
    const float* mcb    = (const float*)d_in[base+2];
    const float* dtbias = (const float*)d_in[base+5];
    const float* Alog   = (const float*)d_in[base+6];
    const float* Dp     = (const float*)d_in[base+7];
    const __hip_bfloat16* hin = (dir==0) ? h_enc : h_rev;

    gemm(hin, CCH, 0, w_in[dir], xz, 2*DI, 0, BL, 2*DI, CCH, nullptr, 0, nullptr, false);
    k_dwconv<<<dim3(nb((size_t)BL*DI)), dim3(256), 0, stream>>>(xz, mcw, mcb, u, ub);
    gemm(ub, DI, 0, w_x[dir], xdbc, 64, 0, BL, 64, DI, nullptr, 0, nullptr, false);
    k_dtcast<<<dim3(nb((size_t)BL*DTR)), dim3(256), 0, stream>>>(xdbc, dtb);
    gemm(dtb, DTR, 0, w_dt[dir], dy, DI, 0, BL, DI, DTR, dtbias, 1, nullptr, false);
    k_scan<<<dim3(BL/16), dim3(256), 0, stream>>>(Alog, dy, u, xdbc);
    k_ygate<<<dim3(nb((size_t)BL*DI)), dim3(256), 0, stream>>>(dy, u, xz, Dp, yb);
    gemm(yb, DI, 0, w_out[dir], fob, DI, (dir==0)?0:512, BL, CCH, DI, nullptr, 0, nullptr, true);
  }

  // --- final projection + bias + mask -> d_out (f32) ---
  gemm(fob, DI, 0, w_proj, d_out, CCH, 0, BL, CCH, DI, projb, 0, m, false);
}

// Round 2
// 847.259 us; speedup vs baseline: 1.7564x; 1.7564x over previous
//
#include <hip/hip_runtime.h>
#include <hip/hip_bf16.h>

typedef __attribute__((ext_vector_type(8))) short short8;
typedef __attribute__((ext_vector_type(4))) float f32x4;
typedef __attribute__((ext_vector_type(4))) unsigned short ushort4_t;

#define BSZ 4
#define LSEQ 1024
#define CCH 512
#define BL (BSZ*LSEQ)   // 4096 rows
#define DI 1024         // d_inner
#define NST 16
#define DTR 32

__device__ __forceinline__ float sigmoidf_(float x){ return 1.f/(1.f+__expf(-x)); }
__device__ __forceinline__ float softplus_(float x){ return x > 20.f ? x : log1pf(__expf(x)); }
__device__ __forceinline__ unsigned short f2bf_(float f){
  __hip_bfloat16 h = __float2bfloat16(f); return *(unsigned short*)&h;
}

typedef const __attribute__((address_space(1))) unsigned int* gas_t;
typedef __attribute__((address_space(3))) unsigned int* las_t;
__device__ __forceinline__ void gload16(const void* g, void* l){
  __builtin_amdgcn_global_load_lds((gas_t)g, (las_t)l, 16, 0, 0);
}

// ---------------- prep / elementwise kernels ----------------

__global__ void k_cast_b4(const float* __restrict__ s, unsigned short* __restrict__ d, int n4){
  int i = blockIdx.x*256 + threadIdx.x;
  if (i >= n4) return;
  float4 v = ((const float4*)s)[i];
  ushort4_t o = { f2bf_(v.x), f2bf_(v.y), f2bf_(v.z), f2bf_(v.w) };
  *(ushort4_t*)(d + (size_t)i*4) = o;
}

// conv_w [3][512][512][5] -> wt [3][512][2560], j = k*512 + ci  (matches contiguous patch)
__global__ void k_prep_convw(const float* __restrict__ cw, __hip_bfloat16* __restrict__ wt){
  int i = blockIdx.x*256 + threadIdx.x;
  const int total = 3*CCH*CCH*5;
  if (i >= total) return;
  int j = i % (CCH*5);
  int co = (i/(CCH*5)) % CCH;
  int layer = i/(CCH*5*CCH);
  int k = j >> 9, ci = j & 511;
  wt[i] = __float2bfloat16(cw[(((size_t)layer*CCH + co)*CCH + ci)*5 + k]);
}

// gather emb[x] into padded [B][L+4][C] bf16 (2 zero rows each side for K=5 conv)
__global__ void k_embed(const int* __restrict__ x, const float* __restrict__ emb,
                        __hip_bfloat16* __restrict__ xpad){
  int i = blockIdx.x*256 + threadIdx.x;
  const int total = BSZ*(LSEQ+4)*CCH;
  if (i >= total) return;
  int c = i & (CCH-1);
  int r = (i >> 9) % (LSEQ+4);
  int b = i / ((LSEQ+4)*CCH);
  float v = 0.f;
  if (r >= 2 && r < LSEQ+2){
    int tok = x[b*LSEQ + (r-2)];
    v = emb[(size_t)tok*CCH + c];
  }
  xpad[i] = __float2bfloat16(v);
}

__global__ void k_zero_pads(__hip_bfloat16* __restrict__ xpad){
  int i = blockIdx.x*256 + threadIdx.x;
  const int total = BSZ*4*CCH;
  if (i >= total) return;
  int c = i & (CCH-1);
  int pr = (i >> 9) & 3;
  int b = i >> 11;
  int r = (pr < 2) ? pr : (LSEQ+2) + (pr-2);
  xpad[((size_t)b*(LSEQ+4) + r)*CCH + c] = __float2bfloat16(0.f);
}

// per-(b,l) channel LayerNorm + scale/shift + LeakyReLU(0.2) + mask
__global__ __launch_bounds__(256) void k_ln(
    const float* __restrict__ in, const float* __restrict__ g, const float* __restrict__ bb,
    const unsigned char* __restrict__ mask,
    __hip_bfloat16* __restrict__ xpad_next,
    __hip_bfloat16* __restrict__ h_enc, __hip_bfloat16* __restrict__ h_rev){
  int row = blockIdx.x;                 // b*1024 + l
  int b = row >> 10, l = row & 1023;
  const float* xr = in + (size_t)row*CCH;
  int t = threadIdx.x;
  float v0 = xr[t], v1 = xr[t+256];
  float s = v0+v1, s2 = v0*v0 + v1*v1;
  #pragma unroll
  for (int off=32; off>0; off>>=1){ s += __shfl_down(s,off); s2 += __shfl_down(s2,off); }
  __shared__ float ls[8];
  if ((t&63)==0){ ls[t>>6] = s; ls[(t>>6)+4] = s2; }
  __syncthreads();
  float S  = ls[0]+ls[1]+ls[2]+ls[3];
  float S2 = ls[4]+ls[5]+ls[6]+ls[7];
  float mu = S*(1.f/CCH);
  float var = S2*(1.f/CCH) - mu*mu;
  float rs = rsqrtf(var + 1e-5f);
  bool mk = mask[row] != 0;
  #pragma unroll
  for (int e=0; e<2; e++){
    int c = t + e*256;
    float v = e ? v1 : v0;
    float h = (v-mu)*rs*g[c] + bb[c];
    h = h > 0.f ? h : 0.2f*h;
    if (mk) h = 0.f;
    __hip_bfloat16 hb = __float2bfloat16(h);
    if (xpad_next) xpad_next[((size_t)b*(LSEQ+4) + (l+2))*CCH + c] = hb;
    if (h_enc) h_enc[(size_t)row*CCH + c] = hb;
    if (h_rev) h_rev[((size_t)(b<<10) + (1023-l))*CCH + c] = hb;
  }
}

// ---------------- small MFMA wave-GEMM (x_proj N=64, dt_proj K=32) ----------------
template<bool OUTBF>
__global__ __launch_bounds__(64) void k_gemm(
    const __hip_bfloat16* __restrict__ A, int lda, int padExtra,
    const __hip_bfloat16* __restrict__ W, void* __restrict__ Cout,
    int ldc, int coloff, int N, int K,
    const float* __restrict__ bias, int act,
    const unsigned char* __restrict__ mask){
  int tiles_n = N >> 6;
  int tn = blockIdx.x % tiles_n;
  int tm = blockIdx.x / tiles_n;
  int m0 = tm << 6, n0 = tn << 6;
  int lane = threadIdx.x;
  int r = lane & 15, kg = lane >> 4;

  const short* Ap[4];
  const short* Wp[4];
  #pragma unroll
  for (int mi=0; mi<4; mi++){
    int row = m0 + mi*16 + r;
    int phys = row + padExtra*(row >> 10);
    Ap[mi] = (const short*)A + (size_t)phys*lda + kg*8;
  }
  #pragma unroll
  for (int nj=0; nj<4; nj++){
    int col = n0 + nj*16 + r;
    Wp[nj] = (const short*)W + (size_t)col*K + kg*8;
  }
  f32x4 acc[4][4];
  #pragma unroll
  for (int mi=0;mi<4;mi++)
    #pragma unroll
    for (int nj=0;nj<4;nj++) acc[mi][nj] = (f32x4){0.f,0.f,0.f,0.f};

  for (int kk=0; kk<K; kk+=32){
    short8 a[4], w[4];
    #pragma unroll
    for (int mi=0;mi<4;mi++) a[mi] = *(const short8*)(Ap[mi] + kk);
    #pragma unroll
    for (int nj=0;nj<4;nj++) w[nj] = *(const short8*)(Wp[nj] + kk);
    #pragma unroll
    for (int mi=0;mi<4;mi++)
      #pragma unroll
      for (int nj=0;nj<4;nj++)
        acc[mi][nj] = __builtin_amdgcn_mfma_f32_16x16x32_bf16(a[mi], w[nj], acc[mi][nj], 0,0,0);
  }
  #pragma unroll
  for (int mi=0;mi<4;mi++){
    #pragma unroll
    for (int nj=0;nj<4;nj++){
      #pragma unroll
      for (int reg=0; reg<4; reg++){
        int row = m0 + mi*16 + kg*4 + reg;
        int col = n0 + nj*16 + r;
        float v = acc[mi][nj][reg];
        if (bias) v += bias[col];
        if (act == 1) v = softplus_(v);
        if (mask && mask[row]) v = 0.f;
        size_t o = (size_t)row*ldc + coloff + col;
        if (OUTBF) ((__hip_bfloat16*)Cout)[o] = __float2bfloat16(v);
        else       ((float*)Cout)[o] = v;
      }
    }
  }
}

// ---------------- big staged GEMM: 128(M)x64(N) tile, BK=32, 4 waves, dbuf LDS ----------
// LDS A[128][32] + B[64][32] bf16, slot-swizzled: LDS 16B-slot s of row r holds global
// slot s^(r&3). global_load_lds writes linearly, so the swizzle is applied to the
// per-lane GLOBAL source address (both-sides rule) and to the ds_read address.
template<bool OUTBF>
__global__ __launch_bounds__(256) void k_gemm_big(
    const __hip_bfloat16* __restrict__ A, int lda, int padExtra,
    const __hip_bfloat16* __restrict__ W, void* __restrict__ Cout,
    int ldc, int coloff, int tiles_n, int K,
    const float* __restrict__ bias, const unsigned char* __restrict__ mask){
  __shared__ alignas(16) __hip_bfloat16 smem[2][6144];   // 2 x (4096 A + 2048 B)
  int tn = blockIdx.x % tiles_n;
  int tm = blockIdx.x / tiles_n;
  int m0 = tm*128, n0 = tn*64;
  int tid = threadIdx.x;
  int wid = tid >> 6, lane = tid & 63;
  int r = lane & 15, kg = lane >> 4;

  // staging source element-offsets (k0-invariant part)
  int sr = lane >> 2;                 // sub-row within 16-row chunk
  int gs = (lane & 3) ^ (sr & 3);     // swizzled global 16B-slot
  int row0 = m0 + wid*16 + sr;        // A chunk, call 0
  int row1 = row0 + 64;               // A chunk, call 1
  int p0 = row0 + padExtra*(row0 >> 10);
  int p1 = row1 + padExtra*(row1 >> 10);
  size_t aoff0 = (size_t)p0*lda + gs*8;
  size_t aoff1 = (size_t)p1*lda + gs*8;
  int bcol = n0 + wid*16 + sr;
  size_t boff = (size_t)bcol*K + gs*8;

  // fragment ds_read element-offsets
  int wr = wid >> 1, wc = wid & 1;
  int xs = (kg ^ (r & 3))*8;          // swizzled slot on the read side
  int afrag[4], bfrag[2];
  #pragma unroll
  for (int mi=0; mi<4; mi++) afrag[mi] = (wr*64 + mi*16 + r)*32 + xs;
  #pragma unroll
  for (int nj=0; nj<2; nj++) bfrag[nj] = 4096 + (wc*32 + nj*16 + r)*32 + xs;

  f32x4 acc[4][2];
  #pragma unroll
  for (int mi=0;mi<4;mi++)
    #pragma unroll
    for (int nj=0;nj<2;nj++) acc[mi][nj] = (f32x4){0.f,0.f,0.f,0.f};

  const int nt = K >> 5;
  // prologue: stage tile 0
  gload16((const short*)A + aoff0, &smem[0][wid*512]);
  gload16((const short*)A + aoff1, &smem[0][(wid+4)*512]);
  gload16((const short*)W + boff,  &smem[0][4096 + wid*512]);
  __syncthreads();
  int cur = 0;
  for (int t=0; t<nt; t++){
    if (t+1 < nt){
      int k0 = (t+1)*32;
      gload16((const short*)A + aoff0 + k0, &smem[cur^1][wid*512]);
      gload16((const short*)A + aoff1 + k0, &smem[cur^1][(wid+4)*512]);
      gload16((const short*)W + boff  + k0, &smem[cur^1][4096 + wid*512]);
    }
    short8 a[4], b[2];
    #pragma unroll
    for (int mi=0;mi<4;mi++) a[mi] = *(const short8*)&smem[cur][afrag[mi]];
    #pragma unroll
    for (int nj=0;nj<2;nj++) b[nj] = *(const short8*)&smem[cur][bfrag[nj]];
    #pragma unroll
    for (int mi=0;mi<4;mi++)
      #pragma unroll
      for (int nj=0;nj<2;nj++)
        acc[mi][nj] = __builtin_amdgcn_mfma_f32_16x16x32_bf16(a[mi], b[nj], acc[mi][nj], 0,0,0);
    __syncthreads();     // drains vmcnt(0)+lgkmcnt(0): next tile staged, reads retired
    cur ^= 1;
  }
  #pragma unroll
  for (int mi=0;mi<4;mi++){
    #pragma unroll
    for (int nj=0;nj<2;nj++){
      #pragma unroll
      for (int reg=0; reg<4; reg++){
        int row = m0 + wr*64 + mi*16 + kg*4 + reg;
        int col = n0 + wc*32 + nj*16 + r;
        float v = acc[mi][nj][reg];
        if (bias) v += bias[col];
        if (mask && mask[row]) v = 0.f;
        size_t o = (size_t)row*ldc + coloff + col;
        if (OUTBF) ((__hip_bfloat16*)Cout)[o] = __float2bfloat16(v);
        else       ((float*)Cout)[o] = v;
      }
    }
  }
}

// ---------------- mamba pieces ----------------

__global__ void k_dwconv(const float* __restrict__ xz, const float* __restrict__ cw,
                         const float* __restrict__ cb, float* __restrict__ u,
                         __hip_bfloat16* __restrict__ ub){
  int i = blockIdx.x*256 + threadIdx.x;
  if (i >= BL*DI) return;
  int d = i & (DI-1);
  int row = i >> 10;
  int l = row & 1023;
  int rb = row & ~1023;
  float acc = cb[d];
  #pragma unroll
  for (int k=0;k<4;k++){
    int ll = l - 3 + k;
    if (ll >= 0) acc += cw[d*4 + k] * xz[(size_t)(rb + ll)*(2*DI) + d];
  }
  float s = acc * sigmoidf_(acc);
  u[i] = s;
  ub[i] = __float2bfloat16(s);
}

__global__ void k_dtcast(const float* __restrict__ xdbc, __hip_bfloat16* __restrict__ dtb){
  int i = blockIdx.x*256 + threadIdx.x;
  if (i >= BL*DTR) return;
  int row = i >> 5, j = i & 31;
  dtb[i] = __float2bfloat16(xdbc[(size_t)row*64 + j]);
}

// -------- chunked selective scan (3 passes; 16 chunks of 64 steps) --------
// pair = row*16 + chunk; 16 lanes (states) per pair.

__global__ __launch_bounds__(256) void k_scan_part(
    const float* __restrict__ A_log, const float* __restrict__ dy,
    const float* __restrict__ u, const float* __restrict__ xdbc,
    float* __restrict__ Hp, float* __restrict__ Pp){
  int t = threadIdx.x;
  int n = t & 15;
  int pair = blockIdx.x*16 + (t>>4);
  int row = pair >> 4, c = pair & 15;
  int b = row >> 10, d = row & 1023;
  float Af = -__expf(A_log[d*NST + n]);
  float h = 0.f, P = 1.f;
  size_t blbase = (size_t)b*1024 + c*64;
  #pragma unroll 2
  for (int l=0; l<64; l++){
    size_t bl = blbase + l;
    float dv = dy[bl*DI + d];
    float uv = u[bl*DI + d];
    float Bv = xdbc[bl*64 + 32 + n];
    float dA = __expf(dv*Af);
    h = __fmaf_rn(dA, h, dv*Bv*uv);
    P *= dA;
  }
  Hp[(size_t)pair*16 + n] = h;
  Pp[(size_t)pair*16 + n] = P;
}

// combine: h_in[c+1] = P[c]*h_in[c] + H[c]; writes h_in back into Pp (in place)
__global__ void k_scan_comb(float* __restrict__ Hp, float* __restrict__ Pp){
  int i = blockIdx.x*256 + threadIdx.x;   // row*16 + n
  if (i >= BL*NST) return;
  int n = i & 15, row = i >> 4;
  float hin = 0.f;
  #pragma unroll
  for (int c=0;c<16;c++){
    size_t idx = ((size_t)row*16 + c)*16 + n;
    float P = Pp[idx], H = Hp[idx];
    Pp[idx] = hin;
    hin = __fmaf_rn(P, hin, H);
  }
}

__global__ __launch_bounds__(256) void k_scan_fin(
    const float* __restrict__ A_log, float* __restrict__ dy,
    const float* __restrict__ u, const float* __restrict__ xdbc,
    const float* __restrict__ Hin){
  int t = threadIdx.x;
  int n = t & 15;
  int pair = blockIdx.x*16 + (t>>4);
  int row = pair >> 4, c = pair & 15;
  int b = row >> 10, d = row & 1023;
  float Af = -__expf(A_log[d*NST + n]);
  float h = Hin[(size_t)pair*16 + n];
  size_t blbase = (size_t)b*1024 + c*64;
  #pragma unroll 2
  for (int l=0; l<64; l++){
    size_t bl = blbase + l;
    float dv = dy[bl*DI + d];
    float uv = u[bl*DI + d];
    float Bv = xdbc[bl*64 + 32 + n];
    float Cv = xdbc[bl*64 + 48 + n];
    float dA = __expf(dv*Af);
    h = __fmaf_rn(dA, h, dv*Bv*uv);
    float p = h * Cv;
    p += __shfl_xor(p, 1);
    p += __shfl_xor(p, 2);
    p += __shfl_xor(p, 4);
    p += __shfl_xor(p, 8);
    if (n == 0) dy[bl*DI + d] = p;
  }
}

__global__ void k_ygate(const float* __restrict__ y, const float* __restrict__ u,
                        const float* __restrict__ xz, const float* __restrict__ Dp,
                        __hip_bfloat16* __restrict__ yb){
  int i = blockIdx.x*256 + threadIdx.x;
  if (i >= BL*DI) return;
  int d = i & (DI-1);
  size_t row = (size_t)(i >> 10);
  float z = xz[row*(2*DI) + DI + d];
  float v = (y[i] + u[i]*Dp[d]) * (z * sigmoidf_(z));
  yb[i] = __float2bfloat16(v);
}

// ---------------- host ----------------

extern "C" void kernel_launch(void* const* d_in, const int* in_sizes, int n_in,
                              void* d_out, int out_size, void* d_ws, size_t ws_size,
                              hipStream_t stream){
  (void)in_sizes; (void)n_in; (void)out_size; (void)ws_size;
  const int*   x     = (const int*)d_in[0];
  const unsigned char* m = (const unsigned char*)d_in[2];
  const float* emb   = (const float*)d_in[3];
  const float* convw = (const float*)d_in[4];
  const float* convb = (const float*)d_in[5];
  const float* lng   = (const float*)d_in[6];
  const float* lnb   = (const float*)d_in[7];
  const float* projw = (const float*)d_in[8];
  const float* projb = (const float*)d_in[9];

  char* ws = (char*)d_ws;
  size_t off = 0;
  auto alloc = [&](size_t bytes)->char*{
    char* p = ws + off; off += (bytes + 255) & ~((size_t)255); return p;
  };
  auto wt_conv = (__hip_bfloat16*)alloc((size_t)3*CCH*CCH*5*2);
  __hip_bfloat16 *w_in[2], *w_x[2], *w_dt[2], *w_out[2];
  for (int dir=0; dir<2; dir++){
    w_in[dir]  = (__hip_bfloat16*)alloc((size_t)2*DI*CCH*2);
    w_x[dir]   = (__hip_bfloat16*)alloc((size_t)64*DI*2);
    w_dt[dir]  = (__hip_bfloat16*)alloc((size_t)DI*DTR*2);
    w_out[dir] = (__hip_bfloat16*)alloc((size_t)CCH*DI*2);
  }
  auto w_proj  = (__hip_bfloat16*)alloc((size_t)CCH*1024*2);
  auto xpad0   = (__hip_bfloat16*)alloc((size_t)BSZ*(LSEQ+4)*CCH*2);
  auto xpad1   = (__hip_bfloat16*)alloc((size_t)BSZ*(LSEQ+4)*CCH*2);
  auto convtmp = (float*)alloc((size_t)BL*CCH*4);       // conv out; later scan scratch
  auto h_enc   = (__hip_bfloat16*)alloc((size_t)BL*CCH*2);
  auto h_rev   = (__hip_bfloat16*)alloc((size_t)BL*CCH*2);
  auto xz      = (float*)alloc((size_t)BL*2*DI*4);
  auto u       = (float*)alloc((size_t)BL*DI*4);
  auto ub      = (__hip_bfloat16*)alloc((size_t)BL*DI*2);
  auto xdbc    = (float*)alloc((size_t)BL*64*4);
  auto dtb     = (__hip_bfloat16*)alloc((size_t)BL*DTR*2);
  auto dy      = (float*)alloc((size_t)BL*DI*4);        // delta in, y out (in place)
  auto yb      = (__hip_bfloat16*)alloc((size_t)BL*DI*2);
  auto fob     = (__hip_bfloat16*)alloc((size_t)BL*DI*2);

  float* Hp = convtmp;                    // 4 MB
  float* Pp = convtmp + (size_t)BL*NST*16/16*16;  // = convtmp + 1M floats (4 MB)
  // (BL*16 pairs * 16 states = 1,048,576 floats each; convtmp is 2,097,152 floats)

  auto nb = [](size_t n){ return (unsigned)((n + 255)/256); };

  // --- weight prep ---
  k_prep_convw<<<dim3(nb((size_t)3*CCH*CCH*5)), dim3(256), 0, stream>>>(convw, wt_conv);
  for (int dir=0; dir<2; dir++){
    int base = 10 + 9*dir;
    k_cast_b4<<<dim3(nb((size_t)2*DI*CCH/4)), dim3(256), 0, stream>>>((const float*)d_in[base+0], (unsigned short*)w_in[dir], 2*DI*CCH/4);
    k_cast_b4<<<dim3(nb((size_t)64*DI/4)),    dim3(256), 0, stream>>>((const float*)d_in[base+3], (unsigned short*)w_x[dir], 64*DI/4);
    k_cast_b4<<<dim3(nb((size_t)DI*DTR/4)),   dim3(256), 0, stream>>>((const float*)d_in[base+4], (unsigned short*)w_dt[dir], DI*DTR/4);
    k_cast_b4<<<dim3(nb((size_t)CCH*DI/4)),   dim3(256), 0, stream>>>((const float*)d_in[base+8], (unsigned short*)w_out[dir], CCH*DI/4);
  }
  k_cast_b4<<<dim3(nb((size_t)CCH*1024/4)), dim3(256), 0, stream>>>(projw, (unsigned short*)w_proj, CCH*1024/4);

  auto gemm_small = [&](const void* A, int lda, int padE, const void* W, void* C, int ldc, int coloff,
                  int M, int N, int K, const float* bias, int act, const unsigned char* msk, bool outbf){
    int blocks = (M/64)*(N/64);
    if (outbf)
      k_gemm<true><<<dim3(blocks), dim3(64), 0, stream>>>((const __hip_bfloat16*)A, lda, padE,
          (const __hip_bfloat16*)W, C, ldc, coloff, N, K, bias, act, msk);
    else
      k_gemm<false><<<dim3(blocks), dim3(64), 0, stream>>>((const __hip_bfloat16*)A, lda, padE,
          (const __hip_bfloat16*)W, C, ldc, coloff, N, K, bias, act, msk);
  };
  auto gemm_big = [&](const void* A, int lda, int padE, const void* W, void* C, int ldc, int coloff,
                  int M, int N, int K, const float* bias, const unsigned char* msk, bool outbf){
    int tiles_n = N/64;
    int blocks = (M/128)*tiles_n;
    if (outbf)
      k_gemm_big<true><<<dim3(blocks), dim3(256), 0, stream>>>((const __hip_bfloat16*)A, lda, padE,
          (const __hip_bfloat16*)W, C, ldc, coloff, tiles_n, K, bias, msk);
    else
      k_gemm_big<false><<<dim3(blocks), dim3(256), 0, stream>>>((const __hip_bfloat16*)A, lda, padE,
          (const __hip_bfloat16*)W, C, ldc, coloff, tiles_n, K, bias, msk);
  };

  // --- encoder: embed + 3x (conv-as-GEMM -> LN/leaky/mask) ---
  k_embed<<<dim3(nb((size_t)BSZ*(LSEQ+4)*CCH)), dim3(256), 0, stream>>>(x, emb, xpad0);
  k_zero_pads<<<dim3(nb((size_t)BSZ*4*CCH)), dim3(256), 0, stream>>>(xpad1);

  __hip_bfloat16* xp_in = xpad0;
  __hip_bfloat16* xp_out = xpad1;
  for (int layer=0; layer<3; layer++){
    gemm_big(xp_in, CCH, 4, wt_conv + (size_t)layer*CCH*CCH*5, convtmp, CCH, 0,
         BL, CCH, CCH*5, convb + layer*CCH, nullptr, false);
    bool last = (layer==2);
    k_ln<<<dim3(BL), dim3(256), 0, stream>>>(convtmp, lng + layer*CCH, lnb + layer*CCH, m,
        last ? nullptr : xp_out, last ? h_enc : nullptr, last ? h_rev : nullptr);
    __hip_bfloat16* t2 = xp_in; xp_in = xp_out; xp_out = t2;
  }

  // --- bidirectional mamba ---
  for (int dir=0; dir<2; dir++){
    int base = 10 + 9*dir;
    const float* mcw    = (const float*)d_in[base+1];
    const float* mcb    = (const float*)d_in[base+2];
    const float* dtbias = (const float*)d_in[base+5];
    const float* Alog   = (const float*)d_in[base+6];
    const float* Dp     = (const float*)d_in[base+7];
    const __hip_bfloat16* hin = (dir==0) ? h_enc : h_rev;

    gemm_big(hin, CCH, 0, w_in[dir], xz, 2*DI, 0, BL, 2*DI, CCH, nullptr, nullptr, false);
    k_dwconv<<<dim3(nb((size_t)BL*DI)), dim3(256), 0, stream>>>(xz, mcw, mcb, u, ub);
    gemm_small(ub, DI, 0, w_x[dir], xdbc, 64, 0, BL, 64, DI, nullptr, 0, nullptr, false);
    k_dtcast<<<dim3(nb((size_t)BL*DTR)), dim3(256), 0, stream>>>(xdbc, dtb);
    gemm_small(dtb, DTR, 0, w_dt[dir], dy, DI, 0, BL, DI, DTR, dtbias, 1, nullptr, false);
    k_scan_part<<<dim3(BL*NST/16), dim3(256), 0, stream>>>(Alog, dy, u, xdbc, Hp, Pp);
    k_scan_comb<<<dim3(nb((size_t)BL*NST)), dim3(256), 0, stream>>>(Hp, Pp);
    k_scan_fin<<<dim3(BL*NST/16), dim3(256), 0, stream>>>(Alog, dy, u, xdbc, Pp);
    k_ygate<<<dim3(nb((size_t)BL*DI)), dim3(256), 0, stream>>>(dy, u, xz, Dp, yb);
    gemm_big(yb, DI, 0, w_out[dir], fob, DI, (dir==0)?0:512, BL, CCH, DI, nullptr, nullptr, true);
  }

  // --- final projection + bias + mask -> d_out (f32) ---
  gemm_big(fob, DI, 0, w_proj, d_out, CCH, 0, BL, CCH, DI, projb, m, false);
}

// Round 3
// 615.280 us; speedup vs baseline: 2.4186x; 1.3770x over previous
//
#include <hip/hip_runtime.h>
#include <hip/hip_bf16.h>

typedef __attribute__((ext_vector_type(8))) short short8;
typedef __attribute__((ext_vector_type(4))) float f32x4;
typedef __attribute__((ext_vector_type(4))) unsigned short ushort4_t;

#define BSZ 4
#define LSEQ 1024
#define CCH 512
#define BL (BSZ*LSEQ)   // 4096 rows
#define DI 1024         // d_inner
#define NST 16
#define DTR 32

__device__ __forceinline__ float sigmoidf_(float x){ return 1.f/(1.f+__expf(-x)); }
__device__ __forceinline__ float softplus_(float x){ return x > 20.f ? x : log1pf(__expf(x)); }
__device__ __forceinline__ unsigned short f2bf_(float f){
  __hip_bfloat16 h = __float2bfloat16(f); return *(unsigned short*)&h;
}

typedef const __attribute__((address_space(1))) unsigned int* gas_t;
typedef __attribute__((address_space(3))) unsigned int* las_t;
__device__ __forceinline__ void gload16(const void* g, void* l){
  __builtin_amdgcn_global_load_lds((gas_t)g, (las_t)l, 16, 0, 0);
}

// ---------------- prep / elementwise kernels ----------------

__global__ void k_cast_b4(const float* __restrict__ s, unsigned short* __restrict__ d, int n4){
  int i = blockIdx.x*256 + threadIdx.x;
  if (i >= n4) return;
  float4 v = ((const float4*)s)[i];
  ushort4_t o = { f2bf_(v.x), f2bf_(v.y), f2bf_(v.z), f2bf_(v.w) };
  *(ushort4_t*)(d + (size_t)i*4) = o;
}

// conv_w [3][512][512][5] -> wt [3][512][2560], j = k*512 + ci  (matches contiguous patch)
__global__ void k_prep_convw(const float* __restrict__ cw, __hip_bfloat16* __restrict__ wt){
  int i = blockIdx.x*256 + threadIdx.x;
  const int total = 3*CCH*CCH*5;
  if (i >= total) return;
  int j = i % (CCH*5);
  int co = (i/(CCH*5)) % CCH;
  int layer = i/(CCH*5*CCH);
  int k = j >> 9, ci = j & 511;
  wt[i] = __float2bfloat16(cw[(((size_t)layer*CCH + co)*CCH + ci)*5 + k]);
}

// gather emb[x] into padded [B][L+4][C] bf16 (2 zero rows each side for K=5 conv)
__global__ void k_embed(const int* __restrict__ x, const float* __restrict__ emb,
                        __hip_bfloat16* __restrict__ xpad){
  int i = blockIdx.x*256 + threadIdx.x;
  const int total = BSZ*(LSEQ+4)*CCH;
  if (i >= total) return;
  int c = i & (CCH-1);
  int r = (i >> 9) % (LSEQ+4);
  int b = i / ((LSEQ+4)*CCH);
  float v = 0.f;
  if (r >= 2 && r < LSEQ+2){
    int tok = x[b*LSEQ + (r-2)];
    v = emb[(size_t)tok*CCH + c];
  }
  xpad[i] = __float2bfloat16(v);
}

__global__ void k_zero_pads(__hip_bfloat16* __restrict__ xpad){
  int i = blockIdx.x*256 + threadIdx.x;
  const int total = BSZ*4*CCH;
  if (i >= total) return;
  int c = i & (CCH-1);
  int pr = (i >> 9) & 3;
  int b = i >> 11;
  int r = (pr < 2) ? pr : (LSEQ+2) + (pr-2);
  xpad[((size_t)b*(LSEQ+4) + r)*CCH + c] = __float2bfloat16(0.f);
}

// per-(b,l) channel LayerNorm + scale/shift + LeakyReLU(0.2) + mask
__global__ __launch_bounds__(256) void k_ln(
    const float* __restrict__ in, const float* __restrict__ g, const float* __restrict__ bb,
    const unsigned char* __restrict__ mask,
    __hip_bfloat16* __restrict__ xpad_next,
    __hip_bfloat16* __restrict__ h_enc, __hip_bfloat16* __restrict__ h_rev){
  int row = blockIdx.x;                 // b*1024 + l
  int b = row >> 10, l = row & 1023;
  const float* xr = in + (size_t)row*CCH;
  int t = threadIdx.x;
  float v0 = xr[t], v1 = xr[t+256];
  float s = v0+v1, s2 = v0*v0 + v1*v1;
  #pragma unroll
  for (int off=32; off>0; off>>=1){ s += __shfl_down(s,off); s2 += __shfl_down(s2,off); }
  __shared__ float ls[8];
  if ((t&63)==0){ ls[t>>6] = s; ls[(t>>6)+4] = s2; }
  __syncthreads();
  float S  = ls[0]+ls[1]+ls[2]+ls[3];
  float S2 = ls[4]+ls[5]+ls[6]+ls[7];
  float mu = S*(1.f/CCH);
  float var = S2*(1.f/CCH) - mu*mu;
  float rs = rsqrtf(var + 1e-5f);
  bool mk = mask[row] != 0;
  #pragma unroll
  for (int e=0; e<2; e++){
    int c = t + e*256;
    float v = e ? v1 : v0;
    float h = (v-mu)*rs*g[c] + bb[c];
    h = h > 0.f ? h : 0.2f*h;
    if (mk) h = 0.f;
    __hip_bfloat16 hb = __float2bfloat16(h);
    if (xpad_next) xpad_next[((size_t)b*(LSEQ+4) + (l+2))*CCH + c] = hb;
    if (h_enc) h_enc[(size_t)row*CCH + c] = hb;
    if (h_rev) h_rev[((size_t)(b<<10) + (1023-l))*CCH + c] = hb;
  }
}

// ---------------- small MFMA wave-GEMM (dt_proj K=32) ----------------
template<bool OUTBF>
__global__ __launch_bounds__(64) void k_gemm(
    const __hip_bfloat16* __restrict__ A, int lda, int padExtra,
    const __hip_bfloat16* __restrict__ W, void* __restrict__ Cout,
    int ldc, int coloff, int N, int K,
    const float* __restrict__ bias, int act,
    const unsigned char* __restrict__ mask){
  int tiles_n = N >> 6;
  int tn = blockIdx.x % tiles_n;
  int tm = blockIdx.x / tiles_n;
  int m0 = tm << 6, n0 = tn << 6;
  int lane = threadIdx.x;
  int r = lane & 15, kg = lane >> 4;

  const short* Ap[4];
  const short* Wp[4];
  #pragma unroll
  for (int mi=0; mi<4; mi++){
    int row = m0 + mi*16 + r;
    int phys = row + padExtra*(row >> 10);
    Ap[mi] = (const short*)A + (size_t)phys*lda + kg*8;
  }
  #pragma unroll
  for (int nj=0; nj<4; nj++){
    int col = n0 + nj*16 + r;
    Wp[nj] = (const short*)W + (size_t)col*K + kg*8;
  }
  f32x4 acc[4][4];
  #pragma unroll
  for (int mi=0;mi<4;mi++)
    #pragma unroll
    for (int nj=0;nj<4;nj++) acc[mi][nj] = (f32x4){0.f,0.f,0.f,0.f};

  for (int kk=0; kk<K; kk+=32){
    short8 a[4], w[4];
    #pragma unroll
    for (int mi=0;mi<4;mi++) a[mi] = *(const short8*)(Ap[mi] + kk);
    #pragma unroll
    for (int nj=0;nj<4;nj++) w[nj] = *(const short8*)(Wp[nj] + kk);
    #pragma unroll
    for (int mi=0;mi<4;mi++)
      #pragma unroll
      for (int nj=0;nj<4;nj++)
        acc[mi][nj] = __builtin_amdgcn_mfma_f32_16x16x32_bf16(a[mi], w[nj], acc[mi][nj], 0,0,0);
  }
  #pragma unroll
  for (int mi=0;mi<4;mi++){
    #pragma unroll
    for (int nj=0;nj<4;nj++){
      #pragma unroll
      for (int reg=0; reg<4; reg++){
        int row = m0 + mi*16 + kg*4 + reg;
        int col = n0 + nj*16 + r;
        float v = acc[mi][nj][reg];
        if (bias) v += bias[col];
        if (act == 1) v = softplus_(v);
        if (mask && mask[row]) v = 0.f;
        size_t o = (size_t)row*ldc + coloff + col;
        if (OUTBF) ((__hip_bfloat16*)Cout)[o] = __float2bfloat16(v);
        else       ((float*)Cout)[o] = v;
      }
    }
  }
}

// ---------------- K-split GEMM for skinny N=64 (x_proj) ----------------
// One 64x64 m-tile per block; 4 waves each accumulate a K/4 slice; LDS reduce.
__global__ __launch_bounds__(256) void k_gemm_ksplit(
    const __hip_bfloat16* __restrict__ A, int lda,
    const __hip_bfloat16* __restrict__ W, float* __restrict__ Cout,
    int ldc, int K){
  __shared__ float red[4*4096];   // 64 KB
  int m0 = blockIdx.x << 6;
  int tid = threadIdx.x;
  int w = tid >> 6, lane = tid & 63;
  int r = lane & 15, kg = lane >> 4;
  int Kw = K >> 2;
  int kbase = w*Kw;

  const short* Ap[4];
  const short* Wp[4];
  #pragma unroll
  for (int mi=0; mi<4; mi++)
    Ap[mi] = (const short*)A + (size_t)(m0 + mi*16 + r)*lda + kbase + kg*8;
  #pragma unroll
  for (int nj=0; nj<4; nj++)
    Wp[nj] = (const short*)W + (size_t)(nj*16 + r)*K + kbase + kg*8;

  f32x4 acc[4][4];
  #pragma unroll
  for (int mi=0;mi<4;mi++)
    #pragma unroll
    for (int nj=0;nj<4;nj++) acc[mi][nj] = (f32x4){0.f,0.f,0.f,0.f};

  for (int kk=0; kk<Kw; kk+=32){
    short8 a[4], wv[4];
    #pragma unroll
    for (int mi=0;mi<4;mi++) a[mi] = *(const short8*)(Ap[mi] + kk);
    #pragma unroll
    for (int nj=0;nj<4;nj++) wv[nj] = *(const short8*)(Wp[nj] + kk);
    #pragma unroll
    for (int mi=0;mi<4;mi++)
      #pragma unroll
      for (int nj=0;nj<4;nj++)
        acc[mi][nj] = __builtin_amdgcn_mfma_f32_16x16x32_bf16(a[mi], wv[nj], acc[mi][nj], 0,0,0);
  }
  #pragma unroll
  for (int mi=0;mi<4;mi++)
    #pragma unroll
    for (int nj=0;nj<4;nj++)
      #pragma unroll
      for (int reg=0; reg<4; reg++){
        int rowt = mi*16 + kg*4 + reg;
        int col  = nj*16 + r;
        red[w*4096 + rowt*64 + col] = acc[mi][nj][reg];
      }
  __syncthreads();
  int e0 = tid*16;
  #pragma unroll
  for (int j=0; j<16; j+=4){
    f32x4 s = *(const f32x4*)&red[e0+j];
    #pragma unroll
    for (int ww=1; ww<4; ww++){
      f32x4 p = *(const f32x4*)&red[ww*4096 + e0 + j];
      s.x += p.x; s.y += p.y; s.z += p.z; s.w += p.w;
    }
    int e = e0 + j;
    int rowt = e >> 6, col = e & 63;
    *(f32x4*)&Cout[(size_t)(m0+rowt)*ldc + col] = s;
  }
}

// ---------------- big staged GEMM: 128(M)x64(N) tile, BK=32, 4 waves, dbuf LDS ----------
template<bool OUTBF>
__global__ __launch_bounds__(256) void k_gemm_big(
    const __hip_bfloat16* __restrict__ A, int lda, int padExtra,
    const __hip_bfloat16* __restrict__ W, void* __restrict__ Cout,
    int ldc, int coloff, int tiles_n, int K,
    const float* __restrict__ bias, const unsigned char* __restrict__ mask){
  __shared__ alignas(16) __hip_bfloat16 smem[2][6144];   // 2 x (4096 A + 2048 B)
  int tn = blockIdx.x % tiles_n;
  int tm = blockIdx.x / tiles_n;
  int m0 = tm*128, n0 = tn*64;
  int tid = threadIdx.x;
  int wid = tid >> 6, lane = tid & 63;
  int r = lane & 15, kg = lane >> 4;

  int sr = lane >> 2;
  int gs = (lane & 3) ^ (sr & 3);
  int row0 = m0 + wid*16 + sr;
  int row1 = row0 + 64;
  int p0 = row0 + padExtra*(row0 >> 10);
  int p1 = row1 + padExtra*(row1 >> 10);
  size_t aoff0 = (size_t)p0*lda + gs*8;
  size_t aoff1 = (size_t)p1*lda + gs*8;
  int bcol = n0 + wid*16 + sr;
  size_t boff = (size_t)bcol*K + gs*8;

  int wr = wid >> 1, wc = wid & 1;
  int xs = (kg ^ (r & 3))*8;
  int afrag[4], bfrag[2];
  #pragma unroll
  for (int mi=0; mi<4; mi++) afrag[mi] = (wr*64 + mi*16 + r)*32 + xs;
  #pragma unroll
  for (int nj=0; nj<2; nj++) bfrag[nj] = 4096 + (wc*32 + nj*16 + r)*32 + xs;

  f32x4 acc[4][2];
  #pragma unroll
  for (int mi=0;mi<4;mi++)
    #pragma unroll
    for (int nj=0;nj<2;nj++) acc[mi][nj] = (f32x4){0.f,0.f,0.f,0.f};

  const int nt = K >> 5;
  gload16((const short*)A + aoff0, &smem[0][wid*512]);
  gload16((const short*)A + aoff1, &smem[0][(wid+4)*512]);
  gload16((const short*)W + boff,  &smem[0][4096 + wid*512]);
  __syncthreads();
  int cur = 0;
  for (int t=0; t<nt; t++){
    if (t+1 < nt){
      int k0 = (t+1)*32;
      gload16((const short*)A + aoff0 + k0, &smem[cur^1][wid*512]);
      gload16((const short*)A + aoff1 + k0, &smem[cur^1][(wid+4)*512]);
      gload16((const short*)W + boff  + k0, &smem[cur^1][4096 + wid*512]);
    }
    short8 a[4], b[2];
    #pragma unroll
    for (int mi=0;mi<4;mi++) a[mi] = *(const short8*)&smem[cur][afrag[mi]];
    #pragma unroll
    for (int nj=0;nj<2;nj++) b[nj] = *(const short8*)&smem[cur][bfrag[nj]];
    #pragma unroll
    for (int mi=0;mi<4;mi++)
      #pragma unroll
      for (int nj=0;nj<2;nj++)
        acc[mi][nj] = __builtin_amdgcn_mfma_f32_16x16x32_bf16(a[mi], b[nj], acc[mi][nj], 0,0,0);
    __syncthreads();
    cur ^= 1;
  }
  #pragma unroll
  for (int mi=0;mi<4;mi++){
    #pragma unroll
    for (int nj=0;nj<2;nj++){
      #pragma unroll
      for (int reg=0; reg<4; reg++){
        int row = m0 + wr*64 + mi*16 + kg*4 + reg;
        int col = n0 + wc*32 + nj*16 + r;
        float v = acc[mi][nj][reg];
        if (bias) v += bias[col];
        if (mask && mask[row]) v = 0.f;
        size_t o = (size_t)row*ldc + coloff + col;
        if (OUTBF) ((__hip_bfloat16*)Cout)[o] = __float2bfloat16(v);
        else       ((float*)Cout)[o] = v;
      }
    }
  }
}

// ---------------- mamba pieces ----------------

__global__ void k_dwconv(const float* __restrict__ xz, const float* __restrict__ cw,
                         const float* __restrict__ cb, float* __restrict__ u,
                         __hip_bfloat16* __restrict__ ub){
  int i = blockIdx.x*256 + threadIdx.x;
  if (i >= BL*DI) return;
  int d = i & (DI-1);
  int row = i >> 10;
  int l = row & 1023;
  int rb = row & ~1023;
  float acc = cb[d];
  #pragma unroll
  for (int k=0;k<4;k++){
    int ll = l - 3 + k;
    if (ll >= 0) acc += cw[d*4 + k] * xz[(size_t)(rb + ll)*(2*DI) + d];
  }
  float s = acc * sigmoidf_(acc);
  u[i] = s;
  ub[i] = __float2bfloat16(s);
}

__global__ void k_dtcast(const float* __restrict__ xdbc, __hip_bfloat16* __restrict__ dtb){
  int i = blockIdx.x*256 + threadIdx.x;
  if (i >= BL*DTR) return;
  int row = i >> 5, j = i & 31;
  dtb[i] = __float2bfloat16(xdbc[(size_t)row*64 + j]);
}

// -------- chunked selective scan, cache-line-exact mapping --------
// block = (b, chunk c, 16-d block); threads: n = t&15 (state), dd = t>>4 (d).
// Per step the block touches exactly one 64B line each of dy, u, xdbc, y.

__global__ __launch_bounds__(256) void k_scan_part(
    const float* __restrict__ A_log, const float* __restrict__ dy,
    const float* __restrict__ u, const float* __restrict__ xdbc,
    float* __restrict__ Hp, float* __restrict__ Pp){
  int t = threadIdx.x;
  int n = t & 15, dd = t >> 4;
  int dblk = blockIdx.x & 63;
  int c = (blockIdx.x >> 6) & 15;
  int b = blockIdx.x >> 10;
  int d = dblk*16 + dd;
  float Af = -__expf(A_log[d*NST + n]);
  float h = 0.f, P = 1.f;
  size_t blbase = (size_t)b*1024 + c*64;
  #pragma unroll 4
  for (int l=0; l<64; l++){
    size_t bl = blbase + l;
    float dv = dy[bl*DI + d];
    float uv = u[bl*DI + d];
    float Bv = xdbc[bl*64 + 32 + n];
    float dA = __expf(dv*Af);
    h = __fmaf_rn(dA, h, dv*Bv*uv);
    P *= dA;
  }
  size_t pair = (size_t)((b<<10)|d)*16 + c;
  Hp[pair*16 + n] = h;
  Pp[pair*16 + n] = P;
}

// combine: h_in[c+1] = P[c]*h_in[c] + H[c]; writes h_in back into Pp (in place)
__global__ void k_scan_comb(float* __restrict__ Hp, float* __restrict__ Pp){
  int i = blockIdx.x*256 + threadIdx.x;   // row*16 + n
  if (i >= BL*NST) return;
  int n = i & 15, row = i >> 4;
  float hin = 0.f;
  #pragma unroll
  for (int c=0;c<16;c++){
    size_t idx = ((size_t)row*16 + c)*16 + n;
    float P = Pp[idx], H = Hp[idx];
    Pp[idx] = hin;
    hin = __fmaf_rn(P, hin, H);
  }
}

__global__ __launch_bounds__(256) void k_scan_fin(
    const float* __restrict__ A_log, float* __restrict__ dy,
    const float* __restrict__ u, const float* __restrict__ xdbc,
    const float* __restrict__ Hin){
  int t = threadIdx.x;
  int n = t & 15, dd = t >> 4;
  int dblk = blockIdx.x & 63;
  int c = (blockIdx.x >> 6) & 15;
  int b = blockIdx.x >> 10;
  int d = dblk*16 + dd;
  float Af = -__expf(A_log[d*NST + n]);
  size_t pair = (size_t)((b<<10)|d)*16 + c;
  float h = Hin[pair*16 + n];
  size_t blbase = (size_t)b*1024 + c*64;
  #pragma unroll 4
  for (int l=0; l<64; l++){
    size_t bl = blbase + l;
    float dv = dy[bl*DI + d];
    float uv = u[bl*DI + d];
    float Bv = xdbc[bl*64 + 32 + n];
    float Cv = xdbc[bl*64 + 48 + n];
    float dA = __expf(dv*Af);
    h = __fmaf_rn(dA, h, dv*Bv*uv);
    float p = h * Cv;
    p += __shfl_xor(p, 1);
    p += __shfl_xor(p, 2);
    p += __shfl_xor(p, 4);
    p += __shfl_xor(p, 8);
    if (n == 0) dy[bl*DI + d] = p;
  }
}

__global__ void k_ygate(const float* __restrict__ y, const float* __restrict__ u,
                        const float* __restrict__ xz, const float* __restrict__ Dp,
                        __hip_bfloat16* __restrict__ yb){
  int i = blockIdx.x*256 + threadIdx.x;
  if (i >= BL*DI) return;
  int d = i & (DI-1);
  size_t row = (size_t)(i >> 10);
  float z = xz[row*(2*DI) + DI + d];
  float v = (y[i] + u[i]*Dp[d]) * (z * sigmoidf_(z));
  yb[i] = __float2bfloat16(v);
}

// ---------------- host ----------------

extern "C" void kernel_launch(void* const* d_in, const int* in_sizes, int n_in,
                              void* d_out, int out_size, void* d_ws, size_t ws_size,
                              hipStream_t stream){
  (void)in_sizes; (void)n_in; (void)out_size; (void)ws_size;
  const int*   x     = (const int*)d_in[0];
  const unsigned char* m = (const unsigned char*)d_in[2];
  const float* emb   = (const float*)d_in[3];
  const float* convw = (const float*)d_in[4];
  const float* convb = (const float*)d_in[5];
  const float* lng   = (const float*)d_in[6];
  const float* lnb   = (const float*)d_in[7];
  const float* projw = (const float*)d_in[8];
  const float* projb = (const float*)d_in[9];

  char* ws = (char*)d_ws;
  size_t off = 0;
  auto alloc = [&](size_t bytes)->char*{
    char* p = ws + off; off += (bytes + 255) & ~((size_t)255); return p;
  };
  auto wt_conv = (__hip_bfloat16*)alloc((size_t)3*CCH*CCH*5*2);
  __hip_bfloat16 *w_in[2], *w_x[2], *w_dt[2], *w_out[2];
  for (int dir=0; dir<2; dir++){
    w_in[dir]  = (__hip_bfloat16*)alloc((size_t)2*DI*CCH*2);
    w_x[dir]   = (__hip_bfloat16*)alloc((size_t)64*DI*2);
    w_dt[dir]  = (__hip_bfloat16*)alloc((size_t)DI*DTR*2);
    w_out[dir] = (__hip_bfloat16*)alloc((size_t)CCH*DI*2);
  }
  auto w_proj  = (__hip_bfloat16*)alloc((size_t)CCH*1024*2);
  auto xpad0   = (__hip_bfloat16*)alloc((size_t)BSZ*(LSEQ+4)*CCH*2);
  auto xpad1   = (__hip_bfloat16*)alloc((size_t)BSZ*(LSEQ+4)*CCH*2);
  auto convtmp = (float*)alloc((size_t)BL*CCH*4);       // conv out; later scan scratch
  auto h_enc   = (__hip_bfloat16*)alloc((size_t)BL*CCH*2);
  auto h_rev   = (__hip_bfloat16*)alloc((size_t)BL*CCH*2);
  auto xz      = (float*)alloc((size_t)BL*2*DI*4);
  auto u       = (float*)alloc((size_t)BL*DI*4);
  auto ub      = (__hip_bfloat16*)alloc((size_t)BL*DI*2);
  auto xdbc    = (float*)alloc((size_t)BL*64*4);
  auto dtb     = (__hip_bfloat16*)alloc((size_t)BL*DTR*2);
  auto dy      = (float*)alloc((size_t)BL*DI*4);        // delta in, y out (in place)
  auto yb      = (__hip_bfloat16*)alloc((size_t)BL*DI*2);
  auto fob     = (__hip_bfloat16*)alloc((size_t)BL*DI*2);

  float* Hp = convtmp;
  float* Pp = convtmp + (size_t)1048576;

  auto nb = [](size_t n){ return (unsigned)((n + 255)/256); };

  // --- weight prep ---
  k_prep_convw<<<dim3(nb((size_t)3*CCH*CCH*5)), dim3(256), 0, stream>>>(convw, wt_conv);
  for (int dir=0; dir<2; dir++){
    int base = 10 + 9*dir;
    k_cast_b4<<<dim3(nb((size_t)2*DI*CCH/4)), dim3(256), 0, stream>>>((const float*)d_in[base+0], (unsigned short*)w_in[dir], 2*DI*CCH/4);
    k_cast_b4<<<dim3(nb((size_t)64*DI/4)),    dim3(256), 0, stream>>>((const float*)d_in[base+3], (unsigned short*)w_x[dir], 64*DI/4);
    k_cast_b4<<<dim3(nb((size_t)DI*DTR/4)),   dim3(256), 0, stream>>>((const float*)d_in[base+4], (unsigned short*)w_dt[dir], DI*DTR/4);
    k_cast_b4<<<dim3(nb((size_t)CCH*DI/4)),   dim3(256), 0, stream>>>((const float*)d_in[base+8], (unsigned short*)w_out[dir], CCH*DI/4);
  }
  k_cast_b4<<<dim3(nb((size_t)CCH*1024/4)), dim3(256), 0, stream>>>(projw, (unsigned short*)w_proj, CCH*1024/4);

  auto gemm_small = [&](const void* A, int lda, int padE, const void* W, void* C, int ldc, int coloff,
                  int M, int N, int K, const float* bias, int act, const unsigned char* msk, bool outbf){
    int blocks = (M/64)*(N/64);
    if (outbf)
      k_gemm<true><<<dim3(blocks), dim3(64), 0, stream>>>((const __hip_bfloat16*)A, lda, padE,
          (const __hip_bfloat16*)W, C, ldc, coloff, N, K, bias, act, msk);
    else
      k_gemm<false><<<dim3(blocks), dim3(64), 0, stream>>>((const __hip_bfloat16*)A, lda, padE,
          (const __hip_bfloat16*)W, C, ldc, coloff, N, K, bias, act, msk);
  };
  auto gemm_big = [&](const void* A, int lda, int padE, const void* W, void* C, int ldc, int coloff,
                  int M, int N, int K, const float* bias, const unsigned char* msk, bool outbf){
    int tiles_n = N/64;
    int blocks = (M/128)*tiles_n;
    if (outbf)
      k_gemm_big<true><<<dim3(blocks), dim3(256), 0, stream>>>((const __hip_bfloat16*)A, lda, padE,
          (const __hip_bfloat16*)W, C, ldc, coloff, tiles_n, K, bias, msk);
    else
      k_gemm_big<false><<<dim3(blocks), dim3(256), 0, stream>>>((const __hip_bfloat16*)A, lda, padE,
          (const __hip_bfloat16*)W, C, ldc, coloff, tiles_n, K, bias, msk);
  };

  // --- encoder: embed + 3x (conv-as-GEMM -> LN/leaky/mask) ---
  k_embed<<<dim3(nb((size_t)BSZ*(LSEQ+4)*CCH)), dim3(256), 0, stream>>>(x, emb, xpad0);
  k_zero_pads<<<dim3(nb((size_t)BSZ*4*CCH)), dim3(256), 0, stream>>>(xpad1);

  __hip_bfloat16* xp_in = xpad0;
  __hip_bfloat16* xp_out = xpad1;
  for (int layer=0; layer<3; layer++){
    gemm_big(xp_in, CCH, 4, wt_conv + (size_t)layer*CCH*CCH*5, convtmp, CCH, 0,
         BL, CCH, CCH*5, convb + layer*CCH, nullptr, false);
    bool last = (layer==2);
    k_ln<<<dim3(BL), dim3(256), 0, stream>>>(convtmp, lng + layer*CCH, lnb + layer*CCH, m,
        last ? nullptr : xp_out, last ? h_enc : nullptr, last ? h_rev : nullptr);
    __hip_bfloat16* t2 = xp_in; xp_in = xp_out; xp_out = t2;
  }

  // --- bidirectional mamba ---
  for (int dir=0; dir<2; dir++){
    int base = 10 + 9*dir;
    const float* mcw    = (const float*)d_in[base+1];
    const float* mcb    = (const float*)d_in[base+2];
    const float* dtbias = (const float*)d_in[base+5];
    const float* Alog   = (const float*)d_in[base+6];
    const float* Dp     = (const float*)d_in[base+7];
    const __hip_bfloat16* hin = (dir==0) ? h_enc : h_rev;

    gemm_big(hin, CCH, 0, w_in[dir], xz, 2*DI, 0, BL, 2*DI, CCH, nullptr, nullptr, false);
    k_dwconv<<<dim3(nb((size_t)BL*DI)), dim3(256), 0, stream>>>(xz, mcw, mcb, u, ub);
    k_gemm_ksplit<<<dim3(BL/64), dim3(256), 0, stream>>>(ub, DI, w_x[dir], xdbc, 64, DI);
    k_dtcast<<<dim3(nb((size_t)BL*DTR)), dim3(256), 0, stream>>>(xdbc, dtb);
    gemm_small(dtb, DTR, 0, w_dt[dir], dy, DI, 0, BL, DI, DTR, dtbias, 1, nullptr, false);
    k_scan_part<<<dim3(4096), dim3(256), 0, stream>>>(Alog, dy, u, xdbc, Hp, Pp);
    k_scan_comb<<<dim3(nb((size_t)BL*NST)), dim3(256), 0, stream>>>(Hp, Pp);
    k_scan_fin<<<dim3(4096), dim3(256), 0, stream>>>(Alog, dy, u, xdbc, Pp);
    k_ygate<<<dim3(nb((size_t)BL*DI)), dim3(256), 0, stream>>>(dy, u, xz, Dp, yb);
    gemm_big(yb, DI, 0, w_out[dir], fob, DI, (dir==0)?0:512, BL, CCH, DI, nullptr, nullptr, true);
  }

  // --- final projection + bias + mask -> d_out (f32) ---
  gemm_big(fob, DI, 0, w_proj, d_out, CCH, 0, BL, CCH, DI, projb, m, false);
}

// Round 4
// 498.188 us; speedup vs baseline: 2.9871x; 1.2350x over previous
//
#include <hip/hip_runtime.h>
#include <hip/hip_bf16.h>

typedef __attribute__((ext_vector_type(8))) short short8;
typedef __attribute__((ext_vector_type(4))) float f32x4;
typedef __attribute__((ext_vector_type(4))) unsigned short ushort4_t;

#define BSZ 4
#define LSEQ 1024
#define CCH 512
#define BL (BSZ*LSEQ)   // 4096 rows
#define DI 1024         // d_inner
#define NST 16
#define DTR 32
#define NCH 32          // scan chunks
#define CLEN 32         // chunk length (NCH*CLEN == LSEQ)

__device__ __forceinline__ float sigmoidf_(float x){ return 1.f/(1.f+__expf(-x)); }
__device__ __forceinline__ float softplus_(float x){ return x > 20.f ? x : log1pf(__expf(x)); }
__device__ __forceinline__ unsigned short f2bf_(float f){
  __hip_bfloat16 h = __float2bfloat16(f); return *(unsigned short*)&h;
}

typedef const __attribute__((address_space(1))) unsigned int* gas_t;
typedef __attribute__((address_space(3))) unsigned int* las_t;
__device__ __forceinline__ void gload16(const void* g, void* l){
  __builtin_amdgcn_global_load_lds((gas_t)g, (las_t)l, 16, 0, 0);
}

// ---------------- prep / elementwise kernels ----------------

__global__ void k_cast_b4(const float* __restrict__ s, unsigned short* __restrict__ d, int n4){
  int i = blockIdx.x*256 + threadIdx.x;
  if (i >= n4) return;
  float4 v = ((const float4*)s)[i];
  ushort4_t o = { f2bf_(v.x), f2bf_(v.y), f2bf_(v.z), f2bf_(v.w) };
  *(ushort4_t*)(d + (size_t)i*4) = o;
}

// conv_w [3][512][512][5] -> wt [3][512][2560], j = k*512 + ci  (matches contiguous patch)
__global__ void k_prep_convw(const float* __restrict__ cw, __hip_bfloat16* __restrict__ wt){
  int i = blockIdx.x*256 + threadIdx.x;
  const int total = 3*CCH*CCH*5;
  if (i >= total) return;
  int j = i % (CCH*5);
  int co = (i/(CCH*5)) % CCH;
  int layer = i/(CCH*5*CCH);
  int k = j >> 9, ci = j & 511;
  wt[i] = __float2bfloat16(cw[(((size_t)layer*CCH + co)*CCH + ci)*5 + k]);
}

// gather emb[x] into padded [B][L+4][C] bf16 (2 zero rows each side for K=5 conv)
__global__ void k_embed(const int* __restrict__ x, const float* __restrict__ emb,
                        __hip_bfloat16* __restrict__ xpad){
  int i = blockIdx.x*256 + threadIdx.x;
  const int total = BSZ*(LSEQ+4)*CCH;
  if (i >= total) return;
  int c = i & (CCH-1);
  int r = (i >> 9) % (LSEQ+4);
  int b = i / ((LSEQ+4)*CCH);
  float v = 0.f;
  if (r >= 2 && r < LSEQ+2){
    int tok = x[b*LSEQ + (r-2)];
    v = emb[(size_t)tok*CCH + c];
  }
  xpad[i] = __float2bfloat16(v);
}

__global__ void k_zero_pads(__hip_bfloat16* __restrict__ xpad){
  int i = blockIdx.x*256 + threadIdx.x;
  const int total = BSZ*4*CCH;
  if (i >= total) return;
  int c = i & (CCH-1);
  int pr = (i >> 9) & 3;
  int b = i >> 11;
  int r = (pr < 2) ? pr : (LSEQ+2) + (pr-2);
  xpad[((size_t)b*(LSEQ+4) + r)*CCH + c] = __float2bfloat16(0.f);
}

// per-(b,l) channel LayerNorm + scale/shift + LeakyReLU(0.2) + mask
__global__ __launch_bounds__(256) void k_ln(
    const float* __restrict__ in, const float* __restrict__ g, const float* __restrict__ bb,
    const unsigned char* __restrict__ mask,
    __hip_bfloat16* __restrict__ xpad_next,
    __hip_bfloat16* __restrict__ h_enc, __hip_bfloat16* __restrict__ h_rev){
  int row = blockIdx.x;                 // b*1024 + l
  int b = row >> 10, l = row & 1023;
  const float* xr = in + (size_t)row*CCH;
  int t = threadIdx.x;
  float v0 = xr[t], v1 = xr[t+256];
  float s = v0+v1, s2 = v0*v0 + v1*v1;
  #pragma unroll
  for (int off=32; off>0; off>>=1){ s += __shfl_down(s,off); s2 += __shfl_down(s2,off); }
  __shared__ float ls[8];
  if ((t&63)==0){ ls[t>>6] = s; ls[(t>>6)+4] = s2; }
  __syncthreads();
  float S  = ls[0]+ls[1]+ls[2]+ls[3];
  float S2 = ls[4]+ls[5]+ls[6]+ls[7];
  float mu = S*(1.f/CCH);
  float var = S2*(1.f/CCH) - mu*mu;
  float rs = rsqrtf(var + 1e-5f);
  bool mk = mask[row] != 0;
  #pragma unroll
  for (int e=0; e<2; e++){
    int c = t + e*256;
    float v = e ? v1 : v0;
    float h = (v-mu)*rs*g[c] + bb[c];
    h = h > 0.f ? h : 0.2f*h;
    if (mk) h = 0.f;
    __hip_bfloat16 hb = __float2bfloat16(h);
    if (xpad_next) xpad_next[((size_t)b*(LSEQ+4) + (l+2))*CCH + c] = hb;
    if (h_enc) h_enc[(size_t)row*CCH + c] = hb;
    if (h_rev) h_rev[((size_t)(b<<10) + (1023-l))*CCH + c] = hb;
  }
}

// ---------------- small MFMA wave-GEMM (dt_proj K=32) ----------------
template<bool OUTBF>
__global__ __launch_bounds__(64) void k_gemm(
    const __hip_bfloat16* __restrict__ A, int lda, int padExtra,
    const __hip_bfloat16* __restrict__ W, void* __restrict__ Cout,
    int ldc, int coloff, int N, int K,
    const float* __restrict__ bias, int act,
    const unsigned char* __restrict__ mask){
  int tiles_n = N >> 6;
  int tn = blockIdx.x % tiles_n;
  int tm = blockIdx.x / tiles_n;
  int m0 = tm << 6, n0 = tn << 6;
  int lane = threadIdx.x;
  int r = lane & 15, kg = lane >> 4;

  const short* Ap[4];
  const short* Wp[4];
  #pragma unroll
  for (int mi=0; mi<4; mi++){
    int row = m0 + mi*16 + r;
    int phys = row + padExtra*(row >> 10);
    Ap[mi] = (const short*)A + (size_t)phys*lda + kg*8;
  }
  #pragma unroll
  for (int nj=0; nj<4; nj++){
    int col = n0 + nj*16 + r;
    Wp[nj] = (const short*)W + (size_t)col*K + kg*8;
  }
  f32x4 acc[4][4];
  #pragma unroll
  for (int mi=0;mi<4;mi++)
    #pragma unroll
    for (int nj=0;nj<4;nj++) acc[mi][nj] = (f32x4){0.f,0.f,0.f,0.f};

  for (int kk=0; kk<K; kk+=32){
    short8 a[4], w[4];
    #pragma unroll
    for (int mi=0;mi<4;mi++) a[mi] = *(const short8*)(Ap[mi] + kk);
    #pragma unroll
    for (int nj=0;nj<4;nj++) w[nj] = *(const short8*)(Wp[nj] + kk);
    #pragma unroll
    for (int mi=0;mi<4;mi++)
      #pragma unroll
      for (int nj=0;nj<4;nj++)
        acc[mi][nj] = __builtin_amdgcn_mfma_f32_16x16x32_bf16(a[mi], w[nj], acc[mi][nj], 0,0,0);
  }
  #pragma unroll
  for (int mi=0;mi<4;mi++){
    #pragma unroll
    for (int nj=0;nj<4;nj++){
      #pragma unroll
      for (int reg=0; reg<4; reg++){
        int row = m0 + mi*16 + kg*4 + reg;
        int col = n0 + nj*16 + r;
        float v = acc[mi][nj][reg];
        if (bias) v += bias[col];
        if (act == 1) v = softplus_(v);
        if (mask && mask[row]) v = 0.f;
        size_t o = (size_t)row*ldc + coloff + col;
        if (OUTBF) ((__hip_bfloat16*)Cout)[o] = __float2bfloat16(v);
        else       ((float*)Cout)[o] = v;
      }
    }
  }
}

// ---------------- K-split GEMM for skinny N=64 (x_proj), fused dt bf16 extract --------
__global__ __launch_bounds__(256) void k_gemm_ksplit(
    const __hip_bfloat16* __restrict__ A, int lda,
    const __hip_bfloat16* __restrict__ W, float* __restrict__ Cout,
    int ldc, int K, unsigned short* __restrict__ dtb){
  __shared__ float red[4*4096];   // 64 KB
  int m0 = blockIdx.x << 6;
  int tid = threadIdx.x;
  int w = tid >> 6, lane = tid & 63;
  int r = lane & 15, kg = lane >> 4;
  int Kw = K >> 2;
  int kbase = w*Kw;

  const short* Ap[4];
  const short* Wp[4];
  #pragma unroll
  for (int mi=0; mi<4; mi++)
    Ap[mi] = (const short*)A + (size_t)(m0 + mi*16 + r)*lda + kbase + kg*8;
  #pragma unroll
  for (int nj=0; nj<4; nj++)
    Wp[nj] = (const short*)W + (size_t)(nj*16 + r)*K + kbase + kg*8;

  f32x4 acc[4][4];
  #pragma unroll
  for (int mi=0;mi<4;mi++)
    #pragma unroll
    for (int nj=0;nj<4;nj++) acc[mi][nj] = (f32x4){0.f,0.f,0.f,0.f};

  for (int kk=0; kk<Kw; kk+=32){
    short8 a[4], wv[4];
    #pragma unroll
    for (int mi=0;mi<4;mi++) a[mi] = *(const short8*)(Ap[mi] + kk);
    #pragma unroll
    for (int nj=0;nj<4;nj++) wv[nj] = *(const short8*)(Wp[nj] + kk);
    #pragma unroll
    for (int mi=0;mi<4;mi++)
      #pragma unroll
      for (int nj=0;nj<4;nj++)
        acc[mi][nj] = __builtin_amdgcn_mfma_f32_16x16x32_bf16(a[mi], wv[nj], acc[mi][nj], 0,0,0);
  }
  #pragma unroll
  for (int mi=0;mi<4;mi++)
    #pragma unroll
    for (int nj=0;nj<4;nj++)
      #pragma unroll
      for (int reg=0; reg<4; reg++){
        int rowt = mi*16 + kg*4 + reg;
        int col  = nj*16 + r;
        red[w*4096 + rowt*64 + col] = acc[mi][nj][reg];
      }
  __syncthreads();
  int e0 = tid*16;
  #pragma unroll
  for (int j=0; j<16; j+=4){
    f32x4 s = *(const f32x4*)&red[e0+j];
    #pragma unroll
    for (int ww=1; ww<4; ww++){
      f32x4 p = *(const f32x4*)&red[ww*4096 + e0 + j];
      s.x += p.x; s.y += p.y; s.z += p.z; s.w += p.w;
    }
    int e = e0 + j;
    int rowt = e >> 6, col = e & 63;
    *(f32x4*)&Cout[(size_t)(m0+rowt)*ldc + col] = s;
    if (col < 32){
      ushort4_t o = { f2bf_(s.x), f2bf_(s.y), f2bf_(s.z), f2bf_(s.w) };
      *(ushort4_t*)&dtb[(size_t)(m0+rowt)*32 + col] = o;
    }
  }
}

// ---------------- big staged GEMM: 128(M)x64(N) tile, BK=32, 4 waves, dbuf LDS ----------
template<bool OUTBF>
__global__ __launch_bounds__(256) void k_gemm_big(
    const __hip_bfloat16* __restrict__ A, int lda, int padExtra,
    const __hip_bfloat16* __restrict__ W, void* __restrict__ Cout,
    int ldc, int coloff, int tiles_n, int K,
    const float* __restrict__ bias, const unsigned char* __restrict__ mask){
  __shared__ alignas(16) __hip_bfloat16 smem[2][6144];   // 2 x (4096 A + 2048 B)
  int tn = blockIdx.x % tiles_n;
  int tm = blockIdx.x / tiles_n;
  int m0 = tm*128, n0 = tn*64;
  int tid = threadIdx.x;
  int wid = tid >> 6, lane = tid & 63;
  int r = lane & 15, kg = lane >> 4;

  int sr = lane >> 2;
  int gs = (lane & 3) ^ (sr & 3);
  int row0 = m0 + wid*16 + sr;
  int row1 = row0 + 64;
  int p0 = row0 + padExtra*(row0 >> 10);
  int p1 = row1 + padExtra*(row1 >> 10);
  size_t aoff0 = (size_t)p0*lda + gs*8;
  size_t aoff1 = (size_t)p1*lda + gs*8;
  int bcol = n0 + wid*16 + sr;
  size_t boff = (size_t)bcol*K + gs*8;

  int wr = wid >> 1, wc = wid & 1;
  int xs = (kg ^ (r & 3))*8;
  int afrag[4], bfrag[2];
  #pragma unroll
  for (int mi=0; mi<4; mi++) afrag[mi] = (wr*64 + mi*16 + r)*32 + xs;
  #pragma unroll
  for (int nj=0; nj<2; nj++) bfrag[nj] = 4096 + (wc*32 + nj*16 + r)*32 + xs;

  f32x4 acc[4][2];
  #pragma unroll
  for (int mi=0;mi<4;mi++)
    #pragma unroll
    for (int nj=0;nj<2;nj++) acc[mi][nj] = (f32x4){0.f,0.f,0.f,0.f};

  const int nt = K >> 5;
  gload16((const short*)A + aoff0, &smem[0][wid*512]);
  gload16((const short*)A + aoff1, &smem[0][(wid+4)*512]);
  gload16((const short*)W + boff,  &smem[0][4096 + wid*512]);
  __syncthreads();
  int cur = 0;
  for (int t=0; t<nt; t++){
    if (t+1 < nt){
      int k0 = (t+1)*32;
      gload16((const short*)A + aoff0 + k0, &smem[cur^1][wid*512]);
      gload16((const short*)A + aoff1 + k0, &smem[cur^1][(wid+4)*512]);
      gload16((const short*)W + boff  + k0, &smem[cur^1][4096 + wid*512]);
    }
    short8 a[4], b[2];
    #pragma unroll
    for (int mi=0;mi<4;mi++) a[mi] = *(const short8*)&smem[cur][afrag[mi]];
    #pragma unroll
    for (int nj=0;nj<2;nj++) b[nj] = *(const short8*)&smem[cur][bfrag[nj]];
    #pragma unroll
    for (int mi=0;mi<4;mi++)
      #pragma unroll
      for (int nj=0;nj<2;nj++)
        acc[mi][nj] = __builtin_amdgcn_mfma_f32_16x16x32_bf16(a[mi], b[nj], acc[mi][nj], 0,0,0);
    __syncthreads();
    cur ^= 1;
  }
  #pragma unroll
  for (int mi=0;mi<4;mi++){
    #pragma unroll
    for (int nj=0;nj<2;nj++){
      #pragma unroll
      for (int reg=0; reg<4; reg++){
        int row = m0 + wr*64 + mi*16 + kg*4 + reg;
        int col = n0 + wc*32 + nj*16 + r;
        float v = acc[mi][nj][reg];
        if (bias) v += bias[col];
        if (mask && mask[row]) v = 0.f;
        size_t o = (size_t)row*ldc + coloff + col;
        if (OUTBF) ((__hip_bfloat16*)Cout)[o] = __float2bfloat16(v);
        else       ((float*)Cout)[o] = v;
      }
    }
  }
}

// ---------------- mamba pieces ----------------

__global__ void k_dwconv(const float* __restrict__ xz, const float* __restrict__ cw,
                         const float* __restrict__ cb, float* __restrict__ u,
                         __hip_bfloat16* __restrict__ ub){
  int i = blockIdx.x*256 + threadIdx.x;
  if (i >= BL*DI) return;
  int d = i & (DI-1);
  int row = i >> 10;
  int l = row & 1023;
  int rb = row & ~1023;
  float acc = cb[d];
  #pragma unroll
  for (int k=0;k<4;k++){
    int ll = l - 3 + k;
    if (ll >= 0) acc += cw[d*4 + k] * xz[(size_t)(rb + ll)*(2*DI) + d];
  }
  float s = acc * sigmoidf_(acc);
  u[i] = s;
  ub[i] = __float2bfloat16(s);
}

// -------- chunked selective scan, thread-per-d, state vector in registers --------
// block = (b, chunk c, 256-d block); NCH=32 chunks of CLEN=32.
// B (and C for fin) rows are block-uniform -> staged in LDS, broadcast reads.

__global__ __launch_bounds__(256) void k_scan_part(
    const float* __restrict__ A_log, const float* __restrict__ dy,
    const float* __restrict__ u, const float* __restrict__ xdbc,
    float* __restrict__ Hp, float* __restrict__ Pp){
  __shared__ alignas(16) float Bsh[CLEN*16];
  int t = threadIdx.x;
  int dblk = blockIdx.x & 3;
  int c = (blockIdx.x >> 2) & (NCH-1);
  int b = blockIdx.x >> 7;
  int d = dblk*256 + t;
  size_t blbase = (size_t)b*LSEQ + (size_t)c*CLEN;
  if (t < CLEN*4){
    int l = t >> 2, q = t & 3;
    *(f32x4*)&Bsh[l*16 + q*4] = *(const f32x4*)&xdbc[(blbase+l)*64 + 32 + q*4];
  }
  float Af[16];
  #pragma unroll
  for (int n=0; n<16; n+=4){
    f32x4 a = *(const f32x4*)&A_log[(size_t)d*16 + n];
    Af[n]   = -__expf(a.x); Af[n+1] = -__expf(a.y);
    Af[n+2] = -__expf(a.z); Af[n+3] = -__expf(a.w);
  }
  float h[16], P[16];
  #pragma unroll
  for (int n=0;n<16;n++){ h[n]=0.f; P[n]=1.f; }
  __syncthreads();
  float dv = dy[blbase*DI + d];
  float uv = u[blbase*DI + d];
  for (int l=0; l<CLEN; l++){
    float dvn = 0.f, uvn = 0.f;
    if (l+1 < CLEN){
      dvn = dy[(blbase+l+1)*DI + d];
      uvn = u[(blbase+l+1)*DI + d];
    }
    float duv = dv*uv;
    #pragma unroll
    for (int n=0;n<16;n++){
      float dA = __expf(dv*Af[n]);
      h[n] = __fmaf_rn(dA, h[n], duv*Bsh[l*16+n]);
      P[n] *= dA;
    }
    dv = dvn; uv = uvn;
  }
  size_t pb = (((size_t)(b*NCH + c))*DI + d)*16;
  #pragma unroll
  for (int n=0;n<16;n+=4){
    *(f32x4*)&Hp[pb+n] = (f32x4){h[n],h[n+1],h[n+2],h[n+3]};
    *(f32x4*)&Pp[pb+n] = (f32x4){P[n],P[n+1],P[n+2],P[n+3]};
  }
}

// combine: h_in[c+1] = P[c]*h_in[c] + H[c]; writes h_in back into Pp (in place)
__global__ void k_scan_comb(float* __restrict__ Hp, float* __restrict__ Pp){
  int i = blockIdx.x*256 + threadIdx.x;   // (b*1024+d)*16 + n
  if (i >= BL*NST) return;
  int n = i & 15, row = i >> 4;
  int b = row >> 10, d = row & 1023;
  float hin = 0.f;
  #pragma unroll
  for (int c=0;c<NCH;c++){
    size_t idx = (((size_t)(b*NCH + c))*DI + d)*16 + n;
    float P = Pp[idx], H = Hp[idx];
    Pp[idx] = hin;
    hin = __fmaf_rn(P, hin, H);
  }
}

// final pass: recompute chunk states from h_in, emit y fused with ygate -> yb (bf16)
__global__ __launch_bounds__(256) void k_scan_fin(
    const float* __restrict__ A_log, const float* __restrict__ dy,
    const float* __restrict__ u, const float* __restrict__ xdbc,
    const float* __restrict__ Hin, const float* __restrict__ xz,
    const float* __restrict__ Dp, __hip_bfloat16* __restrict__ yb){
  __shared__ alignas(16) float BCsh[CLEN*32];
  int t = threadIdx.x;
  int dblk = blockIdx.x & 3;
  int c = (blockIdx.x >> 2) & (NCH-1);
  int b = blockIdx.x >> 7;
  int d = dblk*256 + t;
  size_t blbase = (size_t)b*LSEQ + (size_t)c*CLEN;
  {
    int l = t >> 3, q = t & 7;   // 256 threads cover 32 rows x 8 quads
    *(f32x4*)&BCsh[l*32 + q*4] = *(const f32x4*)&xdbc[(blbase+l)*64 + 32 + q*4];
  }
  float Af[16];
  #pragma unroll
  for (int n=0; n<16; n+=4){
    f32x4 a = *(const f32x4*)&A_log[(size_t)d*16 + n];
    Af[n]   = -__expf(a.x); Af[n+1] = -__expf(a.y);
    Af[n+2] = -__expf(a.z); Af[n+3] = -__expf(a.w);
  }
  size_t pb = (((size_t)(b*NCH + c))*DI + d)*16;
  float h[16];
  #pragma unroll
  for (int n=0;n<16;n+=4){
    f32x4 hv = *(const f32x4*)&Hin[pb+n];
    h[n]=hv.x; h[n+1]=hv.y; h[n+2]=hv.z; h[n+3]=hv.w;
  }
  float Dd = Dp[d];
  __syncthreads();
  float dv = dy[blbase*DI + d];
  float uv = u[blbase*DI + d];
  float zv = xz[blbase*(2*DI) + DI + d];
  for (int l=0; l<CLEN; l++){
    float dvn = 0.f, uvn = 0.f, zvn = 0.f;
    if (l+1 < CLEN){
      dvn = dy[(blbase+l+1)*DI + d];
      uvn = u[(blbase+l+1)*DI + d];
      zvn = xz[(blbase+l+1)*(2*DI) + DI + d];
    }
    float duv = dv*uv;
    float y = 0.f;
    #pragma unroll
    for (int n=0;n<16;n++){
      float dA = __expf(dv*Af[n]);
      h[n] = __fmaf_rn(dA, h[n], duv*BCsh[l*32+n]);
      y = __fmaf_rn(h[n], BCsh[l*32+16+n], y);
    }
    float g = zv * sigmoidf_(zv);
    float out = __fmaf_rn(uv, Dd, y) * g;
    yb[(blbase+l)*DI + d] = __float2bfloat16(out);
    dv = dvn; uv = uvn; zv = zvn;
  }
}

// ---------------- host ----------------

extern "C" void kernel_launch(void* const* d_in, const int* in_sizes, int n_in,
                              void* d_out, int out_size, void* d_ws, size_t ws_size,
                              hipStream_t stream){
  (void)in_sizes; (void)n_in; (void)out_size; (void)ws_size;
  const int*   x     = (const int*)d_in[0];
  const unsigned char* m = (const unsigned char*)d_in[2];
  const float* emb   = (const float*)d_in[3];
  const float* convw = (const float*)d_in[4];
  const float* convb = (const float*)d_in[5];
  const float* lng   = (const float*)d_in[6];
  const float* lnb   = (const float*)d_in[7];
  const float* projw = (const float*)d_in[8];
  const float* projb = (const float*)d_in[9];

  char* ws = (char*)d_ws;
  size_t off = 0;
  auto alloc = [&](size_t bytes)->char*{
    char* p = ws + off; off += (bytes + 255) & ~((size_t)255); return p;
  };
  auto wt_conv = (__hip_bfloat16*)alloc((size_t)3*CCH*CCH*5*2);
  __hip_bfloat16 *w_in[2], *w_x[2], *w_dt[2], *w_out[2];
  for (int dir=0; dir<2; dir++){
    w_in[dir]  = (__hip_bfloat16*)alloc((size_t)2*DI*CCH*2);
    w_x[dir]   = (__hip_bfloat16*)alloc((size_t)64*DI*2);
    w_dt[dir]  = (__hip_bfloat16*)alloc((size_t)DI*DTR*2);
    w_out[dir] = (__hip_bfloat16*)alloc((size_t)CCH*DI*2);
  }
  auto w_proj  = (__hip_bfloat16*)alloc((size_t)CCH*1024*2);
  auto xpad0   = (__hip_bfloat16*)alloc((size_t)BSZ*(LSEQ+4)*CCH*2);
  auto xpad1   = (__hip_bfloat16*)alloc((size_t)BSZ*(LSEQ+4)*CCH*2);
  auto convtmp = (float*)alloc((size_t)BL*CCH*4);       // conv out; later Hp (8 MB)
  auto h_enc   = (__hip_bfloat16*)alloc((size_t)BL*CCH*2);
  auto h_rev   = (__hip_bfloat16*)alloc((size_t)BL*CCH*2);
  auto xz      = (float*)alloc((size_t)BL*2*DI*4);
  auto u       = (float*)alloc((size_t)BL*DI*4);
  auto ub      = (__hip_bfloat16*)alloc((size_t)BL*DI*2);
  auto xdbc    = (float*)alloc((size_t)BL*64*4);
  auto dtb     = (unsigned short*)alloc((size_t)BL*DTR*2);
  auto dy      = (float*)alloc((size_t)BL*DI*4);        // delta (read-only in scan)
  auto yb      = (__hip_bfloat16*)alloc((size_t)BL*DI*2);
  auto fob     = (__hip_bfloat16*)alloc((size_t)BL*DI*2);

  // scan scratch: Hp reuses convtmp (8 MB); Pp reuses xpad0+xpad1 region (8.4 MB,
  // contiguous in ws, dead after the encoder finishes).
  float* Hp = convtmp;
  float* Pp = (float*)xpad0;

  auto nb = [](size_t n){ return (unsigned)((n + 255)/256); };

  // --- weight prep ---
  k_prep_convw<<<dim3(nb((size_t)3*CCH*CCH*5)), dim3(256), 0, stream>>>(convw, wt_conv);
  for (int dir=0; dir<2; dir++){
    int base = 10 + 9*dir;
    k_cast_b4<<<dim3(nb((size_t)2*DI*CCH/4)), dim3(256), 0, stream>>>((const float*)d_in[base+0], (unsigned short*)w_in[dir], 2*DI*CCH/4);
    k_cast_b4<<<dim3(nb((size_t)64*DI/4)),    dim3(256), 0, stream>>>((const float*)d_in[base+3], (unsigned short*)w_x[dir], 64*DI/4);
    k_cast_b4<<<dim3(nb((size_t)DI*DTR/4)),   dim3(256), 0, stream>>>((const float*)d_in[base+4], (unsigned short*)w_dt[dir], DI*DTR/4);
    k_cast_b4<<<dim3(nb((size_t)CCH*DI/4)),   dim3(256), 0, stream>>>((const float*)d_in[base+8], (unsigned short*)w_out[dir], CCH*DI/4);
  }
  k_cast_b4<<<dim3(nb((size_t)CCH*1024/4)), dim3(256), 0, stream>>>(projw, (unsigned short*)w_proj, CCH*1024/4);

  auto gemm_small = [&](const void* A, int lda, int padE, const void* W, void* C, int ldc, int coloff,
                  int M, int N, int K, const float* bias, int act, const unsigned char* msk, bool outbf){
    int blocks = (M/64)*(N/64);
    if (outbf)
      k_gemm<true><<<dim3(blocks), dim3(64), 0, stream>>>((const __hip_bfloat16*)A, lda, padE,
          (const __hip_bfloat16*)W, C, ldc, coloff, N, K, bias, act, msk);
    else
      k_gemm<false><<<dim3(blocks), dim3(64), 0, stream>>>((const __hip_bfloat16*)A, lda, padE,
          (const __hip_bfloat16*)W, C, ldc, coloff, N, K, bias, act, msk);
  };
  auto gemm_big = [&](const void* A, int lda, int padE, const void* W, void* C, int ldc, int coloff,
                  int M, int N, int K, const float* bias, const unsigned char* msk, bool outbf){
    int tiles_n = N/64;
    int blocks = (M/128)*tiles_n;
    if (outbf)
      k_gemm_big<true><<<dim3(blocks), dim3(256), 0, stream>>>((const __hip_bfloat16*)A, lda, padE,
          (const __hip_bfloat16*)W, C, ldc, coloff, tiles_n, K, bias, msk);
    else
      k_gemm_big<false><<<dim3(blocks), dim3(256), 0, stream>>>((const __hip_bfloat16*)A, lda, padE,
          (const __hip_bfloat16*)W, C, ldc, coloff, tiles_n, K, bias, msk);
  };

  // --- encoder: embed + 3x (conv-as-GEMM -> LN/leaky/mask) ---
  k_embed<<<dim3(nb((size_t)BSZ*(LSEQ+4)*CCH)), dim3(256), 0, stream>>>(x, emb, xpad0);
  k_zero_pads<<<dim3(nb((size_t)BSZ*4*CCH)), dim3(256), 0, stream>>>(xpad1);

  __hip_bfloat16* xp_in = xpad0;
  __hip_bfloat16* xp_out = xpad1;
  for (int layer=0; layer<3; layer++){
    gemm_big(xp_in, CCH, 4, wt_conv + (size_t)layer*CCH*CCH*5, convtmp, CCH, 0,
         BL, CCH, CCH*5, convb + layer*CCH, nullptr, false);
    bool last = (layer==2);
    k_ln<<<dim3(BL), dim3(256), 0, stream>>>(convtmp, lng + layer*CCH, lnb + layer*CCH, m,
        last ? nullptr : xp_out, last ? h_enc : nullptr, last ? h_rev : nullptr);
    __hip_bfloat16* t2 = xp_in; xp_in = xp_out; xp_out = t2;
  }

  // --- bidirectional mamba ---
  for (int dir=0; dir<2; dir++){
    int base = 10 + 9*dir;
    const float* mcw    = (const float*)d_in[base+1];
    const float* mcb    = (const float*)d_in[base+2];
    const float* dtbias = (const float*)d_in[base+5];
    const float* Alog   = (const float*)d_in[base+6];
    const float* Dp     = (const float*)d_in[base+7];
    const __hip_bfloat16* hin = (dir==0) ? h_enc : h_rev;

    gemm_big(hin, CCH, 0, w_in[dir], xz, 2*DI, 0, BL, 2*DI, CCH, nullptr, nullptr, false);
    k_dwconv<<<dim3(nb((size_t)BL*DI)), dim3(256), 0, stream>>>(xz, mcw, mcb, u, ub);
    k_gemm_ksplit<<<dim3(BL/64), dim3(256), 0, stream>>>(ub, DI, w_x[dir], xdbc, 64, DI, dtb);
    gemm_small(dtb, DTR, 0, w_dt[dir], dy, DI, 0, BL, DI, DTR, dtbias, 1, nullptr, false);
    k_scan_part<<<dim3(512), dim3(256), 0, stream>>>(Alog, dy, u, xdbc, Hp, Pp);
    k_scan_comb<<<dim3(nb((size_t)BL*NST)), dim3(256), 0, stream>>>(Hp, Pp);
    k_scan_fin<<<dim3(512), dim3(256), 0, stream>>>(Alog, dy, u, xdbc, Pp, xz, Dp, yb);
    gemm_big(yb, DI, 0, w_out[dir], fob, DI, (dir==0)?0:512, BL, CCH, DI, nullptr, nullptr, true);
  }

  // --- final projection + bias + mask -> d_out (f32) ---
  gemm_big(fob, DI, 0, w_proj, d_out, CCH, 0, BL, CCH, DI, projb, m, false);
}

// Round 5
// 463.553 us; speedup vs baseline: 3.2103x; 1.0747x over previous
//
#include <hip/hip_runtime.h>
#include <hip/hip_bf16.h>

typedef __attribute__((ext_vector_type(8))) short short8;
typedef __attribute__((ext_vector_type(4))) float f32x4;
typedef __attribute__((ext_vector_type(4))) unsigned short ushort4_t;

#define BSZ 4
#define LSEQ 1024
#define CCH 512
#define BL (BSZ*LSEQ)   // 4096 rows
#define DI 1024         // d_inner
#define NST 16
#define DTR 32
#define NCH 32          // scan chunks
#define CLEN 32         // chunk length (NCH*CLEN == LSEQ)

__device__ __forceinline__ float sigmoidf_(float x){ return 1.f/(1.f+__expf(-x)); }
__device__ __forceinline__ float softplus_(float x){ return x > 20.f ? x : log1pf(__expf(x)); }
__device__ __forceinline__ unsigned short f2bf_(float f){
  __hip_bfloat16 h = __float2bfloat16(f); return *(unsigned short*)&h;
}

typedef const __attribute__((address_space(1))) unsigned int* gas_t;
typedef __attribute__((address_space(3))) unsigned int* las_t;
__device__ __forceinline__ void gload16(const void* g, void* l){
  __builtin_amdgcn_global_load_lds((gas_t)g, (las_t)l, 16, 0, 0);
}

// ---------------- prep / elementwise kernels ----------------

__global__ void k_cast_b4(const float* __restrict__ s, unsigned short* __restrict__ d, int n4){
  int i = blockIdx.x*256 + threadIdx.x;
  if (i >= n4) return;
  float4 v = ((const float4*)s)[i];
  ushort4_t o = { f2bf_(v.x), f2bf_(v.y), f2bf_(v.z), f2bf_(v.w) };
  *(ushort4_t*)(d + (size_t)i*4) = o;
}

// conv_w [3][512][512][5] -> wt [3][512][2560], j = k*512 + ci  (matches contiguous patch)
__global__ void k_prep_convw(const float* __restrict__ cw, __hip_bfloat16* __restrict__ wt){
  int i = blockIdx.x*256 + threadIdx.x;
  const int total = 3*CCH*CCH*5;
  if (i >= total) return;
  int j = i % (CCH*5);
  int co = (i/(CCH*5)) % CCH;
  int layer = i/(CCH*5*CCH);
  int k = j >> 9, ci = j & 511;
  wt[i] = __float2bfloat16(cw[(((size_t)layer*CCH + co)*CCH + ci)*5 + k]);
}

// gather emb[x] into padded [B][L+4][C] bf16 (2 zero rows each side for K=5 conv)
__global__ void k_embed(const int* __restrict__ x, const float* __restrict__ emb,
                        __hip_bfloat16* __restrict__ xpad){
  int i = blockIdx.x*256 + threadIdx.x;
  const int total = BSZ*(LSEQ+4)*CCH;
  if (i >= total) return;
  int c = i & (CCH-1);
  int r = (i >> 9) % (LSEQ+4);
  int b = i / ((LSEQ+4)*CCH);
  float v = 0.f;
  if (r >= 2 && r < LSEQ+2){
    int tok = x[b*LSEQ + (r-2)];
    v = emb[(size_t)tok*CCH + c];
  }
  xpad[i] = __float2bfloat16(v);
}

__global__ void k_zero_pads(__hip_bfloat16* __restrict__ xpad){
  int i = blockIdx.x*256 + threadIdx.x;
  const int total = BSZ*4*CCH;
  if (i >= total) return;
  int c = i & (CCH-1);
  int pr = (i >> 9) & 3;
  int b = i >> 11;
  int r = (pr < 2) ? pr : (LSEQ+2) + (pr-2);
  xpad[((size_t)b*(LSEQ+4) + r)*CCH + c] = __float2bfloat16(0.f);
}

// per-(b,l) channel LayerNorm + scale/shift + LeakyReLU(0.2) + mask
__global__ __launch_bounds__(256) void k_ln(
    const float* __restrict__ in, const float* __restrict__ g, const float* __restrict__ bb,
    const unsigned char* __restrict__ mask,
    __hip_bfloat16* __restrict__ xpad_next,
    __hip_bfloat16* __restrict__ h_enc, __hip_bfloat16* __restrict__ h_rev){
  int row = blockIdx.x;                 // b*1024 + l
  int b = row >> 10, l = row & 1023;
  const float* xr = in + (size_t)row*CCH;
  int t = threadIdx.x;
  float v0 = xr[t], v1 = xr[t+256];
  float s = v0+v1, s2 = v0*v0 + v1*v1;
  #pragma unroll
  for (int off=32; off>0; off>>=1){ s += __shfl_down(s,off); s2 += __shfl_down(s2,off); }
  __shared__ float ls[8];
  if ((t&63)==0){ ls[t>>6] = s; ls[(t>>6)+4] = s2; }
  __syncthreads();
  float S  = ls[0]+ls[1]+ls[2]+ls[3];
  float S2 = ls[4]+ls[5]+ls[6]+ls[7];
  float mu = S*(1.f/CCH);
  float var = S2*(1.f/CCH) - mu*mu;
  float rs = rsqrtf(var + 1e-5f);
  bool mk = mask[row] != 0;
  #pragma unroll
  for (int e=0; e<2; e++){
    int c = t + e*256;
    float v = e ? v1 : v0;
    float h = (v-mu)*rs*g[c] + bb[c];
    h = h > 0.f ? h : 0.2f*h;
    if (mk) h = 0.f;
    __hip_bfloat16 hb = __float2bfloat16(h);
    if (xpad_next) xpad_next[((size_t)b*(LSEQ+4) + (l+2))*CCH + c] = hb;
    if (h_enc) h_enc[(size_t)row*CCH + c] = hb;
    if (h_rev) h_rev[((size_t)(b<<10) + (1023-l))*CCH + c] = hb;
  }
}

// ---------------- small MFMA wave-GEMM (dt_proj K=32) ----------------
template<bool OUTBF>
__global__ __launch_bounds__(64) void k_gemm(
    const __hip_bfloat16* __restrict__ A, int lda, int padExtra,
    const __hip_bfloat16* __restrict__ W, void* __restrict__ Cout,
    int ldc, int coloff, int N, int K,
    const float* __restrict__ bias, int act,
    const unsigned char* __restrict__ mask){
  int tiles_n = N >> 6;
  int tn = blockIdx.x % tiles_n;
  int tm = blockIdx.x / tiles_n;
  int m0 = tm << 6, n0 = tn << 6;
  int lane = threadIdx.x;
  int r = lane & 15, kg = lane >> 4;

  const short* Ap[4];
  const short* Wp[4];
  #pragma unroll
  for (int mi=0; mi<4; mi++){
    int row = m0 + mi*16 + r;
    int phys = row + padExtra*(row >> 10);
    Ap[mi] = (const short*)A + (size_t)phys*lda + kg*8;
  }
  #pragma unroll
  for (int nj=0; nj<4; nj++){
    int col = n0 + nj*16 + r;
    Wp[nj] = (const short*)W + (size_t)col*K + kg*8;
  }
  f32x4 acc[4][4];
  #pragma unroll
  for (int mi=0;mi<4;mi++)
    #pragma unroll
    for (int nj=0;nj<4;nj++) acc[mi][nj] = (f32x4){0.f,0.f,0.f,0.f};

  for (int kk=0; kk<K; kk+=32){
    short8 a[4], w[4];
    #pragma unroll
    for (int mi=0;mi<4;mi++) a[mi] = *(const short8*)(Ap[mi] + kk);
    #pragma unroll
    for (int nj=0;nj<4;nj++) w[nj] = *(const short8*)(Wp[nj] + kk);
    #pragma unroll
    for (int mi=0;mi<4;mi++)
      #pragma unroll
      for (int nj=0;nj<4;nj++)
        acc[mi][nj] = __builtin_amdgcn_mfma_f32_16x16x32_bf16(a[mi], w[nj], acc[mi][nj], 0,0,0);
  }
  #pragma unroll
  for (int mi=0;mi<4;mi++){
    #pragma unroll
    for (int nj=0;nj<4;nj++){
      #pragma unroll
      for (int reg=0; reg<4; reg++){
        int row = m0 + mi*16 + kg*4 + reg;
        int col = n0 + nj*16 + r;
        float v = acc[mi][nj][reg];
        if (bias) v += bias[col];
        if (act == 1) v = softplus_(v);
        if (mask && mask[row]) v = 0.f;
        size_t o = (size_t)row*ldc + coloff + col;
        if (OUTBF) ((__hip_bfloat16*)Cout)[o] = __float2bfloat16(v);
        else       ((float*)Cout)[o] = v;
      }
    }
  }
}

// ---------------- K-split GEMM for skinny N=64 (x_proj), fused dt bf16 extract --------
__global__ __launch_bounds__(256) void k_gemm_ksplit(
    const __hip_bfloat16* __restrict__ A, int lda,
    const __hip_bfloat16* __restrict__ W, float* __restrict__ Cout,
    int ldc, int K, unsigned short* __restrict__ dtb){
  __shared__ float red[4*4096];   // 64 KB
  int m0 = blockIdx.x << 6;
  int tid = threadIdx.x;
  int w = tid >> 6, lane = tid & 63;
  int r = lane & 15, kg = lane >> 4;
  int Kw = K >> 2;
  int kbase = w*Kw;

  const short* Ap[4];
  const short* Wp[4];
  #pragma unroll
  for (int mi=0; mi<4; mi++)
    Ap[mi] = (const short*)A + (size_t)(m0 + mi*16 + r)*lda + kbase + kg*8;
  #pragma unroll
  for (int nj=0; nj<4; nj++)
    Wp[nj] = (const short*)W + (size_t)(nj*16 + r)*K + kbase + kg*8;

  f32x4 acc[4][4];
  #pragma unroll
  for (int mi=0;mi<4;mi++)
    #pragma unroll
    for (int nj=0;nj<4;nj++) acc[mi][nj] = (f32x4){0.f,0.f,0.f,0.f};

  for (int kk=0; kk<Kw; kk+=32){
    short8 a[4], wv[4];
    #pragma unroll
    for (int mi=0;mi<4;mi++) a[mi] = *(const short8*)(Ap[mi] + kk);
    #pragma unroll
    for (int nj=0;nj<4;nj++) wv[nj] = *(const short8*)(Wp[nj] + kk);
    #pragma unroll
    for (int mi=0;mi<4;mi++)
      #pragma unroll
      for (int nj=0;nj<4;nj++)
        acc[mi][nj] = __builtin_amdgcn_mfma_f32_16x16x32_bf16(a[mi], wv[nj], acc[mi][nj], 0,0,0);
  }
  #pragma unroll
  for (int mi=0;mi<4;mi++)
    #pragma unroll
    for (int nj=0;nj<4;nj++)
      #pragma unroll
      for (int reg=0; reg<4; reg++){
        int rowt = mi*16 + kg*4 + reg;
        int col  = nj*16 + r;
        red[w*4096 + rowt*64 + col] = acc[mi][nj][reg];
      }
  __syncthreads();
  int e0 = tid*16;
  #pragma unroll
  for (int j=0; j<16; j+=4){
    f32x4 s = *(const f32x4*)&red[e0+j];
    #pragma unroll
    for (int ww=1; ww<4; ww++){
      f32x4 p = *(const f32x4*)&red[ww*4096 + e0 + j];
      s.x += p.x; s.y += p.y; s.z += p.z; s.w += p.w;
    }
    int e = e0 + j;
    int rowt = e >> 6, col = e & 63;
    *(f32x4*)&Cout[(size_t)(m0+rowt)*ldc + col] = s;
    if (col < 32){
      ushort4_t o = { f2bf_(s.x), f2bf_(s.y), f2bf_(s.z), f2bf_(s.w) };
      *(ushort4_t*)&dtb[(size_t)(m0+rowt)*32 + col] = o;
    }
  }
}

// ---------------- big staged GEMM: 128(M)x64(N) tile, BK=32, 4 waves ----------------
// 3-buffer LDS ring, prefetch depth 2, counted s_waitcnt vmcnt(3) + raw s_barrier
// (T3+T4: never drain vmcnt to 0 in the main loop). Each wave issues exactly 3
// global_load_lds per tile, so vmcnt(3) == "my tile-t loads landed, t+1 in flight".
// Stage of t+2 goes into the buffer vacated at t-1 (reads provably retired: their
// data was consumed by MFMAs before the wave reached this iteration's barrier).
template<bool OUTBF>
__global__ __launch_bounds__(256) void k_gemm_big(
    const __hip_bfloat16* __restrict__ A, int lda, int padExtra,
    const __hip_bfloat16* __restrict__ W, void* __restrict__ Cout,
    int ldc, int coloff, int tiles_n, int K,
    const float* __restrict__ bias, const unsigned char* __restrict__ mask){
  __shared__ alignas(16) __hip_bfloat16 smem[3][6144];   // 3 x (4096 A + 2048 B) = 36 KB
  int tn = blockIdx.x % tiles_n;
  int tm = blockIdx.x / tiles_n;
  int m0 = tm*128, n0 = tn*64;
  int tid = threadIdx.x;
  int wid = tid >> 6, lane = tid & 63;
  int r = lane & 15, kg = lane >> 4;

  int sr = lane >> 2;
  int gs = (lane & 3) ^ (sr & 3);
  int row0 = m0 + wid*16 + sr;
  int row1 = row0 + 64;
  int p0 = row0 + padExtra*(row0 >> 10);
  int p1 = row1 + padExtra*(row1 >> 10);
  size_t aoff0 = (size_t)p0*lda + gs*8;
  size_t aoff1 = (size_t)p1*lda + gs*8;
  int bcol = n0 + wid*16 + sr;
  size_t boff = (size_t)bcol*K + gs*8;

  int wr = wid >> 1, wc = wid & 1;
  int xs = (kg ^ (r & 3))*8;
  int afrag[4], bfrag[2];
  #pragma unroll
  for (int mi=0; mi<4; mi++) afrag[mi] = (wr*64 + mi*16 + r)*32 + xs;
  #pragma unroll
  for (int nj=0; nj<2; nj++) bfrag[nj] = 4096 + (wc*32 + nj*16 + r)*32 + xs;

  f32x4 acc[4][2];
  #pragma unroll
  for (int mi=0;mi<4;mi++)
    #pragma unroll
    for (int nj=0;nj<2;nj++) acc[mi][nj] = (f32x4){0.f,0.f,0.f,0.f};

  const int nt = K >> 5;
  auto stage = [&](int kt, int bufi){
    __hip_bfloat16* sb = &smem[bufi][0];
    int k0 = kt*32;
    gload16((const short*)A + aoff0 + k0, sb + wid*512);
    gload16((const short*)A + aoff1 + k0, sb + (wid+4)*512);
    gload16((const short*)W + boff  + k0, sb + 4096 + wid*512);
  };
  auto compute = [&](int bufi){
    const __hip_bfloat16* sb = &smem[bufi][0];
    short8 a[4], b[2];
    #pragma unroll
    for (int mi=0;mi<4;mi++) a[mi] = *(const short8*)&sb[afrag[mi]];
    #pragma unroll
    for (int nj=0;nj<2;nj++) b[nj] = *(const short8*)&sb[bfrag[nj]];
    #pragma unroll
    for (int mi=0;mi<4;mi++)
      #pragma unroll
      for (int nj=0;nj<2;nj++)
        acc[mi][nj] = __builtin_amdgcn_mfma_f32_16x16x32_bf16(a[mi], b[nj], acc[mi][nj], 0,0,0);
  };

  stage(0, 0);
  stage(1, 1);
  int bi = 0;
  for (int t=0; t<nt-1; t++){
    asm volatile("s_waitcnt vmcnt(3)" ::: "memory");
    __builtin_amdgcn_s_barrier();
    __builtin_amdgcn_sched_barrier(0);
    if (t+2 < nt){
      int nb2 = bi + 2; if (nb2 >= 3) nb2 -= 3;
      stage(t+2, nb2);
    }
    compute(bi);
    bi = (bi+1 == 3) ? 0 : bi+1;
  }
  asm volatile("s_waitcnt vmcnt(0)" ::: "memory");
  __builtin_amdgcn_s_barrier();
  __builtin_amdgcn_sched_barrier(0);
  compute(bi);

  #pragma unroll
  for (int mi=0;mi<4;mi++){
    #pragma unroll
    for (int nj=0;nj<2;nj++){
      #pragma unroll
      for (int reg=0; reg<4; reg++){
        int row = m0 + wr*64 + mi*16 + kg*4 + reg;
        int col = n0 + wc*32 + nj*16 + r;
        float v = acc[mi][nj][reg];
        if (bias) v += bias[col];
        if (mask && mask[row]) v = 0.f;
        size_t o = (size_t)row*ldc + coloff + col;
        if (OUTBF) ((__hip_bfloat16*)Cout)[o] = __float2bfloat16(v);
        else       ((float*)Cout)[o] = v;
      }
    }
  }
}

// ---------------- mamba pieces ----------------

__global__ void k_dwconv(const float* __restrict__ xz, const float* __restrict__ cw,
                         const float* __restrict__ cb, float* __restrict__ u,
                         __hip_bfloat16* __restrict__ ub){
  int i = blockIdx.x*256 + threadIdx.x;
  if (i >= BL*DI) return;
  int d = i & (DI-1);
  int row = i >> 10;
  int l = row & 1023;
  int rb = row & ~1023;
  float acc = cb[d];
  #pragma unroll
  for (int k=0;k<4;k++){
    int ll = l - 3 + k;
    if (ll >= 0) acc += cw[d*4 + k] * xz[(size_t)(rb + ll)*(2*DI) + d];
  }
  float s = acc * sigmoidf_(acc);
  u[i] = s;
  ub[i] = __float2bfloat16(s);
}

// -------- chunked selective scan, thread-per-d, state vector in registers --------

__global__ __launch_bounds__(256) void k_scan_part(
    const float* __restrict__ A_log, const float* __restrict__ dy,
    const float* __restrict__ u, const float* __restrict__ xdbc,
    float* __restrict__ Hp, float* __restrict__ Pp){
  __shared__ alignas(16) float Bsh[CLEN*16];
  int t = threadIdx.x;
  int dblk = blockIdx.x & 3;
  int c = (blockIdx.x >> 2) & (NCH-1);
  int b = blockIdx.x >> 7;
  int d = dblk*256 + t;
  size_t blbase = (size_t)b*LSEQ + (size_t)c*CLEN;
  if (t < CLEN*4){
    int l = t >> 2, q = t & 3;
    *(f32x4*)&Bsh[l*16 + q*4] = *(const f32x4*)&xdbc[(blbase+l)*64 + 32 + q*4];
  }
  float Af[16];
  #pragma unroll
  for (int n=0; n<16; n+=4){
    f32x4 a = *(const f32x4*)&A_log[(size_t)d*16 + n];
    Af[n]   = -__expf(a.x); Af[n+1] = -__expf(a.y);
    Af[n+2] = -__expf(a.z); Af[n+3] = -__expf(a.w);
  }
  float h[16], P[16];
  #pragma unroll
  for (int n=0;n<16;n++){ h[n]=0.f; P[n]=1.f; }
  __syncthreads();
  float dv = dy[blbase*DI + d];
  float uv = u[blbase*DI + d];
  for (int l=0; l<CLEN; l++){
    float dvn = 0.f, uvn = 0.f;
    if (l+1 < CLEN){
      dvn = dy[(blbase+l+1)*DI + d];
      uvn = u[(blbase+l+1)*DI + d];
    }
    float duv = dv*uv;
    #pragma unroll
    for (int n=0;n<16;n++){
      float dA = __expf(dv*Af[n]);
      h[n] = __fmaf_rn(dA, h[n], duv*Bsh[l*16+n]);
      P[n] *= dA;
    }
    dv = dvn; uv = uvn;
  }
  size_t pb = (((size_t)(b*NCH + c))*DI + d)*16;
  #pragma unroll
  for (int n=0;n<16;n+=4){
    *(f32x4*)&Hp[pb+n] = (f32x4){h[n],h[n+1],h[n+2],h[n+3]};
    *(f32x4*)&Pp[pb+n] = (f32x4){P[n],P[n+1],P[n+2],P[n+3]};
  }
}

// combine: h_in[c+1] = P[c]*h_in[c] + H[c]; writes h_in back into Pp (in place)
__global__ void k_scan_comb(float* __restrict__ Hp, float* __restrict__ Pp){
  int i = blockIdx.x*256 + threadIdx.x;   // (b*1024+d)*16 + n
  if (i >= BL*NST) return;
  int n = i & 15, row = i >> 4;
  int b = row >> 10, d = row & 1023;
  float hin = 0.f;
  #pragma unroll
  for (int c=0;c<NCH;c++){
    size_t idx = (((size_t)(b*NCH + c))*DI + d)*16 + n;
    float P = Pp[idx], H = Hp[idx];
    Pp[idx] = hin;
    hin = __fmaf_rn(P, hin, H);
  }
}

// final pass: recompute chunk states from h_in, emit y fused with ygate -> yb (bf16)
__global__ __launch_bounds__(256) void k_scan_fin(
    const float* __restrict__ A_log, const float* __restrict__ dy,
    const float* __restrict__ u, const float* __restrict__ xdbc,
    const float* __restrict__ Hin, const float* __restrict__ xz,
    const float* __restrict__ Dp, __hip_bfloat16* __restrict__ yb){
  __shared__ alignas(16) float BCsh[CLEN*32];
  int t = threadIdx.x;
  int dblk = blockIdx.x & 3;
  int c = (blockIdx.x >> 2) & (NCH-1);
  int b = blockIdx.x >> 7;
  int d = dblk*256 + t;
  size_t blbase = (size_t)b*LSEQ + (size_t)c*CLEN;
  {
    int l = t >> 3, q = t & 7;   // 256 threads cover 32 rows x 8 quads
    *(f32x4*)&BCsh[l*32 + q*4] = *(const f32x4*)&xdbc[(blbase+l)*64 + 32 + q*4];
  }
  float Af[16];
  #pragma unroll
  for (int n=0; n<16; n+=4){
    f32x4 a = *(const f32x4*)&A_log[(size_t)d*16 + n];
    Af[n]   = -__expf(a.x); Af[n+1] = -__expf(a.y);
    Af[n+2] = -__expf(a.z); Af[n+3] = -__expf(a.w);
  }
  size_t pb = (((size_t)(b*NCH + c))*DI + d)*16;
  float h[16];
  #pragma unroll
  for (int n=0;n<16;n+=4){
    f32x4 hv = *(const f32x4*)&Hin[pb+n];
    h[n]=hv.x; h[n+1]=hv.y; h[n+2]=hv.z; h[n+3]=hv.w;
  }
  float Dd = Dp[d];
  __syncthreads();
  float dv = dy[blbase*DI + d];
  float uv = u[blbase*DI + d];
  float zv = xz[blbase*(2*DI) + DI + d];
  for (int l=0; l<CLEN; l++){
    float dvn = 0.f, uvn = 0.f, zvn = 0.f;
    if (l+1 < CLEN){
      dvn = dy[(blbase+l+1)*DI + d];
      uvn = u[(blbase+l+1)*DI + d];
      zvn = xz[(blbase+l+1)*(2*DI) + DI + d];
    }
    float duv = dv*uv;
    float y = 0.f;
    #pragma unroll
    for (int n=0;n<16;n++){
      float dA = __expf(dv*Af[n]);
      h[n] = __fmaf_rn(dA, h[n], duv*BCsh[l*32+n]);
      y = __fmaf_rn(h[n], BCsh[l*32+16+n], y);
    }
    float g = zv * sigmoidf_(zv);
    float out = __fmaf_rn(uv, Dd, y) * g;
    yb[(blbase+l)*DI + d] = __float2bfloat16(out);
    dv = dvn; uv = uvn; zv = zvn;
  }
}

// ---------------- host ----------------

extern "C" void kernel_launch(void* const* d_in, const int* in_sizes, int n_in,
                              void* d_out, int out_size, void* d_ws, size_t ws_size,
                              hipStream_t stream){
  (void)in_sizes; (void)n_in; (void)out_size; (void)ws_size;
  const int*   x     = (const int*)d_in[0];
  const unsigned char* m = (const unsigned char*)d_in[2];
  const float* emb   = (const float*)d_in[3];
  const float* convw = (const float*)d_in[4];
  const float* convb = (const float*)d_in[5];
  const float* lng   = (const float*)d_in[6];
  const float* lnb   = (const float*)d_in[7];
  const float* projw = (const float*)d_in[8];
  const float* projb = (const float*)d_in[9];

  char* ws = (char*)d_ws;
  size_t off = 0;
  auto alloc = [&](size_t bytes)->char*{
    char* p = ws + off; off += (bytes + 255) & ~((size_t)255); return p;
  };
  auto wt_conv = (__hip_bfloat16*)alloc((size_t)3*CCH*CCH*5*2);
  __hip_bfloat16 *w_in[2], *w_x[2], *w_dt[2], *w_out[2];
  for (int dir=0; dir<2; dir++){
    w_in[dir]  = (__hip_bfloat16*)alloc((size_t)2*DI*CCH*2);
    w_x[dir]   = (__hip_bfloat16*)alloc((size_t)64*DI*2);
    w_dt[dir]  = (__hip_bfloat16*)alloc((size_t)DI*DTR*2);
    w_out[dir] = (__hip_bfloat16*)alloc((size_t)CCH*DI*2);
  }
  auto w_proj  = (__hip_bfloat16*)alloc((size_t)CCH*1024*2);
  auto xpad0   = (__hip_bfloat16*)alloc((size_t)BSZ*(LSEQ+4)*CCH*2);
  auto xpad1   = (__hip_bfloat16*)alloc((size_t)BSZ*(LSEQ+4)*CCH*2);
  auto convtmp = (float*)alloc((size_t)BL*CCH*4);       // conv out; later Hp (8 MB)
  auto h_enc   = (__hip_bfloat16*)alloc((size_t)BL*CCH*2);
  auto h_rev   = (__hip_bfloat16*)alloc((size_t)BL*CCH*2);
  auto xz      = (float*)alloc((size_t)BL*2*DI*4);
  auto u       = (float*)alloc((size_t)BL*DI*4);
  auto ub      = (__hip_bfloat16*)alloc((size_t)BL*DI*2);
  auto xdbc    = (float*)alloc((size_t)BL*64*4);
  auto dtb     = (unsigned short*)alloc((size_t)BL*DTR*2);
  auto dy      = (float*)alloc((size_t)BL*DI*4);        // delta (read-only in scan)
  auto yb      = (__hip_bfloat16*)alloc((size_t)BL*DI*2);
  auto fob     = (__hip_bfloat16*)alloc((size_t)BL*DI*2);

  // scan scratch: Hp reuses convtmp (8 MB); Pp reuses xpad0+xpad1 region (8.4 MB,
  // contiguous in ws, dead after the encoder finishes).
  float* Hp = convtmp;
  float* Pp = (float*)xpad0;

  auto nb = [](size_t n){ return (unsigned)((n + 255)/256); };

  // --- weight prep ---
  k_prep_convw<<<dim3(nb((size_t)3*CCH*CCH*5)), dim3(256), 0, stream>>>(convw, wt_conv);
  for (int dir=0; dir<2; dir++){
    int base = 10 + 9*dir;
    k_cast_b4<<<dim3(nb((size_t)2*DI*CCH/4)), dim3(256), 0, stream>>>((const float*)d_in[base+0], (unsigned short*)w_in[dir], 2*DI*CCH/4);
    k_cast_b4<<<dim3(nb((size_t)64*DI/4)),    dim3(256), 0, stream>>>((const float*)d_in[base+3], (unsigned short*)w_x[dir], 64*DI/4);
    k_cast_b4<<<dim3(nb((size_t)DI*DTR/4)),   dim3(256), 0, stream>>>((const float*)d_in[base+4], (unsigned short*)w_dt[dir], DI*DTR/4);
    k_cast_b4<<<dim3(nb((size_t)CCH*DI/4)),   dim3(256), 0, stream>>>((const float*)d_in[base+8], (unsigned short*)w_out[dir], CCH*DI/4);
  }
  k_cast_b4<<<dim3(nb((size_t)CCH*1024/4)), dim3(256), 0, stream>>>(projw, (unsigned short*)w_proj, CCH*1024/4);

  auto gemm_small = [&](const void* A, int lda, int padE, const void* W, void* C, int ldc, int coloff,
                  int M, int N, int K, const float* bias, int act, const unsigned char* msk, bool outbf){
    int blocks = (M/64)*(N/64);
    if (outbf)
      k_gemm<true><<<dim3(blocks), dim3(64), 0, stream>>>((const __hip_bfloat16*)A, lda, padE,
          (const __hip_bfloat16*)W, C, ldc, coloff, N, K, bias, act, msk);
    else
      k_gemm<false><<<dim3(blocks), dim3(64), 0, stream>>>((const __hip_bfloat16*)A, lda, padE,
          (const __hip_bfloat16*)W, C, ldc, coloff, N, K, bias, act, msk);
  };
  auto gemm_big = [&](const void* A, int lda, int padE, const void* W, void* C, int ldc, int coloff,
                  int M, int N, int K, const float* bias, const unsigned char* msk, bool outbf){
    int tiles_n = N/64;
    int blocks = (M/128)*tiles_n;
    if (outbf)
      k_gemm_big<true><<<dim3(blocks), dim3(256), 0, stream>>>((const __hip_bfloat16*)A, lda, padE,
          (const __hip_bfloat16*)W, C, ldc, coloff, tiles_n, K, bias, msk);
    else
      k_gemm_big<false><<<dim3(blocks), dim3(256), 0, stream>>>((const __hip_bfloat16*)A, lda, padE,
          (const __hip_bfloat16*)W, C, ldc, coloff, tiles_n, K, bias, msk);
  };

  // --- encoder: embed + 3x (conv-as-GEMM -> LN/leaky/mask) ---
  k_embed<<<dim3(nb((size_t)BSZ*(LSEQ+4)*CCH)), dim3(256), 0, stream>>>(x, emb, xpad0);
  k_zero_pads<<<dim3(nb((size_t)BSZ*4*CCH)), dim3(256), 0, stream>>>(xpad1);

  __hip_bfloat16* xp_in = xpad0;
  __hip_bfloat16* xp_out = xpad1;
  for (int layer=0; layer<3; layer++){
    gemm_big(xp_in, CCH, 4, wt_conv + (size_t)layer*CCH*CCH*5, convtmp, CCH, 0,
         BL, CCH, CCH*5, convb + layer*CCH, nullptr, false);
    bool last = (layer==2);
    k_ln<<<dim3(BL), dim3(256), 0, stream>>>(convtmp, lng + layer*CCH, lnb + layer*CCH, m,
        last ? nullptr : xp_out, last ? h_enc : nullptr, last ? h_rev : nullptr);
    __hip_bfloat16* t2 = xp_in; xp_in = xp_out; xp_out = t2;
  }

  // --- bidirectional mamba ---
  for (int dir=0; dir<2; dir++){
    int base = 10 + 9*dir;
    const float* mcw    = (const float*)d_in[base+1];
    const float* mcb    = (const float*)d_in[base+2];
    const float* dtbias = (const float*)d_in[base+5];
    const float* Alog   = (const float*)d_in[base+6];
    const float* Dp     = (const float*)d_in[base+7];
    const __hip_bfloat16* hin = (dir==0) ? h_enc : h_rev;

    gemm_big(hin, CCH, 0, w_in[dir], xz, 2*DI, 0, BL, 2*DI, CCH, nullptr, nullptr, false);
    k_dwconv<<<dim3(nb((size_t)BL*DI)), dim3(256), 0, stream>>>(xz, mcw, mcb, u, ub);
    k_gemm_ksplit<<<dim3(BL/64), dim3(256), 0, stream>>>(ub, DI, w_x[dir], xdbc, 64, DI, dtb);
    gemm_small(dtb, DTR, 0, w_dt[dir], dy, DI, 0, BL, DI, DTR, dtbias, 1, nullptr, false);
    k_scan_part<<<dim3(512), dim3(256), 0, stream>>>(Alog, dy, u, xdbc, Hp, Pp);
    k_scan_comb<<<dim3(nb((size_t)BL*NST)), dim3(256), 0, stream>>>(Hp, Pp);
    k_scan_fin<<<dim3(512), dim3(256), 0, stream>>>(Alog, dy, u, xdbc, Pp, xz, Dp, yb);
    gemm_big(yb, DI, 0, w_out[dir], fob, DI, (dir==0)?0:512, BL, CCH, DI, nullptr, nullptr, true);
  }

  // --- final projection + bias + mask -> d_out (f32) ---
  gemm_big(fob, DI, 0, w_proj, d_out, CCH, 0, BL, CCH, DI, projb, m, false);
}

// Round 6
// 459.221 us; speedup vs baseline: 3.2406x; 1.0094x over previous
//
#include <hip/hip_runtime.h>
#include <hip/hip_bf16.h>

typedef __attribute__((ext_vector_type(8))) short short8;
typedef __attribute__((ext_vector_type(4))) float f32x4;
typedef __attribute__((ext_vector_type(4))) unsigned short ushort4_t;

#define BSZ 4
#define LSEQ 1024
#define CCH 512
#define BL (BSZ*LSEQ)   // 4096 rows
#define DI 1024         // d_inner
#define NST 16
#define DTR 32
#define NCH 32          // scan chunks
#define CLEN 32         // chunk length (NCH*CLEN == LSEQ)

__device__ __forceinline__ float sigmoidf_(float x){ return 1.f/(1.f+__expf(-x)); }
__device__ __forceinline__ float softplus_(float x){ return x > 20.f ? x : log1pf(__expf(x)); }
__device__ __forceinline__ unsigned short f2bf_(float f){
  __hip_bfloat16 h = __float2bfloat16(f); return *(unsigned short*)&h;
}

typedef const __attribute__((address_space(1))) unsigned int* gas_t;
typedef __attribute__((address_space(3))) unsigned int* las_t;
__device__ __forceinline__ void gload16(const void* g, void* l){
  __builtin_amdgcn_global_load_lds((gas_t)g, (las_t)l, 16, 0, 0);
}

// ---------------- prep / elementwise kernels ----------------

__global__ void k_cast_b4(const float* __restrict__ s, unsigned short* __restrict__ d, int n4){
  int i = blockIdx.x*256 + threadIdx.x;
  if (i >= n4) return;
  float4 v = ((const float4*)s)[i];
  ushort4_t o = { f2bf_(v.x), f2bf_(v.y), f2bf_(v.z), f2bf_(v.w) };
  *(ushort4_t*)(d + (size_t)i*4) = o;
}

// conv_w [3][512][512][5] -> wt [3][512][2560], j = k*512 + ci  (matches contiguous patch)
__global__ void k_prep_convw(const float* __restrict__ cw, __hip_bfloat16* __restrict__ wt){
  int i = blockIdx.x*256 + threadIdx.x;
  const int total = 3*CCH*CCH*5;
  if (i >= total) return;
  int j = i % (CCH*5);
  int co = (i/(CCH*5)) % CCH;
  int layer = i/(CCH*5*CCH);
  int k = j >> 9, ci = j & 511;
  wt[i] = __float2bfloat16(cw[(((size_t)layer*CCH + co)*CCH + ci)*5 + k]);
}

// gather emb[x] into padded [B][L+4][C] bf16 (2 zero rows each side for K=5 conv)
__global__ void k_embed(const int* __restrict__ x, const float* __restrict__ emb,
                        __hip_bfloat16* __restrict__ xpad){
  int i = blockIdx.x*256 + threadIdx.x;
  const int total = BSZ*(LSEQ+4)*CCH;
  if (i >= total) return;
  int c = i & (CCH-1);
  int r = (i >> 9) % (LSEQ+4);
  int b = i / ((LSEQ+4)*CCH);
  float v = 0.f;
  if (r >= 2 && r < LSEQ+2){
    int tok = x[b*LSEQ + (r-2)];
    v = emb[(size_t)tok*CCH + c];
  }
  xpad[i] = __float2bfloat16(v);
}

__global__ void k_zero_pads(__hip_bfloat16* __restrict__ xpad){
  int i = blockIdx.x*256 + threadIdx.x;
  const int total = BSZ*4*CCH;
  if (i >= total) return;
  int c = i & (CCH-1);
  int pr = (i >> 9) & 3;
  int b = i >> 11;
  int r = (pr < 2) ? pr : (LSEQ+2) + (pr-2);
  xpad[((size_t)b*(LSEQ+4) + r)*CCH + c] = __float2bfloat16(0.f);
}

// per-(b,l) channel LayerNorm over (in + in2) + scale/shift + LeakyReLU(0.2) + mask
__global__ __launch_bounds__(256) void k_ln(
    const float* __restrict__ in, const float* __restrict__ in2,
    const float* __restrict__ g, const float* __restrict__ bb,
    const unsigned char* __restrict__ mask,
    __hip_bfloat16* __restrict__ xpad_next,
    __hip_bfloat16* __restrict__ h_enc, __hip_bfloat16* __restrict__ h_rev){
  int row = blockIdx.x;                 // b*1024 + l
  int b = row >> 10, l = row & 1023;
  const float* xr = in + (size_t)row*CCH;
  const float* xr2 = in2 + (size_t)row*CCH;
  int t = threadIdx.x;
  float v0 = xr[t] + xr2[t], v1 = xr[t+256] + xr2[t+256];
  float s = v0+v1, s2 = v0*v0 + v1*v1;
  #pragma unroll
  for (int off=32; off>0; off>>=1){ s += __shfl_down(s,off); s2 += __shfl_down(s2,off); }
  __shared__ float ls[8];
  if ((t&63)==0){ ls[t>>6] = s; ls[(t>>6)+4] = s2; }
  __syncthreads();
  float S  = ls[0]+ls[1]+ls[2]+ls[3];
  float S2 = ls[4]+ls[5]+ls[6]+ls[7];
  float mu = S*(1.f/CCH);
  float var = S2*(1.f/CCH) - mu*mu;
  float rs = rsqrtf(var + 1e-5f);
  bool mk = mask[row] != 0;
  #pragma unroll
  for (int e=0; e<2; e++){
    int c = t + e*256;
    float v = e ? v1 : v0;
    float h = (v-mu)*rs*g[c] + bb[c];
    h = h > 0.f ? h : 0.2f*h;
    if (mk) h = 0.f;
    __hip_bfloat16 hb = __float2bfloat16(h);
    if (xpad_next) xpad_next[((size_t)b*(LSEQ+4) + (l+2))*CCH + c] = hb;
    if (h_enc) h_enc[(size_t)row*CCH + c] = hb;
    if (h_rev) h_rev[((size_t)(b<<10) + (1023-l))*CCH + c] = hb;
  }
}

// ---------------- K-split GEMM for skinny N=64 (x_proj), fused dt bf16 extract --------
__global__ __launch_bounds__(256) void k_gemm_ksplit(
    const __hip_bfloat16* __restrict__ A, int lda,
    const __hip_bfloat16* __restrict__ W, float* __restrict__ Cout,
    int ldc, int K, unsigned short* __restrict__ dtb){
  __shared__ float red[4*4096];   // 64 KB
  int m0 = blockIdx.x << 6;
  int tid = threadIdx.x;
  int w = tid >> 6, lane = tid & 63;
  int r = lane & 15, kg = lane >> 4;
  int Kw = K >> 2;
  int kbase = w*Kw;

  const short* Ap[4];
  const short* Wp[4];
  #pragma unroll
  for (int mi=0; mi<4; mi++)
    Ap[mi] = (const short*)A + (size_t)(m0 + mi*16 + r)*lda + kbase + kg*8;
  #pragma unroll
  for (int nj=0; nj<4; nj++)
    Wp[nj] = (const short*)W + (size_t)(nj*16 + r)*K + kbase + kg*8;

  f32x4 acc[4][4];
  #pragma unroll
  for (int mi=0;mi<4;mi++)
    #pragma unroll
    for (int nj=0;nj<4;nj++) acc[mi][nj] = (f32x4){0.f,0.f,0.f,0.f};

  for (int kk=0; kk<Kw; kk+=32){
    short8 a[4], wv[4];
    #pragma unroll
    for (int mi=0;mi<4;mi++) a[mi] = *(const short8*)(Ap[mi] + kk);
    #pragma unroll
    for (int nj=0;nj<4;nj++) wv[nj] = *(const short8*)(Wp[nj] + kk);
    #pragma unroll
    for (int mi=0;mi<4;mi++)
      #pragma unroll
      for (int nj=0;nj<4;nj++)
        acc[mi][nj] = __builtin_amdgcn_mfma_f32_16x16x32_bf16(a[mi], wv[nj], acc[mi][nj], 0,0,0);
  }
  #pragma unroll
  for (int mi=0;mi<4;mi++)
    #pragma unroll
    for (int nj=0;nj<4;nj++)
      #pragma unroll
      for (int reg=0; reg<4; reg++){
        int rowt = mi*16 + kg*4 + reg;
        int col  = nj*16 + r;
        red[w*4096 + rowt*64 + col] = acc[mi][nj][reg];
      }
  __syncthreads();
  int e0 = tid*16;
  #pragma unroll
  for (int j=0; j<16; j+=4){
    f32x4 s = *(const f32x4*)&red[e0+j];
    #pragma unroll
    for (int ww=1; ww<4; ww++){
      f32x4 p = *(const f32x4*)&red[ww*4096 + e0 + j];
      s.x += p.x; s.y += p.y; s.z += p.z; s.w += p.w;
    }
    int e = e0 + j;
    int rowt = e >> 6, col = e & 63;
    *(f32x4*)&Cout[(size_t)(m0+rowt)*ldc + col] = s;
    if (col < 32){
      ushort4_t o = { f2bf_(s.x), f2bf_(s.y), f2bf_(s.z), f2bf_(s.w) };
      *(ushort4_t*)&dtb[(size_t)(m0+rowt)*32 + col] = o;
    }
  }
}

// ---------------- big staged GEMM: 128(M)x64(N) tile, BK=32, 4 waves ----------------
// 3-buffer LDS ring, prefetch depth 2, counted s_waitcnt vmcnt(3) + raw s_barrier.
// Kc = this block's K chunk length; Kb = B row stride (full K); kOff = chunk offset
// (K-split: partials summed downstream). act==1 applies softplus in the epilogue.
template<bool OUTBF>
__global__ __launch_bounds__(256) void k_gemm_big(
    const __hip_bfloat16* __restrict__ A, int lda, int padExtra,
    const __hip_bfloat16* __restrict__ W, void* __restrict__ Cout,
    int ldc, int coloff, int tiles_n, int Kc, int Kb, int kOff,
    const float* __restrict__ bias, int act, const unsigned char* __restrict__ mask){
  __shared__ alignas(16) __hip_bfloat16 smem[3][6144];   // 3 x (4096 A + 2048 B) = 36 KB
  int tn = blockIdx.x % tiles_n;
  int tm = blockIdx.x / tiles_n;
  int m0 = tm*128, n0 = tn*64;
  int tid = threadIdx.x;
  int wid = tid >> 6, lane = tid & 63;
  int r = lane & 15, kg = lane >> 4;

  int sr = lane >> 2;
  int gs = (lane & 3) ^ (sr & 3);
  int row0 = m0 + wid*16 + sr;
  int row1 = row0 + 64;
  int p0 = row0 + padExtra*(row0 >> 10);
  int p1 = row1 + padExtra*(row1 >> 10);
  size_t aoff0 = (size_t)p0*lda + kOff + gs*8;
  size_t aoff1 = (size_t)p1*lda + kOff + gs*8;
  int bcol = n0 + wid*16 + sr;
  size_t boff = (size_t)bcol*Kb + kOff + gs*8;

  int wr = wid >> 1, wc = wid & 1;
  int xs = (kg ^ (r & 3))*8;
  int afrag[4], bfrag[2];
  #pragma unroll
  for (int mi=0; mi<4; mi++) afrag[mi] = (wr*64 + mi*16 + r)*32 + xs;
  #pragma unroll
  for (int nj=0; nj<2; nj++) bfrag[nj] = 4096 + (wc*32 + nj*16 + r)*32 + xs;

  f32x4 acc[4][2];
  #pragma unroll
  for (int mi=0;mi<4;mi++)
    #pragma unroll
    for (int nj=0;nj<2;nj++) acc[mi][nj] = (f32x4){0.f,0.f,0.f,0.f};

  const int nt = Kc >> 5;
  auto stage = [&](int kt, int bufi){
    __hip_bfloat16* sb = &smem[bufi][0];
    int k0 = kt*32;
    gload16((const short*)A + aoff0 + k0, sb + wid*512);
    gload16((const short*)A + aoff1 + k0, sb + (wid+4)*512);
    gload16((const short*)W + boff  + k0, sb + 4096 + wid*512);
  };
  auto compute = [&](int bufi){
    const __hip_bfloat16* sb = &smem[bufi][0];
    short8 a[4], b[2];
    #pragma unroll
    for (int mi=0;mi<4;mi++) a[mi] = *(const short8*)&sb[afrag[mi]];
    #pragma unroll
    for (int nj=0;nj<2;nj++) b[nj] = *(const short8*)&sb[bfrag[nj]];
    #pragma unroll
    for (int mi=0;mi<4;mi++)
      #pragma unroll
      for (int nj=0;nj<2;nj++)
        acc[mi][nj] = __builtin_amdgcn_mfma_f32_16x16x32_bf16(a[mi], b[nj], acc[mi][nj], 0,0,0);
  };

  stage(0, 0);
  if (nt > 1) stage(1, 1);
  int bi = 0;
  for (int t=0; t<nt-1; t++){
    asm volatile("s_waitcnt vmcnt(3)" ::: "memory");
    __builtin_amdgcn_s_barrier();
    __builtin_amdgcn_sched_barrier(0);
    if (t+2 < nt){
      int nb2 = bi + 2; if (nb2 >= 3) nb2 -= 3;
      stage(t+2, nb2);
    }
    compute(bi);
    bi = (bi+1 == 3) ? 0 : bi+1;
  }
  asm volatile("s_waitcnt vmcnt(0)" ::: "memory");
  __builtin_amdgcn_s_barrier();
  __builtin_amdgcn_sched_barrier(0);
  compute(bi);

  #pragma unroll
  for (int mi=0;mi<4;mi++){
    #pragma unroll
    for (int nj=0;nj<2;nj++){
      #pragma unroll
      for (int reg=0; reg<4; reg++){
        int row = m0 + wr*64 + mi*16 + kg*4 + reg;
        int col = n0 + wc*32 + nj*16 + r;
        float v = acc[mi][nj][reg];
        if (bias) v += bias[col];
        if (act == 1) v = softplus_(v);
        if (mask && mask[row]) v = 0.f;
        size_t o = (size_t)row*ldc + coloff + col;
        if (OUTBF) ((__hip_bfloat16*)Cout)[o] = __float2bfloat16(v);
        else       ((float*)Cout)[o] = v;
      }
    }
  }
}

// ---------------- mamba pieces ----------------

__global__ void k_dwconv(const float* __restrict__ xz, const float* __restrict__ cw,
                         const float* __restrict__ cb, float* __restrict__ u,
                         __hip_bfloat16* __restrict__ ub){
  int i = blockIdx.x*256 + threadIdx.x;
  if (i >= BL*DI) return;
  int d = i & (DI-1);
  int row = i >> 10;
  int l = row & 1023;
  int rb = row & ~1023;
  float acc = cb[d];
  #pragma unroll
  for (int k=0;k<4;k++){
    int ll = l - 3 + k;
    if (ll >= 0) acc += cw[d*4 + k] * xz[(size_t)(rb + ll)*(2*DI) + d];
  }
  float s = acc * sigmoidf_(acc);
  u[i] = s;
  ub[i] = __float2bfloat16(s);
}

// -------- chunked selective scan, thread-per-d, state vector in registers --------

__global__ __launch_bounds__(256) void k_scan_part(
    const float* __restrict__ A_log, const float* __restrict__ dy,
    const float* __restrict__ u, const float* __restrict__ xdbc,
    float* __restrict__ Hp, float* __restrict__ Pp){
  __shared__ alignas(16) float Bsh[CLEN*16];
  int t = threadIdx.x;
  int dblk = blockIdx.x & 3;
  int c = (blockIdx.x >> 2) & (NCH-1);
  int b = blockIdx.x >> 7;
  int d = dblk*256 + t;
  size_t blbase = (size_t)b*LSEQ + (size_t)c*CLEN;
  if (t < CLEN*4){
    int l = t >> 2, q = t & 3;
    *(f32x4*)&Bsh[l*16 + q*4] = *(const f32x4*)&xdbc[(blbase+l)*64 + 32 + q*4];
  }
  float Af[16];
  #pragma unroll
  for (int n=0; n<16; n+=4){
    f32x4 a = *(const f32x4*)&A_log[(size_t)d*16 + n];
    Af[n]   = -__expf(a.x); Af[n+1] = -__expf(a.y);
    Af[n+2] = -__expf(a.z); Af[n+3] = -__expf(a.w);
  }
  float h[16], P[16];
  #pragma unroll
  for (int n=0;n<16;n++){ h[n]=0.f; P[n]=1.f; }
  __syncthreads();
  float dv = dy[blbase*DI + d];
  float uv = u[blbase*DI + d];
  for (int l=0; l<CLEN; l++){
    float dvn = 0.f, uvn = 0.f;
    if (l+1 < CLEN){
      dvn = dy[(blbase+l+1)*DI + d];
      uvn = u[(blbase+l+1)*DI + d];
    }
    float duv = dv*uv;
    #pragma unroll
    for (int n=0;n<16;n++){
      float dA = __expf(dv*Af[n]);
      h[n] = __fmaf_rn(dA, h[n], duv*Bsh[l*16+n]);
      P[n] *= dA;
    }
    dv = dvn; uv = uvn;
  }
  size_t pb = (((size_t)(b*NCH + c))*DI + d)*16;
  #pragma unroll
  for (int n=0;n<16;n+=4){
    *(f32x4*)&Hp[pb+n] = (f32x4){h[n],h[n+1],h[n+2],h[n+3]};
    *(f32x4*)&Pp[pb+n] = (f32x4){P[n],P[n+1],P[n+2],P[n+3]};
  }
}

// combine: h_in[c+1] = P[c]*h_in[c] + H[c]; writes h_in back into Pp (in place)
__global__ void k_scan_comb(float* __restrict__ Hp, float* __restrict__ Pp){
  int i = blockIdx.x*256 + threadIdx.x;   // (b*1024+d)*16 + n
  if (i >= BL*NST) return;
  int n = i & 15, row = i >> 4;
  int b = row >> 10, d = row & 1023;
  float hin = 0.f;
  #pragma unroll
  for (int c=0;c<NCH;c++){
    size_t idx = (((size_t)(b*NCH + c))*DI + d)*16 + n;
    float P = Pp[idx], H = Hp[idx];
    Pp[idx] = hin;
    hin = __fmaf_rn(P, hin, H);
  }
}

// final pass: recompute chunk states from h_in, emit y fused with ygate -> yb (bf16)
__global__ __launch_bounds__(256) void k_scan_fin(
    const float* __restrict__ A_log, const float* __restrict__ dy,
    const float* __restrict__ u, const float* __restrict__ xdbc,
    const float* __restrict__ Hin, const float* __restrict__ xz,
    const float* __restrict__ Dp, __hip_bfloat16* __restrict__ yb){
  __shared__ alignas(16) float BCsh[CLEN*32];
  int t = threadIdx.x;
  int dblk = blockIdx.x & 3;
  int c = (blockIdx.x >> 2) & (NCH-1);
  int b = blockIdx.x >> 7;
  int d = dblk*256 + t;
  size_t blbase = (size_t)b*LSEQ + (size_t)c*CLEN;
  {
    int l = t >> 3, q = t & 7;   // 256 threads cover 32 rows x 8 quads
    *(f32x4*)&BCsh[l*32 + q*4] = *(const f32x4*)&xdbc[(blbase+l)*64 + 32 + q*4];
  }
  float Af[16];
  #pragma unroll
  for (int n=0; n<16; n+=4){
    f32x4 a = *(const f32x4*)&A_log[(size_t)d*16 + n];
    Af[n]   = -__expf(a.x); Af[n+1] = -__expf(a.y);
    Af[n+2] = -__expf(a.z); Af[n+3] = -__expf(a.w);
  }
  size_t pb = (((size_t)(b*NCH + c))*DI + d)*16;
  float h[16];
  #pragma unroll
  for (int n=0;n<16;n+=4){
    f32x4 hv = *(const f32x4*)&Hin[pb+n];
    h[n]=hv.x; h[n+1]=hv.y; h[n+2]=hv.z; h[n+3]=hv.w;
  }
  float Dd = Dp[d];
  __syncthreads();
  float dv = dy[blbase*DI + d];
  float uv = u[blbase*DI + d];
  float zv = xz[blbase*(2*DI) + DI + d];
  for (int l=0; l<CLEN; l++){
    float dvn = 0.f, uvn = 0.f, zvn = 0.f;
    if (l+1 < CLEN){
      dvn = dy[(blbase+l+1)*DI + d];
      uvn = u[(blbase+l+1)*DI + d];
      zvn = xz[(blbase+l+1)*(2*DI) + DI + d];
    }
    float duv = dv*uv;
    float y = 0.f;
    #pragma unroll
    for (int n=0;n<16;n++){
      float dA = __expf(dv*Af[n]);
      h[n] = __fmaf_rn(dA, h[n], duv*BCsh[l*32+n]);
      y = __fmaf_rn(h[n], BCsh[l*32+16+n], y);
    }
    float g = zv * sigmoidf_(zv);
    float out = __fmaf_rn(uv, Dd, y) * g;
    yb[(blbase+l)*DI + d] = __float2bfloat16(out);
    dv = dvn; uv = uvn; zv = zvn;
  }
}

// ---------------- host ----------------

extern "C" void kernel_launch(void* const* d_in, const int* in_sizes, int n_in,
                              void* d_out, int out_size, void* d_ws, size_t ws_size,
                              hipStream_t stream){
  (void)in_sizes; (void)n_in; (void)out_size; (void)ws_size;
  const int*   x     = (const int*)d_in[0];
  const unsigned char* m = (const unsigned char*)d_in[2];
  const float* emb   = (const float*)d_in[3];
  const float* convw = (const float*)d_in[4];
  const float* convb = (const float*)d_in[5];
  const float* lng   = (const float*)d_in[6];
  const float* lnb   = (const float*)d_in[7];
  const float* projw = (const float*)d_in[8];
  const float* projb = (const float*)d_in[9];

  char* ws = (char*)d_ws;
  size_t off = 0;
  auto alloc = [&](size_t bytes)->char*{
    char* p = ws + off; off += (bytes + 255) & ~((size_t)255); return p;
  };
  auto wt_conv = (__hip_bfloat16*)alloc((size_t)3*CCH*CCH*5*2);
  __hip_bfloat16 *w_in[2], *w_x[2], *w_dt[2], *w_out[2];
  for (int dir=0; dir<2; dir++){
    w_in[dir]  = (__hip_bfloat16*)alloc((size_t)2*DI*CCH*2);
    w_x[dir]   = (__hip_bfloat16*)alloc((size_t)64*DI*2);
    w_dt[dir]  = (__hip_bfloat16*)alloc((size_t)DI*DTR*2);
    w_out[dir] = (__hip_bfloat16*)alloc((size_t)CCH*DI*2);
  }
  auto w_proj  = (__hip_bfloat16*)alloc((size_t)CCH*1024*2);
  auto xpad0   = (__hip_bfloat16*)alloc((size_t)BSZ*(LSEQ+4)*CCH*2);
  auto xpad1   = (__hip_bfloat16*)alloc((size_t)BSZ*(LSEQ+4)*CCH*2);
  auto convtmp = (float*)alloc((size_t)BL*CCH*4);       // conv partial 0; later Hp (8 MB)
  auto h_enc   = (__hip_bfloat16*)alloc((size_t)BL*CCH*2);
  auto h_rev   = (__hip_bfloat16*)alloc((size_t)BL*CCH*2);
  auto xz      = (float*)alloc((size_t)BL*2*DI*4);
  auto u       = (float*)alloc((size_t)BL*DI*4);
  auto ub      = (__hip_bfloat16*)alloc((size_t)BL*DI*2);
  auto xdbc    = (float*)alloc((size_t)BL*64*4);
  auto dtb     = (unsigned short*)alloc((size_t)BL*DTR*2);
  auto dy      = (float*)alloc((size_t)BL*DI*4);        // conv partial 1 in encoder; delta in mamba
  auto yb      = (__hip_bfloat16*)alloc((size_t)BL*DI*2);
  auto fob     = (__hip_bfloat16*)alloc((size_t)BL*DI*2);

  // scan scratch: Hp reuses convtmp (8 MB); Pp reuses xpad0+xpad1 region (8.4 MB,
  // contiguous in ws, dead after the encoder finishes).
  float* Hp = convtmp;
  float* Pp = (float*)xpad0;

  auto nb = [](size_t n){ return (unsigned)((n + 255)/256); };

  // --- weight prep ---
  k_prep_convw<<<dim3(nb((size_t)3*CCH*CCH*5)), dim3(256), 0, stream>>>(convw, wt_conv);
  for (int dir=0; dir<2; dir++){
    int base = 10 + 9*dir;
    k_cast_b4<<<dim3(nb((size_t)2*DI*CCH/4)), dim3(256), 0, stream>>>((const float*)d_in[base+0], (unsigned short*)w_in[dir], 2*DI*CCH/4);
    k_cast_b4<<<dim3(nb((size_t)64*DI/4)),    dim3(256), 0, stream>>>((const float*)d_in[base+3], (unsigned short*)w_x[dir], 64*DI/4);
    k_cast_b4<<<dim3(nb((size_t)DI*DTR/4)),   dim3(256), 0, stream>>>((const float*)d_in[base+4], (unsigned short*)w_dt[dir], DI*DTR/4);
    k_cast_b4<<<dim3(nb((size_t)CCH*DI/4)),   dim3(256), 0, stream>>>((const float*)d_in[base+8], (unsigned short*)w_out[dir], CCH*DI/4);
  }
  k_cast_b4<<<dim3(nb((size_t)CCH*1024/4)), dim3(256), 0, stream>>>(projw, (unsigned short*)w_proj, CCH*1024/4);

  auto gemm_big = [&](const void* A, int lda, int padE, const void* W, void* C, int ldc, int coloff,
                  int M, int N, int Kc, int Kb, int kOff,
                  const float* bias, int act, const unsigned char* msk, bool outbf){
    int tiles_n = N/64;
    int blocks = (M/128)*tiles_n;
    if (outbf)
      k_gemm_big<true><<<dim3(blocks), dim3(256), 0, stream>>>((const __hip_bfloat16*)A, lda, padE,
          (const __hip_bfloat16*)W, C, ldc, coloff, tiles_n, Kc, Kb, kOff, bias, act, msk);
    else
      k_gemm_big<false><<<dim3(blocks), dim3(256), 0, stream>>>((const __hip_bfloat16*)A, lda, padE,
          (const __hip_bfloat16*)W, C, ldc, coloff, tiles_n, Kc, Kb, kOff, bias, act, msk);
  };

  // --- encoder: embed + 3x (conv-as-GEMM, 2-way K-split -> LN(sum)/leaky/mask) ---
  k_embed<<<dim3(nb((size_t)BSZ*(LSEQ+4)*CCH)), dim3(256), 0, stream>>>(x, emb, xpad0);
  k_zero_pads<<<dim3(nb((size_t)BSZ*4*CCH)), dim3(256), 0, stream>>>(xpad1);

  __hip_bfloat16* xp_in = xpad0;
  __hip_bfloat16* xp_out = xpad1;
  for (int layer=0; layer<3; layer++){
    const __hip_bfloat16* wt = wt_conv + (size_t)layer*CCH*CCH*5;
    gemm_big(xp_in, CCH, 4, wt, convtmp, CCH, 0, BL, CCH, 1280, 2560, 0,
             convb + layer*CCH, 0, nullptr, false);
    gemm_big(xp_in, CCH, 4, wt, dy,      CCH, 0, BL, CCH, 1280, 2560, 1280,
             nullptr, 0, nullptr, false);
    bool last = (layer==2);
    k_ln<<<dim3(BL), dim3(256), 0, stream>>>(convtmp, dy, lng + layer*CCH, lnb + layer*CCH, m,
        last ? nullptr : xp_out, last ? h_enc : nullptr, last ? h_rev : nullptr);
    __hip_bfloat16* t2 = xp_in; xp_in = xp_out; xp_out = t2;
  }

  // --- bidirectional mamba ---
  for (int dir=0; dir<2; dir++){
    int base = 10 + 9*dir;
    const float* mcw    = (const float*)d_in[base+1];
    const float* mcb    = (const float*)d_in[base+2];
    const float* dtbias = (const float*)d_in[base+5];
    const float* Alog   = (const float*)d_in[base+6];
    const float* Dp     = (const float*)d_in[base+7];
    const __hip_bfloat16* hin = (dir==0) ? h_enc : h_rev;

    gemm_big(hin, CCH, 0, w_in[dir], xz, 2*DI, 0, BL, 2*DI, CCH, CCH, 0, nullptr, 0, nullptr, false);
    k_dwconv<<<dim3(nb((size_t)BL*DI)), dim3(256), 0, stream>>>(xz, mcw, mcb, u, ub);
    k_gemm_ksplit<<<dim3(BL/64), dim3(256), 0, stream>>>(ub, DI, w_x[dir], xdbc, 64, DI, dtb);
    gemm_big(dtb, DTR, 0, w_dt[dir], dy, DI, 0, BL, DI, DTR, DTR, 0, dtbias, 1, nullptr, false);
    k_scan_part<<<dim3(512), dim3(256), 0, stream>>>(Alog, dy, u, xdbc, Hp, Pp);
    k_scan_comb<<<dim3(nb((size_t)BL*NST)), dim3(256), 0, stream>>>(Hp, Pp);
    k_scan_fin<<<dim3(512), dim3(256), 0, stream>>>(Alog, dy, u, xdbc, Pp, xz, Dp, yb);
    gemm_big(yb, DI, 0, w_out[dir], fob, DI, (dir==0)?0:512, BL, CCH, DI, DI, 0, nullptr, 0, nullptr, true);
  }

  // --- final projection + bias + mask -> d_out (f32) ---
  gemm_big(fob, DI, 0, w_proj, d_out, CCH, 0, BL, CCH, DI, DI, 0, projb, 0, m, false);
}

// Round 7
// 400.651 us; speedup vs baseline: 3.7143x; 1.1462x over previous
//
#include <hip/hip_runtime.h>
#include <hip/hip_bf16.h>

typedef __attribute__((ext_vector_type(8))) short short8;
typedef __attribute__((ext_vector_type(4))) float f32x4;
typedef __attribute__((ext_vector_type(4))) unsigned short ushort4_t;

#define BSZ 4
#define LSEQ 1024
#define CCH 512
#define BL (BSZ*LSEQ)   // 4096 rows
#define DI 1024         // d_inner
#define NST 16
#define DTR 32
#define NCH 32          // scan chunks
#define CLEN 32         // chunk length (NCH*CLEN == LSEQ)

__device__ __forceinline__ float sigmoidf_(float x){ return 1.f/(1.f+__expf(-x)); }
__device__ __forceinline__ float softplus_(float x){ return x > 20.f ? x : log1pf(__expf(x)); }
__device__ __forceinline__ unsigned short f2bf_(float f){
  __hip_bfloat16 h = __float2bfloat16(f); return *(unsigned short*)&h;
}

typedef const __attribute__((address_space(1))) unsigned int* gas_t;
typedef __attribute__((address_space(3))) unsigned int* las_t;
__device__ __forceinline__ void gload16(const void* g, void* l){
  __builtin_amdgcn_global_load_lds((gas_t)g, (las_t)l, 16, 0, 0);
}

// ---------------- prep / elementwise kernels ----------------

// all 9 f32->bf16 weight casts in ONE launch (region table in kernarg)
struct CastEnt { const float* s; unsigned short* d; unsigned n4, acc; };
struct CastArgs { CastEnt e[9]; unsigned total4; };
__global__ void k_cast_all(CastArgs a){
  unsigned i = blockIdx.x*256 + threadIdx.x;
  if (i >= a.total4) return;
  #pragma unroll
  for (int k=0;k<9;k++){
    if (i < a.e[k].acc + a.e[k].n4){
      unsigned j = i - a.e[k].acc;
      float4 v = ((const float4*)a.e[k].s)[j];
      ushort4_t o = { f2bf_(v.x), f2bf_(v.y), f2bf_(v.z), f2bf_(v.w) };
      *(ushort4_t*)(a.e[k].d + (size_t)j*4) = o;
      return;
    }
  }
}

// conv_w [3][512][512][5] -> wt [3][512][2560], j = k*512 + ci  (matches contiguous patch)
__global__ void k_prep_convw(const float* __restrict__ cw, __hip_bfloat16* __restrict__ wt){
  int i = blockIdx.x*256 + threadIdx.x;
  const int total = 3*CCH*CCH*5;
  if (i >= total) return;
  int j = i % (CCH*5);
  int co = (i/(CCH*5)) % CCH;
  int layer = i/(CCH*5*CCH);
  int k = j >> 9, ci = j & 511;
  wt[i] = __float2bfloat16(cw[(((size_t)layer*CCH + co)*CCH + ci)*5 + k]);
}

// gather emb[x] into padded [B][L+4][C] bf16; tail range zeroes xpad1's 4 pad rows
__global__ void k_embed(const int* __restrict__ x, const float* __restrict__ emb,
                        __hip_bfloat16* __restrict__ xpad0, __hip_bfloat16* __restrict__ xpad1){
  int i = blockIdx.x*256 + threadIdx.x;
  const int total = BSZ*(LSEQ+4)*CCH;
  const int total2 = total + BSZ*4*CCH;
  if (i >= total2) return;
  if (i >= total){
    int j = i - total;
    int c = j & (CCH-1);
    int pr = (j >> 9) & 3;
    int b = j >> 11;
    int rr = (pr < 2) ? pr : (LSEQ+2) + (pr-2);
    xpad1[((size_t)b*(LSEQ+4) + rr)*CCH + c] = __float2bfloat16(0.f);
    return;
  }
  int c = i & (CCH-1);
  int r = (i >> 9) % (LSEQ+4);
  int b = i / ((LSEQ+4)*CCH);
  float v = 0.f;
  if (r >= 2 && r < LSEQ+2){
    int tok = x[b*LSEQ + (r-2)];
    v = emb[(size_t)tok*CCH + c];
  }
  xpad0[i] = __float2bfloat16(v);
}

// per-(b,l) channel LayerNorm + scale/shift + LeakyReLU(0.2) + mask
__global__ __launch_bounds__(256) void k_ln(
    const float* __restrict__ in, const float* __restrict__ g, const float* __restrict__ bb,
    const unsigned char* __restrict__ mask,
    __hip_bfloat16* __restrict__ xpad_next,
    __hip_bfloat16* __restrict__ h_enc, __hip_bfloat16* __restrict__ h_rev){
  int row = blockIdx.x;                 // b*1024 + l
  int b = row >> 10, l = row & 1023;
  const float* xr = in + (size_t)row*CCH;
  int t = threadIdx.x;
  float v0 = xr[t], v1 = xr[t+256];
  float s = v0+v1, s2 = v0*v0 + v1*v1;
  #pragma unroll
  for (int off=32; off>0; off>>=1){ s += __shfl_down(s,off); s2 += __shfl_down(s2,off); }
  __shared__ float ls[8];
  if ((t&63)==0){ ls[t>>6] = s; ls[(t>>6)+4] = s2; }
  __syncthreads();
  float S  = ls[0]+ls[1]+ls[2]+ls[3];
  float S2 = ls[4]+ls[5]+ls[6]+ls[7];
  float mu = S*(1.f/CCH);
  float var = S2*(1.f/CCH) - mu*mu;
  float rs = rsqrtf(var + 1e-5f);
  bool mk = mask[row] != 0;
  #pragma unroll
  for (int e=0; e<2; e++){
    int c = t + e*256;
    float v = e ? v1 : v0;
    float h = (v-mu)*rs*g[c] + bb[c];
    h = h > 0.f ? h : 0.2f*h;
    if (mk) h = 0.f;
    __hip_bfloat16 hb = __float2bfloat16(h);
    if (xpad_next) xpad_next[((size_t)b*(LSEQ+4) + (l+2))*CCH + c] = hb;
    if (h_enc) h_enc[(size_t)row*CCH + c] = hb;
    if (h_rev) h_rev[((size_t)(b<<10) + (1023-l))*CCH + c] = hb;
  }
}

// ---------------- K-split GEMM for skinny N=64 (x_proj), fused dt bf16 extract --------
__global__ __launch_bounds__(256) void k_gemm_ksplit(
    const __hip_bfloat16* __restrict__ A, int lda,
    const __hip_bfloat16* __restrict__ W, float* __restrict__ Cout,
    int ldc, int K, unsigned short* __restrict__ dtb){
  __shared__ float red[4*4096];   // 64 KB
  int m0 = blockIdx.x << 6;
  int tid = threadIdx.x;
  int w = tid >> 6, lane = tid & 63;
  int r = lane & 15, kg = lane >> 4;
  int Kw = K >> 2;
  int kbase = w*Kw;

  const short* Ap[4];
  const short* Wp[4];
  #pragma unroll
  for (int mi=0; mi<4; mi++)
    Ap[mi] = (const short*)A + (size_t)(m0 + mi*16 + r)*lda + kbase + kg*8;
  #pragma unroll
  for (int nj=0; nj<4; nj++)
    Wp[nj] = (const short*)W + (size_t)(nj*16 + r)*K + kbase + kg*8;

  f32x4 acc[4][4];
  #pragma unroll
  for (int mi=0;mi<4;mi++)
    #pragma unroll
    for (int nj=0;nj<4;nj++) acc[mi][nj] = (f32x4){0.f,0.f,0.f,0.f};

  for (int kk=0; kk<Kw; kk+=32){
    short8 a[4], wv[4];
    #pragma unroll
    for (int mi=0;mi<4;mi++) a[mi] = *(const short8*)(Ap[mi] + kk);
    #pragma unroll
    for (int nj=0;nj<4;nj++) wv[nj] = *(const short8*)(Wp[nj] + kk);
    #pragma unroll
    for (int mi=0;mi<4;mi++)
      #pragma unroll
      for (int nj=0;nj<4;nj++)
        acc[mi][nj] = __builtin_amdgcn_mfma_f32_16x16x32_bf16(a[mi], wv[nj], acc[mi][nj], 0,0,0);
  }
  #pragma unroll
  for (int mi=0;mi<4;mi++)
    #pragma unroll
    for (int nj=0;nj<4;nj++)
      #pragma unroll
      for (int reg=0; reg<4; reg++){
        int rowt = mi*16 + kg*4 + reg;
        int col  = nj*16 + r;
        red[w*4096 + rowt*64 + col] = acc[mi][nj][reg];
      }
  __syncthreads();
  int e0 = tid*16;
  #pragma unroll
  for (int j=0; j<16; j+=4){
    f32x4 s = *(const f32x4*)&red[e0+j];
    #pragma unroll
    for (int ww=1; ww<4; ww++){
      f32x4 p = *(const f32x4*)&red[ww*4096 + e0 + j];
      s.x += p.x; s.y += p.y; s.z += p.z; s.w += p.w;
    }
    int e = e0 + j;
    int rowt = e >> 6, col = e & 63;
    *(f32x4*)&Cout[(size_t)(m0+rowt)*ldc + col] = s;
    if (col < 32){
      ushort4_t o = { f2bf_(s.x), f2bf_(s.y), f2bf_(s.z), f2bf_(s.w) };
      *(ushort4_t*)&dtb[(size_t)(m0+rowt)*32 + col] = o;
    }
  }
}

// ---------------- big staged GEMM: 64(M)x64(N) tile, BK=32, 4 waves ----------------
// Each wave owns a 32x32 sub-tile (2x2 16x16 fragments). 3-buffer LDS ring (24 KB),
// prefetch depth 2, counted s_waitcnt vmcnt(2) (2 global_load_lds per wave per tile).
// Smaller tile doubles the grid vs 128x64 -> 2-8 blocks/CU so barrier/load stalls
// of co-resident blocks interleave (the TLP the 1-block/CU version lacked).
template<bool OUTBF>
__global__ __launch_bounds__(256) void k_gemm_big(
    const __hip_bfloat16* __restrict__ A, int lda, int padExtra,
    const __hip_bfloat16* __restrict__ W, void* __restrict__ Cout,
    int ldc, int coloff, int tiles_n, int Kc, int Kb, int kOff,
    const float* __restrict__ bias, int act, const unsigned char* __restrict__ mask){
  __shared__ alignas(16) __hip_bfloat16 smem[3][4096];   // 3 x (2048 A + 2048 B) = 24 KB
  int tn = blockIdx.x % tiles_n;
  int tm = blockIdx.x / tiles_n;
  int m0 = tm*64, n0 = tn*64;
  int tid = threadIdx.x;
  int wid = tid >> 6, lane = tid & 63;
  int r = lane & 15, kg = lane >> 4;

  int sr = lane >> 2;                 // 16 sub-rows per wave chunk
  int gs = (lane & 3) ^ (sr & 3);     // swizzled global 16B-slot
  int arow = m0 + wid*16 + sr;
  int pa = arow + padExtra*(arow >> 10);
  size_t aoff = (size_t)pa*lda + kOff + gs*8;
  int bcol = n0 + wid*16 + sr;
  size_t boff = (size_t)bcol*Kb + kOff + gs*8;

  int wr = wid >> 1, wc = wid & 1;
  int xs = (kg ^ (r & 3))*8;
  int afrag[2], bfrag[2];
  #pragma unroll
  for (int mi=0; mi<2; mi++) afrag[mi] = (wr*32 + mi*16 + r)*32 + xs;
  #pragma unroll
  for (int nj=0; nj<2; nj++) bfrag[nj] = 2048 + (wc*32 + nj*16 + r)*32 + xs;

  f32x4 acc[2][2];
  #pragma unroll
  for (int mi=0;mi<2;mi++)
    #pragma unroll
    for (int nj=0;nj<2;nj++) acc[mi][nj] = (f32x4){0.f,0.f,0.f,0.f};

  const int nt = Kc >> 5;
  auto stage = [&](int kt, int bufi){
    __hip_bfloat16* sb = &smem[bufi][0];
    int k0 = kt*32;
    gload16((const short*)A + aoff + k0, sb + wid*512);
    gload16((const short*)W + boff + k0, sb + 2048 + wid*512);
  };
  auto compute = [&](int bufi){
    const __hip_bfloat16* sb = &smem[bufi][0];
    short8 a[2], b[2];
    #pragma unroll
    for (int mi=0;mi<2;mi++) a[mi] = *(const short8*)&sb[afrag[mi]];
    #pragma unroll
    for (int nj=0;nj<2;nj++) b[nj] = *(const short8*)&sb[bfrag[nj]];
    #pragma unroll
    for (int mi=0;mi<2;mi++)
      #pragma unroll
      for (int nj=0;nj<2;nj++)
        acc[mi][nj] = __builtin_amdgcn_mfma_f32_16x16x32_bf16(a[mi], b[nj], acc[mi][nj], 0,0,0);
  };

  stage(0, 0);
  if (nt > 1) stage(1, 1);
  int bi = 0;
  for (int t=0; t<nt-1; t++){
    asm volatile("s_waitcnt vmcnt(2)" ::: "memory");
    __builtin_amdgcn_s_barrier();
    __builtin_amdgcn_sched_barrier(0);
    if (t+2 < nt){
      int nb2 = bi + 2; if (nb2 >= 3) nb2 -= 3;
      stage(t+2, nb2);
    }
    compute(bi);
    bi = (bi+1 == 3) ? 0 : bi+1;
  }
  asm volatile("s_waitcnt vmcnt(0)" ::: "memory");
  __builtin_amdgcn_s_barrier();
  __builtin_amdgcn_sched_barrier(0);
  compute(bi);

  #pragma unroll
  for (int mi=0;mi<2;mi++){
    #pragma unroll
    for (int nj=0;nj<2;nj++){
      #pragma unroll
      for (int reg=0; reg<4; reg++){
        int row = m0 + wr*32 + mi*16 + kg*4 + reg;
        int col = n0 + wc*32 + nj*16 + r;
        float v = acc[mi][nj][reg];
        if (bias) v += bias[col];
        if (act == 1) v = softplus_(v);
        if (mask && mask[row]) v = 0.f;
        size_t o = (size_t)row*ldc + coloff + col;
        if (OUTBF) ((__hip_bfloat16*)Cout)[o] = __float2bfloat16(v);
        else       ((float*)Cout)[o] = v;
      }
    }
  }
}

// ---------------- mamba pieces ----------------

__global__ void k_dwconv(const float* __restrict__ xz, const float* __restrict__ cw,
                         const float* __restrict__ cb, float* __restrict__ u,
                         __hip_bfloat16* __restrict__ ub){
  int i = blockIdx.x*256 + threadIdx.x;
  if (i >= BL*DI) return;
  int d = i & (DI-1);
  int row = i >> 10;
  int l = row & 1023;
  int rb = row & ~1023;
  float acc = cb[d];
  #pragma unroll
  for (int k=0;k<4;k++){
    int ll = l - 3 + k;
    if (ll >= 0) acc += cw[d*4 + k] * xz[(size_t)(rb + ll)*(2*DI) + d];
  }
  float s = acc * sigmoidf_(acc);
  u[i] = s;
  ub[i] = __float2bfloat16(s);
}

// -------- chunked selective scan, thread-per-d, state vector in registers --------

__global__ __launch_bounds__(256) void k_scan_part(
    const float* __restrict__ A_log, const float* __restrict__ dy,
    const float* __restrict__ u, const float* __restrict__ xdbc,
    float* __restrict__ Hp, float* __restrict__ Pp){
  __shared__ alignas(16) float Bsh[CLEN*16];
  int t = threadIdx.x;
  int dblk = blockIdx.x & 3;
  int c = (blockIdx.x >> 2) & (NCH-1);
  int b = blockIdx.x >> 7;
  int d = dblk*256 + t;
  size_t blbase = (size_t)b*LSEQ + (size_t)c*CLEN;
  if (t < CLEN*4){
    int l = t >> 2, q = t & 3;
    *(f32x4*)&Bsh[l*16 + q*4] = *(const f32x4*)&xdbc[(blbase+l)*64 + 32 + q*4];
  }
  float Af[16];
  #pragma unroll
  for (int n=0; n<16; n+=4){
    f32x4 a = *(const f32x4*)&A_log[(size_t)d*16 + n];
    Af[n]   = -__expf(a.x); Af[n+1] = -__expf(a.y);
    Af[n+2] = -__expf(a.z); Af[n+3] = -__expf(a.w);
  }
  float h[16], P[16];
  #pragma unroll
  for (int n=0;n<16;n++){ h[n]=0.f; P[n]=1.f; }
  __syncthreads();
  float dv = dy[blbase*DI + d];
  float uv = u[blbase*DI + d];
  for (int l=0; l<CLEN; l++){
    float dvn = 0.f, uvn = 0.f;
    if (l+1 < CLEN){
      dvn = dy[(blbase+l+1)*DI + d];
      uvn = u[(blbase+l+1)*DI + d];
    }
    float duv = dv*uv;
    #pragma unroll
    for (int n=0;n<16;n++){
      float dA = __expf(dv*Af[n]);
      h[n] = __fmaf_rn(dA, h[n], duv*Bsh[l*16+n]);
      P[n] *= dA;
    }
    dv = dvn; uv = uvn;
  }
  size_t pb = (((size_t)(b*NCH + c))*DI + d)*16;
  #pragma unroll
  for (int n=0;n<16;n+=4){
    *(f32x4*)&Hp[pb+n] = (f32x4){h[n],h[n+1],h[n+2],h[n+3]};
    *(f32x4*)&Pp[pb+n] = (f32x4){P[n],P[n+1],P[n+2],P[n+3]};
  }
}

// combine: h_in[c+1] = P[c]*h_in[c] + H[c]; writes h_in back into Pp (in place)
__global__ void k_scan_comb(float* __restrict__ Hp, float* __restrict__ Pp){
  int i = blockIdx.x*256 + threadIdx.x;   // (b*1024+d)*16 + n
  if (i >= BL*NST) return;
  int n = i & 15, row = i >> 4;
  int b = row >> 10, d = row & 1023;
  float hin = 0.f;
  #pragma unroll
  for (int c=0;c<NCH;c++){
    size_t idx = (((size_t)(b*NCH + c))*DI + d)*16 + n;
    float P = Pp[idx], H = Hp[idx];
    Pp[idx] = hin;
    hin = __fmaf_rn(P, hin, H);
  }
}

// final pass: recompute chunk states from h_in, emit y fused with ygate -> yb (bf16)
__global__ __launch_bounds__(256) void k_scan_fin(
    const float* __restrict__ A_log, const float* __restrict__ dy,
    const float* __restrict__ u, const float* __restrict__ xdbc,
    const float* __restrict__ Hin, const float* __restrict__ xz,
    const float* __restrict__ Dp, __hip_bfloat16* __restrict__ yb){
  __shared__ alignas(16) float BCsh[CLEN*32];
  int t = threadIdx.x;
  int dblk = blockIdx.x & 3;
  int c = (blockIdx.x >> 2) & (NCH-1);
  int b = blockIdx.x >> 7;
  int d = dblk*256 + t;
  size_t blbase = (size_t)b*LSEQ + (size_t)c*CLEN;
  {
    int l = t >> 3, q = t & 7;   // 256 threads cover 32 rows x 8 quads
    *(f32x4*)&BCsh[l*32 + q*4] = *(const f32x4*)&xdbc[(blbase+l)*64 + 32 + q*4];
  }
  float Af[16];
  #pragma unroll
  for (int n=0; n<16; n+=4){
    f32x4 a = *(const f32x4*)&A_log[(size_t)d*16 + n];
    Af[n]   = -__expf(a.x); Af[n+1] = -__expf(a.y);
    Af[n+2] = -__expf(a.z); Af[n+3] = -__expf(a.w);
  }
  size_t pb = (((size_t)(b*NCH + c))*DI + d)*16;
  float h[16];
  #pragma unroll
  for (int n=0;n<16;n+=4){
    f32x4 hv = *(const f32x4*)&Hin[pb+n];
    h[n]=hv.x; h[n+1]=hv.y; h[n+2]=hv.z; h[n+3]=hv.w;
  }
  float Dd = Dp[d];
  __syncthreads();
  float dv = dy[blbase*DI + d];
  float uv = u[blbase*DI + d];
  float zv = xz[blbase*(2*DI) + DI + d];
  for (int l=0; l<CLEN; l++){
    float dvn = 0.f, uvn = 0.f, zvn = 0.f;
    if (l+1 < CLEN){
      dvn = dy[(blbase+l+1)*DI + d];
      uvn = u[(blbase+l+1)*DI + d];
      zvn = xz[(blbase+l+1)*(2*DI) + DI + d];
    }
    float duv = dv*uv;
    float y = 0.f;
    #pragma unroll
    for (int n=0;n<16;n++){
      float dA = __expf(dv*Af[n]);
      h[n] = __fmaf_rn(dA, h[n], duv*BCsh[l*32+n]);
      y = __fmaf_rn(h[n], BCsh[l*32+16+n], y);
    }
    float g = zv * sigmoidf_(zv);
    float out = __fmaf_rn(uv, Dd, y) * g;
    yb[(blbase+l)*DI + d] = __float2bfloat16(out);
    dv = dvn; uv = uvn; zv = zvn;
  }
}

// ---------------- host ----------------

extern "C" void kernel_launch(void* const* d_in, const int* in_sizes, int n_in,
                              void* d_out, int out_size, void* d_ws, size_t ws_size,
                              hipStream_t stream){
  (void)in_sizes; (void)n_in; (void)out_size; (void)ws_size;
  const int*   x     = (const int*)d_in[0];
  const unsigned char* m = (const unsigned char*)d_in[2];
  const float* emb   = (const float*)d_in[3];
  const float* convw = (const float*)d_in[4];
  const float* convb = (const float*)d_in[5];
  const float* lng   = (const float*)d_in[6];
  const float* lnb   = (const float*)d_in[7];
  const float* projw = (const float*)d_in[8];
  const float* projb = (const float*)d_in[9];

  char* ws = (char*)d_ws;
  size_t off = 0;
  auto alloc = [&](size_t bytes)->char*{
    char* p = ws + off; off += (bytes + 255) & ~((size_t)255); return p;
  };
  auto wt_conv = (__hip_bfloat16*)alloc((size_t)3*CCH*CCH*5*2);
  __hip_bfloat16 *w_in[2], *w_x[2], *w_dt[2], *w_out[2];
  for (int dir=0; dir<2; dir++){
    w_in[dir]  = (__hip_bfloat16*)alloc((size_t)2*DI*CCH*2);
    w_x[dir]   = (__hip_bfloat16*)alloc((size_t)64*DI*2);
    w_dt[dir]  = (__hip_bfloat16*)alloc((size_t)DI*DTR*2);
    w_out[dir] = (__hip_bfloat16*)alloc((size_t)CCH*DI*2);
  }
  auto w_proj  = (__hip_bfloat16*)alloc((size_t)CCH*1024*2);
  auto xpad0   = (__hip_bfloat16*)alloc((size_t)BSZ*(LSEQ+4)*CCH*2);
  auto xpad1   = (__hip_bfloat16*)alloc((size_t)BSZ*(LSEQ+4)*CCH*2);
  auto convtmp = (float*)alloc((size_t)BL*CCH*4);       // conv out; later Hp (8 MB)
  auto h_enc   = (__hip_bfloat16*)alloc((size_t)BL*CCH*2);
  auto h_rev   = (__hip_bfloat16*)alloc((size_t)BL*CCH*2);
  auto xz      = (float*)alloc((size_t)BL*2*DI*4);
  auto u       = (float*)alloc((size_t)BL*DI*4);
  auto ub      = (__hip_bfloat16*)alloc((size_t)BL*DI*2);
  auto xdbc    = (float*)alloc((size_t)BL*64*4);
  auto dtb     = (unsigned short*)alloc((size_t)BL*DTR*2);
  auto dy      = (float*)alloc((size_t)BL*DI*4);        // delta (read-only in scan)
  auto yb      = (__hip_bfloat16*)alloc((size_t)BL*DI*2);
  auto fob     = (__hip_bfloat16*)alloc((size_t)BL*DI*2);

  // scan scratch: Hp reuses convtmp (8 MB); Pp reuses xpad0+xpad1 region (8.4 MB,
  // contiguous in ws, dead after the encoder finishes).
  float* Hp = convtmp;
  float* Pp = (float*)xpad0;

  auto nb = [](size_t n){ return (unsigned)((n + 255)/256); };

  // --- weight prep: conv transpose-cast + 9 casts in one launch ---
  k_prep_convw<<<dim3(nb((size_t)3*CCH*CCH*5)), dim3(256), 0, stream>>>(convw, wt_conv);
  {
    CastArgs ca;
    unsigned acc = 0;
    auto put = [&](int k, const void* s, void* d, unsigned n4){
      ca.e[k].s = (const float*)s; ca.e[k].d = (unsigned short*)d;
      ca.e[k].n4 = n4; ca.e[k].acc = acc; acc += n4;
    };
    for (int dir=0; dir<2; dir++){
      int base = 10 + 9*dir;
      put(dir*4+0, d_in[base+0], w_in[dir],  (2*DI*CCH)/4);
      put(dir*4+1, d_in[base+3], w_x[dir],   (64*DI)/4);
      put(dir*4+2, d_in[base+4], w_dt[dir],  (DI*DTR)/4);
      put(dir*4+3, d_in[base+8], w_out[dir], (CCH*DI)/4);
    }
    put(8, projw, w_proj, (CCH*1024)/4);
    ca.total4 = acc;
    k_cast_all<<<dim3(nb(acc)), dim3(256), 0, stream>>>(ca);
  }

  auto gemm_big = [&](const void* A, int lda, int padE, const void* W, void* C, int ldc, int coloff,
                  int M, int N, int Kc, int Kb, int kOff,
                  const float* bias, int act, const unsigned char* msk, bool outbf){
    int tiles_n = N/64;
    int blocks = (M/64)*tiles_n;
    if (outbf)
      k_gemm_big<true><<<dim3(blocks), dim3(256), 0, stream>>>((const __hip_bfloat16*)A, lda, padE,
          (const __hip_bfloat16*)W, C, ldc, coloff, tiles_n, Kc, Kb, kOff, bias, act, msk);
    else
      k_gemm_big<false><<<dim3(blocks), dim3(256), 0, stream>>>((const __hip_bfloat16*)A, lda, padE,
          (const __hip_bfloat16*)W, C, ldc, coloff, tiles_n, Kc, Kb, kOff, bias, act, msk);
  };

  // --- encoder: embed(+pad-zero) + 3x (conv-as-GEMM -> LN/leaky/mask) ---
  k_embed<<<dim3(nb((size_t)BSZ*(LSEQ+4)*CCH + BSZ*4*CCH)), dim3(256), 0, stream>>>(x, emb, xpad0, xpad1);

  __hip_bfloat16* xp_in = xpad0;
  __hip_bfloat16* xp_out = xpad1;
  for (int layer=0; layer<3; layer++){
    const __hip_bfloat16* wt = wt_conv + (size_t)layer*CCH*CCH*5;
    gemm_big(xp_in, CCH, 4, wt, convtmp, CCH, 0, BL, CCH, 2560, 2560, 0,
             convb + layer*CCH, 0, nullptr, false);
    bool last = (layer==2);
    k_ln<<<dim3(BL), dim3(256), 0, stream>>>(convtmp, lng + layer*CCH, lnb + layer*CCH, m,
        last ? nullptr : xp_out, last ? h_enc : nullptr, last ? h_rev : nullptr);
    __hip_bfloat16* t2 = xp_in; xp_in = xp_out; xp_out = t2;
  }

  // --- bidirectional mamba ---
  for (int dir=0; dir<2; dir++){
    int base = 10 + 9*dir;
    const float* mcw    = (const float*)d_in[base+1];
    const float* mcb    = (const float*)d_in[base+2];
    const float* dtbias = (const float*)d_in[base+5];
    const float* Alog   = (const float*)d_in[base+6];
    const float* Dp     = (const float*)d_in[base+7];
    const __hip_bfloat16* hin = (dir==0) ? h_enc : h_rev;

    gemm_big(hin, CCH, 0, w_in[dir], xz, 2*DI, 0, BL, 2*DI, CCH, CCH, 0, nullptr, 0, nullptr, false);
    k_dwconv<<<dim3(nb((size_t)BL*DI)), dim3(256), 0, stream>>>(xz, mcw, mcb, u, ub);
    k_gemm_ksplit<<<dim3(BL/64), dim3(256), 0, stream>>>(ub, DI, w_x[dir], xdbc, 64, DI, dtb);
    gemm_big(dtb, DTR, 0, w_dt[dir], dy, DI, 0, BL, DI, DTR, DTR, 0, dtbias, 1, nullptr, false);
    k_scan_part<<<dim3(512), dim3(256), 0, stream>>>(Alog, dy, u, xdbc, Hp, Pp);
    k_scan_comb<<<dim3(nb((size_t)BL*NST)), dim3(256), 0, stream>>>(Hp, Pp);
    k_scan_fin<<<dim3(512), dim3(256), 0, stream>>>(Alog, dy, u, xdbc, Pp, xz, Dp, yb);
    gemm_big(yb, DI, 0, w_out[dir], fob, DI, (dir==0)?0:512, BL, CCH, DI, DI, 0, nullptr, 0, nullptr, true);
  }

  // --- final projection + bias + mask -> d_out (f32) ---
  gemm_big(fob, DI, 0, w_proj, d_out, CCH, 0, BL, CCH, DI, DI, 0, projb, 0, m, false);
}

// Round 8
// 379.293 us; speedup vs baseline: 3.9234x; 1.0563x over previous
//
#include <hip/hip_runtime.h>
#include <hip/hip_bf16.h>

typedef __attribute__((ext_vector_type(8))) short short8;
typedef __attribute__((ext_vector_type(4))) float f32x4;
typedef __attribute__((ext_vector_type(4))) unsigned short ushort4_t;

#define BSZ 4
#define LSEQ 1024
#define CCH 512
#define BL (BSZ*LSEQ)   // 4096 rows
#define BL2 (2*BL)      // both directions batched: 8192 rows
#define DI 1024         // d_inner
#define NST 16
#define DTR 32
#define NCH 32          // scan chunks
#define CLEN 32         // chunk length (NCH*CLEN == LSEQ)

__device__ __forceinline__ float sigmoidf_(float x){ return 1.f/(1.f+__expf(-x)); }
__device__ __forceinline__ float softplus_(float x){ return x > 20.f ? x : log1pf(__expf(x)); }
__device__ __forceinline__ unsigned short f2bf_(float f){
  __hip_bfloat16 h = __float2bfloat16(f); return *(unsigned short*)&h;
}

typedef const __attribute__((address_space(1))) unsigned int* gas_t;
typedef __attribute__((address_space(3))) unsigned int* las_t;
__device__ __forceinline__ void gload16(const void* g, void* l){
  __builtin_amdgcn_global_load_lds((gas_t)g, (las_t)l, 16, 0, 0);
}

// ---------------- prep / elementwise kernels ----------------

// all 9 f32->bf16 weight casts in ONE launch (region table in kernarg)
struct CastEnt { const float* s; unsigned short* d; unsigned n4, acc; };
struct CastArgs { CastEnt e[9]; unsigned total4; };
__global__ void k_cast_all(CastArgs a){
  unsigned i = blockIdx.x*256 + threadIdx.x;
  if (i >= a.total4) return;
  #pragma unroll
  for (int k=0;k<9;k++){
    if (i < a.e[k].acc + a.e[k].n4){
      unsigned j = i - a.e[k].acc;
      float4 v = ((const float4*)a.e[k].s)[j];
      ushort4_t o = { f2bf_(v.x), f2bf_(v.y), f2bf_(v.z), f2bf_(v.w) };
      *(ushort4_t*)(a.e[k].d + (size_t)j*4) = o;
      return;
    }
  }
}

// conv_w [3][512][512][5] -> wt [3][512][2560], j = k*512 + ci  (matches contiguous patch)
__global__ void k_prep_convw(const float* __restrict__ cw, __hip_bfloat16* __restrict__ wt){
  int i = blockIdx.x*256 + threadIdx.x;
  const int total = 3*CCH*CCH*5;
  if (i >= total) return;
  int j = i % (CCH*5);
  int co = (i/(CCH*5)) % CCH;
  int layer = i/(CCH*5*CCH);
  int k = j >> 9, ci = j & 511;
  wt[i] = __float2bfloat16(cw[(((size_t)layer*CCH + co)*CCH + ci)*5 + k]);
}

// gather emb[x] into padded [B][L+4][C] bf16; tail range zeroes xpad1's 4 pad rows
__global__ void k_embed(const int* __restrict__ x, const float* __restrict__ emb,
                        __hip_bfloat16* __restrict__ xpad0, __hip_bfloat16* __restrict__ xpad1){
  int i = blockIdx.x*256 + threadIdx.x;
  const int total = BSZ*(LSEQ+4)*CCH;
  const int total2 = total + BSZ*4*CCH;
  if (i >= total2) return;
  if (i >= total){
    int j = i - total;
    int c = j & (CCH-1);
    int pr = (j >> 9) & 3;
    int b = j >> 11;
    int rr = (pr < 2) ? pr : (LSEQ+2) + (pr-2);
    xpad1[((size_t)b*(LSEQ+4) + rr)*CCH + c] = __float2bfloat16(0.f);
    return;
  }
  int c = i & (CCH-1);
  int r = (i >> 9) % (LSEQ+4);
  int b = i / ((LSEQ+4)*CCH);
  float v = 0.f;
  if (r >= 2 && r < LSEQ+2){
    int tok = x[b*LSEQ + (r-2)];
    v = emb[(size_t)tok*CCH + c];
  }
  xpad0[i] = __float2bfloat16(v);
}

// per-(b,l) channel LayerNorm over (in + in2) + scale/shift + LeakyReLU(0.2) + mask
__global__ __launch_bounds__(256) void k_ln(
    const float* __restrict__ in, const float* __restrict__ in2,
    const float* __restrict__ g, const float* __restrict__ bb,
    const unsigned char* __restrict__ mask,
    __hip_bfloat16* __restrict__ xpad_next,
    __hip_bfloat16* __restrict__ h_enc, __hip_bfloat16* __restrict__ h_rev){
  int row = blockIdx.x;                 // b*1024 + l
  int b = row >> 10, l = row & 1023;
  const float* xr = in + (size_t)row*CCH;
  const float* xr2 = in2 + (size_t)row*CCH;
  int t = threadIdx.x;
  float v0 = xr[t] + xr2[t], v1 = xr[t+256] + xr2[t+256];
  float s = v0+v1, s2 = v0*v0 + v1*v1;
  #pragma unroll
  for (int off=32; off>0; off>>=1){ s += __shfl_down(s,off); s2 += __shfl_down(s2,off); }
  __shared__ float ls[8];
  if ((t&63)==0){ ls[t>>6] = s; ls[(t>>6)+4] = s2; }
  __syncthreads();
  float S  = ls[0]+ls[1]+ls[2]+ls[3];
  float S2 = ls[4]+ls[5]+ls[6]+ls[7];
  float mu = S*(1.f/CCH);
  float var = S2*(1.f/CCH) - mu*mu;
  float rs = rsqrtf(var + 1e-5f);
  bool mk = mask[row] != 0;
  #pragma unroll
  for (int e=0; e<2; e++){
    int c = t + e*256;
    float v = e ? v1 : v0;
    float h = (v-mu)*rs*g[c] + bb[c];
    h = h > 0.f ? h : 0.2f*h;
    if (mk) h = 0.f;
    __hip_bfloat16 hb = __float2bfloat16(h);
    if (xpad_next) xpad_next[((size_t)b*(LSEQ+4) + (l+2))*CCH + c] = hb;
    if (h_enc) h_enc[(size_t)row*CCH + c] = hb;
    if (h_rev) h_rev[((size_t)(b<<10) + (1023-l))*CCH + c] = hb;
  }
}

// ---------------- K-split GEMM for skinny N=64 (x_proj), batched dirs ----------------
__global__ __launch_bounds__(256) void k_gemm_ksplit(
    const __hip_bfloat16* __restrict__ A, int lda,
    const __hip_bfloat16* __restrict__ W, size_t wStride,
    float* __restrict__ Cout, int ldc, int K, unsigned short* __restrict__ dtb){
  __shared__ float red[4*4096];   // 64 KB
  int m0 = blockIdx.x << 6;
  const __hip_bfloat16* Wd = W + (size_t)(m0 >> 12)*wStride;
  int tid = threadIdx.x;
  int w = tid >> 6, lane = tid & 63;
  int r = lane & 15, kg = lane >> 4;
  int Kw = K >> 2;
  int kbase = w*Kw;

  const short* Ap[4];
  const short* Wp[4];
  #pragma unroll
  for (int mi=0; mi<4; mi++)
    Ap[mi] = (const short*)A + (size_t)(m0 + mi*16 + r)*lda + kbase + kg*8;
  #pragma unroll
  for (int nj=0; nj<4; nj++)
    Wp[nj] = (const short*)Wd + (size_t)(nj*16 + r)*K + kbase + kg*8;

  f32x4 acc[4][4];
  #pragma unroll
  for (int mi=0;mi<4;mi++)
    #pragma unroll
    for (int nj=0;nj<4;nj++) acc[mi][nj] = (f32x4){0.f,0.f,0.f,0.f};

  for (int kk=0; kk<Kw; kk+=32){
    short8 a[4], wv[4];
    #pragma unroll
    for (int mi=0;mi<4;mi++) a[mi] = *(const short8*)(Ap[mi] + kk);
    #pragma unroll
    for (int nj=0;nj<4;nj++) wv[nj] = *(const short8*)(Wp[nj] + kk);
    #pragma unroll
    for (int mi=0;mi<4;mi++)
      #pragma unroll
      for (int nj=0;nj<4;nj++)
        acc[mi][nj] = __builtin_amdgcn_mfma_f32_16x16x32_bf16(a[mi], wv[nj], acc[mi][nj], 0,0,0);
  }
  #pragma unroll
  for (int mi=0;mi<4;mi++)
    #pragma unroll
    for (int nj=0;nj<4;nj++)
      #pragma unroll
      for (int reg=0; reg<4; reg++){
        int rowt = mi*16 + kg*4 + reg;
        int col  = nj*16 + r;
        red[w*4096 + rowt*64 + col] = acc[mi][nj][reg];
      }
  __syncthreads();
  int e0 = tid*16;
  #pragma unroll
  for (int j=0; j<16; j+=4){
    f32x4 s = *(const f32x4*)&red[e0+j];
    #pragma unroll
    for (int ww=1; ww<4; ww++){
      f32x4 p = *(const f32x4*)&red[ww*4096 + e0 + j];
      s.x += p.x; s.y += p.y; s.z += p.z; s.w += p.w;
    }
    int e = e0 + j;
    int rowt = e >> 6, col = e & 63;
    *(f32x4*)&Cout[(size_t)(m0+rowt)*ldc + col] = s;
    if (col < 32){
      ushort4_t o = { f2bf_(s.x), f2bf_(s.y), f2bf_(s.z), f2bf_(s.w) };
      *(ushort4_t*)&dtb[(size_t)(m0+rowt)*32 + col] = o;
    }
  }
}

// ---------------- big staged GEMM: 64(M)x64(N) tile, BK=32, 4 waves ----------------
// 3-buffer LDS ring, counted vmcnt(2) + raw s_barrier. Supports:
//  - in-dispatch K-split: blocks >= baseBlocks compute K=[Kc,2Kc) into C1 (no bias)
//  - batched directions: dir = m0>>12 selects W (+wStride), bias (+biasStride),
//    output row - outRowSub and column + dirColOff.
template<bool OUTBF>
__global__ __launch_bounds__(256) void k_gemm_big(
    const __hip_bfloat16* __restrict__ A, int lda, int padExtra,
    const __hip_bfloat16* __restrict__ W, size_t wStride,
    void* __restrict__ C0, void* __restrict__ C1, int ldc, int coloff,
    int tiles_n, int baseBlocks, int Kc, int Kb,
    const float* __restrict__ bias, int biasStride, int act,
    const unsigned char* __restrict__ mask, int outRowSub, int dirColOff){
  __shared__ alignas(16) __hip_bfloat16 smem[3][4096];   // 3 x (2048 A + 2048 B) = 24 KB
  int seg = (blockIdx.x >= (unsigned)baseBlocks) ? 1 : 0;
  int bid = blockIdx.x - seg*baseBlocks;
  int tn = bid % tiles_n;
  int tm = bid / tiles_n;
  int m0 = tm*64, n0 = tn*64;
  int dir = m0 >> 12;
  int kOff = seg*Kc;
  const __hip_bfloat16* Wd = W + (size_t)dir*wStride;
  void* Cout = seg ? C1 : C0;
  const float* biasp = (bias && seg==0) ? bias + dir*biasStride : nullptr;

  int tid = threadIdx.x;
  int wid = tid >> 6, lane = tid & 63;
  int r = lane & 15, kg = lane >> 4;

  int sr = lane >> 2;                 // 16 sub-rows per wave chunk
  int gs = (lane & 3) ^ (sr & 3);     // swizzled global 16B-slot
  int arow = m0 + wid*16 + sr;
  int pa = arow + padExtra*(arow >> 10);
  size_t aoff = (size_t)pa*lda + kOff + gs*8;
  int bcol = n0 + wid*16 + sr;
  size_t boff = (size_t)bcol*Kb + kOff + gs*8;

  int wr = wid >> 1, wc = wid & 1;
  int xs = (kg ^ (r & 3))*8;
  int afrag[2], bfrag[2];
  #pragma unroll
  for (int mi=0; mi<2; mi++) afrag[mi] = (wr*32 + mi*16 + r)*32 + xs;
  #pragma unroll
  for (int nj=0; nj<2; nj++) bfrag[nj] = 2048 + (wc*32 + nj*16 + r)*32 + xs;

  f32x4 acc[2][2];
  #pragma unroll
  for (int mi=0;mi<2;mi++)
    #pragma unroll
    for (int nj=0;nj<2;nj++) acc[mi][nj] = (f32x4){0.f,0.f,0.f,0.f};

  const int nt = Kc >> 5;
  auto stage = [&](int kt, int bufi){
    __hip_bfloat16* sb = &smem[bufi][0];
    int k0 = kt*32;
    gload16((const short*)A + aoff + k0, sb + wid*512);
    gload16((const short*)Wd + boff + k0, sb + 2048 + wid*512);
  };
  auto compute = [&](int bufi){
    const __hip_bfloat16* sb = &smem[bufi][0];
    short8 a[2], b[2];
    #pragma unroll
    for (int mi=0;mi<2;mi++) a[mi] = *(const short8*)&sb[afrag[mi]];
    #pragma unroll
    for (int nj=0;nj<2;nj++) b[nj] = *(const short8*)&sb[bfrag[nj]];
    #pragma unroll
    for (int mi=0;mi<2;mi++)
      #pragma unroll
      for (int nj=0;nj<2;nj++)
        acc[mi][nj] = __builtin_amdgcn_mfma_f32_16x16x32_bf16(a[mi], b[nj], acc[mi][nj], 0,0,0);
  };

  stage(0, 0);
  if (nt > 1) stage(1, 1);
  int bi = 0;
  for (int t=0; t<nt-1; t++){
    asm volatile("s_waitcnt vmcnt(2)" ::: "memory");
    __builtin_amdgcn_s_barrier();
    __builtin_amdgcn_sched_barrier(0);
    if (t+2 < nt){
      int nb2 = bi + 2; if (nb2 >= 3) nb2 -= 3;
      stage(t+2, nb2);
    }
    compute(bi);
    bi = (bi+1 == 3) ? 0 : bi+1;
  }
  asm volatile("s_waitcnt vmcnt(0)" ::: "memory");
  __builtin_amdgcn_s_barrier();
  __builtin_amdgcn_sched_barrier(0);
  compute(bi);

  #pragma unroll
  for (int mi=0;mi<2;mi++){
    #pragma unroll
    for (int nj=0;nj<2;nj++){
      #pragma unroll
      for (int reg=0; reg<4; reg++){
        int row = m0 + wr*32 + mi*16 + kg*4 + reg;
        int col = n0 + wc*32 + nj*16 + r;
        float v = acc[mi][nj][reg];
        if (biasp) v += biasp[col];
        if (act == 1) v = softplus_(v);
        int row_out = row - dir*outRowSub;
        if (mask && mask[row_out]) v = 0.f;
        size_t o = (size_t)row_out*ldc + coloff + dir*dirColOff + col;
        if (OUTBF) ((__hip_bfloat16*)Cout)[o] = __float2bfloat16(v);
        else       ((float*)Cout)[o] = v;
      }
    }
  }
}

// ---------------- mamba pieces (batched: rows 0..8191, dir = row>>12) ----------------

__global__ void k_dwconv(const float* __restrict__ xz,
                         const float* __restrict__ cw0, const float* __restrict__ cw1,
                         const float* __restrict__ cb0, const float* __restrict__ cb1,
                         float* __restrict__ u, __hip_bfloat16* __restrict__ ub){
  int i = blockIdx.x*256 + threadIdx.x;
  if (i >= BL2*DI) return;
  int d = i & (DI-1);
  int row = i >> 10;
  int dir = row >> 12;
  const float* cw = (dir ? cw1 : cw0) + d*4;
  const float* cb = dir ? cb1 : cb0;
  int l = row & 1023;
  int rb = row & ~1023;
  float acc = cb[d];
  #pragma unroll
  for (int k=0;k<4;k++){
    int ll = l - 3 + k;
    if (ll >= 0) acc += cw[k] * xz[(size_t)(rb + ll)*(2*DI) + d];
  }
  float s = acc * sigmoidf_(acc);
  u[i] = s;
  ub[i] = __float2bfloat16(s);
}

// -------- chunked selective scan, thread-per-d, both dirs in one dispatch --------
// block bits: [1:0]=dblk, [6:2]=c, [9:7]=b8 (0..7; dir = b8>>2)

__global__ __launch_bounds__(256) void k_scan_part(
    const float* __restrict__ Alog0, const float* __restrict__ Alog1,
    const float* __restrict__ dy, const float* __restrict__ u,
    const float* __restrict__ xdbc,
    float* __restrict__ Hp, float* __restrict__ Pp){
  __shared__ alignas(16) float Bsh[CLEN*16];
  int t = threadIdx.x;
  int dblk = blockIdx.x & 3;
  int c = (blockIdx.x >> 2) & (NCH-1);
  int b8 = blockIdx.x >> 7;
  const float* A_log = (b8 >> 2) ? Alog1 : Alog0;
  int d = dblk*256 + t;
  size_t blbase = (size_t)b8*LSEQ + (size_t)c*CLEN;
  if (t < CLEN*4){
    int l = t >> 2, q = t & 3;
    *(f32x4*)&Bsh[l*16 + q*4] = *(const f32x4*)&xdbc[(blbase+l)*64 + 32 + q*4];
  }
  float Af[16];
  #pragma unroll
  for (int n=0; n<16; n+=4){
    f32x4 a = *(const f32x4*)&A_log[(size_t)d*16 + n];
    Af[n]   = -__expf(a.x); Af[n+1] = -__expf(a.y);
    Af[n+2] = -__expf(a.z); Af[n+3] = -__expf(a.w);
  }
  float h[16], P[16];
  #pragma unroll
  for (int n=0;n<16;n++){ h[n]=0.f; P[n]=1.f; }
  __syncthreads();
  float dv = dy[blbase*DI + d];
  float uv = u[blbase*DI + d];
  for (int l=0; l<CLEN; l++){
    float dvn = 0.f, uvn = 0.f;
    if (l+1 < CLEN){
      dvn = dy[(blbase+l+1)*DI + d];
      uvn = u[(blbase+l+1)*DI + d];
    }
    float duv = dv*uv;
    #pragma unroll
    for (int n=0;n<16;n++){
      float dA = __expf(dv*Af[n]);
      h[n] = __fmaf_rn(dA, h[n], duv*Bsh[l*16+n]);
      P[n] *= dA;
    }
    dv = dvn; uv = uvn;
  }
  size_t pb = (((size_t)(b8*NCH + c))*DI + d)*16;
  #pragma unroll
  for (int n=0;n<16;n+=4){
    *(f32x4*)&Hp[pb+n] = (f32x4){h[n],h[n+1],h[n+2],h[n+3]};
    *(f32x4*)&Pp[pb+n] = (f32x4){P[n],P[n+1],P[n+2],P[n+3]};
  }
}

// combine: h_in[c+1] = P[c]*h_in[c] + H[c]; writes h_in back into Pp (in place)
__global__ void k_scan_comb(float* __restrict__ Hp, float* __restrict__ Pp){
  int i = blockIdx.x*256 + threadIdx.x;   // (row8k)*16 + n
  if (i >= BL2*NST) return;
  int n = i & 15, row = i >> 4;
  int b8 = row >> 10, d = row & 1023;
  float hin = 0.f;
  #pragma unroll
  for (int c=0;c<NCH;c++){
    size_t idx = (((size_t)(b8*NCH + c))*DI + d)*16 + n;
    float P = Pp[idx], H = Hp[idx];
    Pp[idx] = hin;
    hin = __fmaf_rn(P, hin, H);
  }
}

// final pass: recompute chunk states from h_in, emit y fused with ygate -> yb (bf16)
__global__ __launch_bounds__(256) void k_scan_fin(
    const float* __restrict__ Alog0, const float* __restrict__ Alog1,
    const float* __restrict__ dy, const float* __restrict__ u,
    const float* __restrict__ xdbc,
    const float* __restrict__ Hin, const float* __restrict__ xz,
    const float* __restrict__ Dp0, const float* __restrict__ Dp1,
    __hip_bfloat16* __restrict__ yb){
  __shared__ alignas(16) float BCsh[CLEN*32];
  int t = threadIdx.x;
  int dblk = blockIdx.x & 3;
  int c = (blockIdx.x >> 2) & (NCH-1);
  int b8 = blockIdx.x >> 7;
  int dirb = b8 >> 2;
  const float* A_log = dirb ? Alog1 : Alog0;
  const float* Dp = dirb ? Dp1 : Dp0;
  int d = dblk*256 + t;
  size_t blbase = (size_t)b8*LSEQ + (size_t)c*CLEN;
  {
    int l = t >> 3, q = t & 7;   // 256 threads cover 32 rows x 8 quads
    *(f32x4*)&BCsh[l*32 + q*4] = *(const f32x4*)&xdbc[(blbase+l)*64 + 32 + q*4];
  }
  float Af[16];
  #pragma unroll
  for (int n=0; n<16; n+=4){
    f32x4 a = *(const f32x4*)&A_log[(size_t)d*16 + n];
    Af[n]   = -__expf(a.x); Af[n+1] = -__expf(a.y);
    Af[n+2] = -__expf(a.z); Af[n+3] = -__expf(a.w);
  }
  size_t pb = (((size_t)(b8*NCH + c))*DI + d)*16;
  float h[16];
  #pragma unroll
  for (int n=0;n<16;n+=4){
    f32x4 hv = *(const f32x4*)&Hin[pb+n];
    h[n]=hv.x; h[n+1]=hv.y; h[n+2]=hv.z; h[n+3]=hv.w;
  }
  float Dd = Dp[d];
  __syncthreads();
  float dv = dy[blbase*DI + d];
  float uv = u[blbase*DI + d];
  float zv = xz[blbase*(2*DI) + DI + d];
  for (int l=0; l<CLEN; l++){
    float dvn = 0.f, uvn = 0.f, zvn = 0.f;
    if (l+1 < CLEN){
      dvn = dy[(blbase+l+1)*DI + d];
      uvn = u[(blbase+l+1)*DI + d];
      zvn = xz[(blbase+l+1)*(2*DI) + DI + d];
    }
    float duv = dv*uv;
    float y = 0.f;
    #pragma unroll
    for (int n=0;n<16;n++){
      float dA = __expf(dv*Af[n]);
      h[n] = __fmaf_rn(dA, h[n], duv*BCsh[l*32+n]);
      y = __fmaf_rn(h[n], BCsh[l*32+16+n], y);
    }
    float g = zv * sigmoidf_(zv);
    float out = __fmaf_rn(uv, Dd, y) * g;
    yb[(blbase+l)*DI + d] = __float2bfloat16(out);
    dv = dvn; uv = uvn; zv = zvn;
  }
}

// ---------------- host ----------------

extern "C" void kernel_launch(void* const* d_in, const int* in_sizes, int n_in,
                              void* d_out, int out_size, void* d_ws, size_t ws_size,
                              hipStream_t stream){
  (void)in_sizes; (void)n_in; (void)out_size; (void)ws_size;
  const int*   x     = (const int*)d_in[0];
  const unsigned char* m = (const unsigned char*)d_in[2];
  const float* emb   = (const float*)d_in[3];
  const float* convw = (const float*)d_in[4];
  const float* convb = (const float*)d_in[5];
  const float* lng   = (const float*)d_in[6];
  const float* lnb   = (const float*)d_in[7];
  const float* projw = (const float*)d_in[8];
  const float* projb = (const float*)d_in[9];

  char* ws = (char*)d_ws;
  size_t off = 0;
  auto alloc = [&](size_t bytes)->char*{
    char* p = ws + off; off += (bytes + 255) & ~((size_t)255); return p;
  };
  auto wt_conv = (__hip_bfloat16*)alloc((size_t)3*CCH*CCH*5*2);
  // mamba weights contiguous per type: [dir0 | dir1]
  auto w_in2  = (__hip_bfloat16*)alloc((size_t)2*2*DI*CCH*2);
  auto w_x2   = (__hip_bfloat16*)alloc((size_t)2*64*DI*2);
  auto w_dt2  = (__hip_bfloat16*)alloc((size_t)2*DI*DTR*2);
  auto w_out2 = (__hip_bfloat16*)alloc((size_t)2*CCH*DI*2);
  auto w_proj = (__hip_bfloat16*)alloc((size_t)CCH*1024*2);
  auto dtbias2= (float*)alloc((size_t)2*DI*4);
  auto xpad0  = (__hip_bfloat16*)alloc((size_t)BSZ*(LSEQ+4)*CCH*2);
  auto xpad1  = (__hip_bfloat16*)alloc((size_t)BSZ*(LSEQ+4)*CCH*2);
  auto scr    = (float*)alloc((size_t)BL2*NCH*NST*16/16*4*16/16);   // 16.78 MB: conv partial0 / scan Hp
  // (exact size: 8*NCH*DI*16 floats = 16.78 MB; expression above == that)
  auto h_cat  = (__hip_bfloat16*)alloc((size_t)BL2*CCH*2);          // [h_enc | h_rev]
  auto xz2    = (float*)alloc((size_t)BL2*2*DI*4);
  auto u2     = (float*)alloc((size_t)BL2*DI*4);
  auto ub2    = (__hip_bfloat16*)alloc((size_t)BL2*DI*2);
  auto xdbc2  = (float*)alloc((size_t)BL2*64*4);
  auto dtb2   = (unsigned short*)alloc((size_t)BL2*DTR*2);
  auto dy2    = (float*)alloc((size_t)BL2*DI*4);   // conv partial1 (first 8.4MB) in encoder; delta in mamba
  auto yb2    = (__hip_bfloat16*)alloc((size_t)BL2*DI*2);
  auto fob    = (__hip_bfloat16*)alloc((size_t)BL*DI*2);
  auto Pp     = (float*)alloc((size_t)8*NCH*DI*NST*4);

  float* Hp = scr;   // 16.78 MB, dead outside scan

  auto nb = [](size_t n){ return (unsigned)((n + 255)/256); };

  // --- weight prep ---
  k_prep_convw<<<dim3(nb((size_t)3*CCH*CCH*5)), dim3(256), 0, stream>>>(convw, wt_conv);
  {
    CastArgs ca;
    unsigned acc = 0;
    auto put = [&](int k, const void* s, void* d, unsigned n4){
      ca.e[k].s = (const float*)s; ca.e[k].d = (unsigned short*)d;
      ca.e[k].n4 = n4; ca.e[k].acc = acc; acc += n4;
    };
    for (int dir=0; dir<2; dir++){
      int base = 10 + 9*dir;
      put(dir*4+0, d_in[base+0], (unsigned short*)w_in2  + (size_t)dir*2*DI*CCH, (2*DI*CCH)/4);
      put(dir*4+1, d_in[base+3], (unsigned short*)w_x2   + (size_t)dir*64*DI,    (64*DI)/4);
      put(dir*4+2, d_in[base+4], (unsigned short*)w_dt2  + (size_t)dir*DI*DTR,   (DI*DTR)/4);
      put(dir*4+3, d_in[base+8], (unsigned short*)w_out2 + (size_t)dir*CCH*DI,   (CCH*DI)/4);
    }
    put(8, projw, w_proj, (CCH*1024)/4);
    ca.total4 = acc;
    k_cast_all<<<dim3(nb(acc)), dim3(256), 0, stream>>>(ca);
  }
  hipMemcpyAsync(dtbias2,      d_in[15], DI*sizeof(float), hipMemcpyDeviceToDevice, stream);
  hipMemcpyAsync(dtbias2 + DI, d_in[24], DI*sizeof(float), hipMemcpyDeviceToDevice, stream);

  auto gemm_big = [&](const void* A, int lda, int padE, const void* W, size_t wStride,
                  void* C0, void* C1, int ldc, int coloff,
                  int M, int N, int Kc, int Kb, int ksplit,
                  const float* bias, int biasStride, int act,
                  const unsigned char* msk, int outRowSub, int dirColOff, bool outbf){
    int tiles_n = N/64;
    int baseBlocks = (M/64)*tiles_n;
    int blocks = baseBlocks * (ksplit ? 2 : 1);
    if (outbf)
      k_gemm_big<true><<<dim3(blocks), dim3(256), 0, stream>>>((const __hip_bfloat16*)A, lda, padE,
          (const __hip_bfloat16*)W, wStride, C0, C1, ldc, coloff, tiles_n, baseBlocks,
          Kc, Kb, bias, biasStride, act, msk, outRowSub, dirColOff);
    else
      k_gemm_big<false><<<dim3(blocks), dim3(256), 0, stream>>>((const __hip_bfloat16*)A, lda, padE,
          (const __hip_bfloat16*)W, wStride, C0, C1, ldc, coloff, tiles_n, baseBlocks,
          Kc, Kb, bias, biasStride, act, msk, outRowSub, dirColOff);
  };

  // --- encoder: embed(+pad-zero) + 3x (conv-as-GEMM in-dispatch K-split -> LN(sum)) ---
  k_embed<<<dim3(nb((size_t)BSZ*(LSEQ+4)*CCH + BSZ*4*CCH)), dim3(256), 0, stream>>>(x, emb, xpad0, xpad1);

  __hip_bfloat16* xp_in = xpad0;
  __hip_bfloat16* xp_out = xpad1;
  __hip_bfloat16* h_rev = h_cat + (size_t)BL*CCH;
  for (int layer=0; layer<3; layer++){
    const __hip_bfloat16* wt = wt_conv + (size_t)layer*CCH*CCH*5;
    gemm_big(xp_in, CCH, 4, wt, 0, scr, dy2, CCH, 0, BL, CCH, 1280, 2560, 1,
             convb + layer*CCH, 0, 0, nullptr, 0, 0, false);
    bool last = (layer==2);
    k_ln<<<dim3(BL), dim3(256), 0, stream>>>(scr, dy2, lng + layer*CCH, lnb + layer*CCH, m,
        last ? nullptr : xp_out, last ? h_cat : nullptr, last ? h_rev : nullptr);
    __hip_bfloat16* t2 = xp_in; xp_in = xp_out; xp_out = t2;
  }

  // --- bidirectional mamba, both directions batched (rows 0..8191, dir = row>>12) ---
  const float* Alog0 = (const float*)d_in[16];
  const float* Alog1 = (const float*)d_in[25];
  const float* Dp0   = (const float*)d_in[17];
  const float* Dp1   = (const float*)d_in[26];

  gemm_big(h_cat, CCH, 0, w_in2, (size_t)2*DI*CCH, xz2, xz2, 2*DI, 0,
           BL2, 2*DI, CCH, CCH, 0, nullptr, 0, 0, nullptr, 0, 0, false);
  k_dwconv<<<dim3(nb((size_t)BL2*DI)), dim3(256), 0, stream>>>(xz2,
      (const float*)d_in[11], (const float*)d_in[20],
      (const float*)d_in[12], (const float*)d_in[21], u2, ub2);
  k_gemm_ksplit<<<dim3(BL2/64), dim3(256), 0, stream>>>(ub2, DI, w_x2, (size_t)64*DI, xdbc2, 64, DI, dtb2);
  gemm_big(dtb2, DTR, 0, w_dt2, (size_t)DI*DTR, dy2, dy2, DI, 0,
           BL2, DI, DTR, DTR, 0, dtbias2, DI, 1, nullptr, 0, 0, false);
  k_scan_part<<<dim3(1024), dim3(256), 0, stream>>>(Alog0, Alog1, dy2, u2, xdbc2, Hp, Pp);
  k_scan_comb<<<dim3(nb((size_t)BL2*NST)), dim3(256), 0, stream>>>(Hp, Pp);
  k_scan_fin<<<dim3(1024), dim3(256), 0, stream>>>(Alog0, Alog1, dy2, u2, xdbc2, Pp, xz2, Dp0, Dp1, yb2);
  gemm_big(yb2, DI, 0, w_out2, (size_t)CCH*DI, fob, fob, DI, 0,
           BL2, CCH, DI, DI, 0, nullptr, 0, 0, nullptr, BL, 512, true);

  // --- final projection + bias + mask -> d_out (f32) ---
  gemm_big(fob, DI, 0, w_proj, 0, d_out, d_out, CCH, 0,
           BL, CCH, DI, DI, 0, projb, 0, 0, m, 0, 0, false);
}

// Round 9
// 367.293 us; speedup vs baseline: 4.0516x; 1.0327x over previous
//
#include <hip/hip_runtime.h>
#include <hip/hip_bf16.h>

typedef __attribute__((ext_vector_type(8))) short short8;
typedef __attribute__((ext_vector_type(4))) float f32x4;
typedef __attribute__((ext_vector_type(4))) unsigned short ushort4_t;

#define BSZ 4
#define LSEQ 1024
#define CCH 512
#define BL (BSZ*LSEQ)   // 4096 rows
#define BL2 (2*BL)      // both directions batched: 8192 rows
#define DI 1024         // d_inner
#define NST 16
#define DTR 32
#define NCH 32          // scan chunks
#define CLEN 32         // chunk length (NCH*CLEN == LSEQ)

__device__ __forceinline__ float sigmoidf_(float x){ return 1.f/(1.f+__expf(-x)); }
__device__ __forceinline__ float softplus_(float x){ return x > 20.f ? x : log1pf(__expf(x)); }
__device__ __forceinline__ unsigned short f2bf_(float f){
  __hip_bfloat16 h = __float2bfloat16(f); return *(unsigned short*)&h;
}

typedef const __attribute__((address_space(1))) unsigned int* gas_t;
typedef __attribute__((address_space(3))) unsigned int* las_t;
__device__ __forceinline__ void gload16(const void* g, void* l){
  __builtin_amdgcn_global_load_lds((gas_t)g, (las_t)l, 16, 0, 0);
}

// ---------------- prep / elementwise kernels ----------------

// all 9 f32->bf16 weight casts in ONE launch (region table in kernarg)
struct CastEnt { const float* s; unsigned short* d; unsigned n4, acc; };
struct CastArgs { CastEnt e[9]; unsigned total4; };
__global__ void k_cast_all(CastArgs a){
  unsigned i = blockIdx.x*256 + threadIdx.x;
  if (i >= a.total4) return;
  #pragma unroll
  for (int k=0;k<9;k++){
    if (i < a.e[k].acc + a.e[k].n4){
      unsigned j = i - a.e[k].acc;
      float4 v = ((const float4*)a.e[k].s)[j];
      ushort4_t o = { f2bf_(v.x), f2bf_(v.y), f2bf_(v.z), f2bf_(v.w) };
      *(ushort4_t*)(a.e[k].d + (size_t)j*4) = o;
      return;
    }
  }
}

// conv_w [3][512][512][5] -> wt [3][512][2560], j = k*512 + ci  (matches contiguous patch)
__global__ void k_prep_convw(const float* __restrict__ cw, __hip_bfloat16* __restrict__ wt){
  int i = blockIdx.x*256 + threadIdx.x;
  const int total = 3*CCH*CCH*5;
  if (i >= total) return;
  int j = i % (CCH*5);
  int co = (i/(CCH*5)) % CCH;
  int layer = i/(CCH*5*CCH);
  int k = j >> 9, ci = j & 511;
  wt[i] = __float2bfloat16(cw[(((size_t)layer*CCH + co)*CCH + ci)*5 + k]);
}

// gather emb[x] into padded [B][L+4][C] bf16; tail range zeroes xpad1's 4 pad rows
__global__ void k_embed(const int* __restrict__ x, const float* __restrict__ emb,
                        __hip_bfloat16* __restrict__ xpad0, __hip_bfloat16* __restrict__ xpad1){
  int i = blockIdx.x*256 + threadIdx.x;
  const int total = BSZ*(LSEQ+4)*CCH;
  const int total2 = total + BSZ*4*CCH;
  if (i >= total2) return;
  if (i >= total){
    int j = i - total;
    int c = j & (CCH-1);
    int pr = (j >> 9) & 3;
    int b = j >> 11;
    int rr = (pr < 2) ? pr : (LSEQ+2) + (pr-2);
    xpad1[((size_t)b*(LSEQ+4) + rr)*CCH + c] = __float2bfloat16(0.f);
    return;
  }
  int c = i & (CCH-1);
  int r = (i >> 9) % (LSEQ+4);
  int b = i / ((LSEQ+4)*CCH);
  float v = 0.f;
  if (r >= 2 && r < LSEQ+2){
    int tok = x[b*LSEQ + (r-2)];
    v = emb[(size_t)tok*CCH + c];
  }
  xpad0[i] = __float2bfloat16(v);
}

// per-(b,l) channel LayerNorm over (in + in2) + scale/shift + LeakyReLU(0.2) + mask
__global__ __launch_bounds__(256) void k_ln(
    const float* __restrict__ in, const float* __restrict__ in2,
    const float* __restrict__ g, const float* __restrict__ bb,
    const unsigned char* __restrict__ mask,
    __hip_bfloat16* __restrict__ xpad_next,
    __hip_bfloat16* __restrict__ h_enc, __hip_bfloat16* __restrict__ h_rev){
  int row = blockIdx.x;                 // b*1024 + l
  int b = row >> 10, l = row & 1023;
  const float* xr = in + (size_t)row*CCH;
  const float* xr2 = in2 + (size_t)row*CCH;
  int t = threadIdx.x;
  float v0 = xr[t] + xr2[t], v1 = xr[t+256] + xr2[t+256];
  float s = v0+v1, s2 = v0*v0 + v1*v1;
  #pragma unroll
  for (int off=32; off>0; off>>=1){ s += __shfl_down(s,off); s2 += __shfl_down(s2,off); }
  __shared__ float ls[8];
  if ((t&63)==0){ ls[t>>6] = s; ls[(t>>6)+4] = s2; }
  __syncthreads();
  float S  = ls[0]+ls[1]+ls[2]+ls[3];
  float S2 = ls[4]+ls[5]+ls[6]+ls[7];
  float mu = S*(1.f/CCH);
  float var = S2*(1.f/CCH) - mu*mu;
  float rs = rsqrtf(var + 1e-5f);
  bool mk = mask[row] != 0;
  #pragma unroll
  for (int e=0; e<2; e++){
    int c = t + e*256;
    float v = e ? v1 : v0;
    float h = (v-mu)*rs*g[c] + bb[c];
    h = h > 0.f ? h : 0.2f*h;
    if (mk) h = 0.f;
    __hip_bfloat16 hb = __float2bfloat16(h);
    if (xpad_next) xpad_next[((size_t)b*(LSEQ+4) + (l+2))*CCH + c] = hb;
    if (h_enc) h_enc[(size_t)row*CCH + c] = hb;
    if (h_rev) h_rev[((size_t)(b<<10) + (1023-l))*CCH + c] = hb;
  }
}

// ---------------- K-split GEMM for skinny N=64 (x_proj), batched dirs ----------------
// 16 rows per block (512 blocks -> 2/CU); 4 waves each own a K/4 slice; LDS reduce.
__global__ __launch_bounds__(256) void k_gemm_ksplit(
    const __hip_bfloat16* __restrict__ A, int lda,
    const __hip_bfloat16* __restrict__ W, size_t wStride,
    float* __restrict__ Cout, int ldc, int K, unsigned short* __restrict__ dtb){
  __shared__ float red[4*1024];   // 16 KB: 4 waves x (16 rows x 64 cols)
  int m0 = blockIdx.x << 4;
  const __hip_bfloat16* Wd = W + (size_t)(m0 >> 12)*wStride;
  int tid = threadIdx.x;
  int w = tid >> 6, lane = tid & 63;
  int r = lane & 15, kg = lane >> 4;
  int Kw = K >> 2;
  int kbase = w*Kw;

  const short* Ap = (const short*)A + (size_t)(m0 + r)*lda + kbase + kg*8;
  const short* Wp[4];
  #pragma unroll
  for (int nj=0; nj<4; nj++)
    Wp[nj] = (const short*)Wd + (size_t)(nj*16 + r)*K + kbase + kg*8;

  f32x4 acc[4];
  #pragma unroll
  for (int nj=0;nj<4;nj++) acc[nj] = (f32x4){0.f,0.f,0.f,0.f};

  for (int kk=0; kk<Kw; kk+=32){
    short8 a = *(const short8*)(Ap + kk);
    #pragma unroll
    for (int nj=0;nj<4;nj++){
      short8 wv = *(const short8*)(Wp[nj] + kk);
      acc[nj] = __builtin_amdgcn_mfma_f32_16x16x32_bf16(a, wv, acc[nj], 0,0,0);
    }
  }
  #pragma unroll
  for (int nj=0;nj<4;nj++)
    #pragma unroll
    for (int reg=0; reg<4; reg++){
      int rowt = kg*4 + reg;
      int col  = nj*16 + r;
      red[w*1024 + rowt*64 + col] = acc[nj][reg];
    }
  __syncthreads();
  int e0 = tid*4;
  f32x4 s = *(const f32x4*)&red[e0];
  #pragma unroll
  for (int ww=1; ww<4; ww++){
    f32x4 p = *(const f32x4*)&red[ww*1024 + e0];
    s.x += p.x; s.y += p.y; s.z += p.z; s.w += p.w;
  }
  int rowt = e0 >> 6, col = e0 & 63;
  *(f32x4*)&Cout[(size_t)(m0+rowt)*ldc + col] = s;
  if (col < 32){
    ushort4_t o = { f2bf_(s.x), f2bf_(s.y), f2bf_(s.z), f2bf_(s.w) };
    *(ushort4_t*)&dtb[(size_t)(m0+rowt)*32 + col] = o;
  }
}

// ---------------- big staged GEMM: 64(M)x64(N) tile, BK=32, 4 waves ----------------
// 3-buffer LDS ring, counted vmcnt(2) + raw s_barrier. Supports:
//  - in-dispatch K-split: blocks >= baseBlocks compute K=[Kc,2Kc) into C1 (no bias)
//  - batched directions: dir = m0>>12 selects W (+wStride), bias (+biasStride),
//    output row - outRowSub and column + dirColOff.
template<bool OUTBF>
__global__ __launch_bounds__(256) void k_gemm_big(
    const __hip_bfloat16* __restrict__ A, int lda, int padExtra,
    const __hip_bfloat16* __restrict__ W, size_t wStride,
    void* __restrict__ C0, void* __restrict__ C1, int ldc, int coloff,
    int tiles_n, int baseBlocks, int Kc, int Kb,
    const float* __restrict__ bias, int biasStride, int act,
    const unsigned char* __restrict__ mask, int outRowSub, int dirColOff){
  __shared__ alignas(16) __hip_bfloat16 smem[3][4096];   // 3 x (2048 A + 2048 B) = 24 KB
  int seg = (blockIdx.x >= (unsigned)baseBlocks) ? 1 : 0;
  int bid = blockIdx.x - seg*baseBlocks;
  int tn = bid % tiles_n;
  int tm = bid / tiles_n;
  int m0 = tm*64, n0 = tn*64;
  int dir = m0 >> 12;
  int kOff = seg*Kc;
  const __hip_bfloat16* Wd = W + (size_t)dir*wStride;
  void* Cout = seg ? C1 : C0;
  const float* biasp = (bias && seg==0) ? bias + dir*biasStride : nullptr;

  int tid = threadIdx.x;
  int wid = tid >> 6, lane = tid & 63;
  int r = lane & 15, kg = lane >> 4;

  int sr = lane >> 2;                 // 16 sub-rows per wave chunk
  int gs = (lane & 3) ^ (sr & 3);     // swizzled global 16B-slot
  int arow = m0 + wid*16 + sr;
  int pa = arow + padExtra*(arow >> 10);
  size_t aoff = (size_t)pa*lda + kOff + gs*8;
  int bcol = n0 + wid*16 + sr;
  size_t boff = (size_t)bcol*Kb + kOff + gs*8;

  int wr = wid >> 1, wc = wid & 1;
  int xs = (kg ^ (r & 3))*8;
  int afrag[2], bfrag[2];
  #pragma unroll
  for (int mi=0; mi<2; mi++) afrag[mi] = (wr*32 + mi*16 + r)*32 + xs;
  #pragma unroll
  for (int nj=0; nj<2; nj++) bfrag[nj] = 2048 + (wc*32 + nj*16 + r)*32 + xs;

  f32x4 acc[2][2];
  #pragma unroll
  for (int mi=0;mi<2;mi++)
    #pragma unroll
    for (int nj=0;nj<2;nj++) acc[mi][nj] = (f32x4){0.f,0.f,0.f,0.f};

  const int nt = Kc >> 5;
  auto stage = [&](int kt, int bufi){
    __hip_bfloat16* sb = &smem[bufi][0];
    int k0 = kt*32;
    gload16((const short*)A + aoff + k0, sb + wid*512);
    gload16((const short*)Wd + boff + k0, sb + 2048 + wid*512);
  };
  auto compute = [&](int bufi){
    const __hip_bfloat16* sb = &smem[bufi][0];
    short8 a[2], b[2];
    #pragma unroll
    for (int mi=0;mi<2;mi++) a[mi] = *(const short8*)&sb[afrag[mi]];
    #pragma unroll
    for (int nj=0;nj<2;nj++) b[nj] = *(const short8*)&sb[bfrag[nj]];
    #pragma unroll
    for (int mi=0;mi<2;mi++)
      #pragma unroll
      for (int nj=0;nj<2;nj++)
        acc[mi][nj] = __builtin_amdgcn_mfma_f32_16x16x32_bf16(a[mi], b[nj], acc[mi][nj], 0,0,0);
  };

  stage(0, 0);
  if (nt > 1) stage(1, 1);
  int bi = 0;
  for (int t=0; t<nt-1; t++){
    asm volatile("s_waitcnt vmcnt(2)" ::: "memory");
    __builtin_amdgcn_s_barrier();
    __builtin_amdgcn_sched_barrier(0);
    if (t+2 < nt){
      int nb2 = bi + 2; if (nb2 >= 3) nb2 -= 3;
      stage(t+2, nb2);
    }
    compute(bi);
    bi = (bi+1 == 3) ? 0 : bi+1;
  }
  asm volatile("s_waitcnt vmcnt(0)" ::: "memory");
  __builtin_amdgcn_s_barrier();
  __builtin_amdgcn_sched_barrier(0);
  compute(bi);

  #pragma unroll
  for (int mi=0;mi<2;mi++){
    #pragma unroll
    for (int nj=0;nj<2;nj++){
      #pragma unroll
      for (int reg=0; reg<4; reg++){
        int row = m0 + wr*32 + mi*16 + kg*4 + reg;
        int col = n0 + wc*32 + nj*16 + r;
        float v = acc[mi][nj][reg];
        if (biasp) v += biasp[col];
        if (act == 1) v = softplus_(v);
        int row_out = row - dir*outRowSub;
        if (mask && mask[row_out]) v = 0.f;
        size_t o = (size_t)row_out*ldc + coloff + dir*dirColOff + col;
        if (OUTBF) ((__hip_bfloat16*)Cout)[o] = __float2bfloat16(v);
        else       ((float*)Cout)[o] = v;
      }
    }
  }
}

// ---------------- mamba pieces (batched: rows 0..8191, dir = row>>12) ----------------

// vectorized x4 channels per thread: all loads/stores are 16B
__global__ void k_dwconv(const float* __restrict__ xz,
                         const float* __restrict__ cw0, const float* __restrict__ cw1,
                         const float* __restrict__ cb0, const float* __restrict__ cb1,
                         float* __restrict__ u, __hip_bfloat16* __restrict__ ub){
  int i = blockIdx.x*256 + threadIdx.x;     // over BL2*DI/4
  if (i >= BL2*DI/4) return;
  int d4 = i & (DI/4 - 1);
  int d = d4 << 2;
  int row = i >> 8;
  int dir = row >> 12;
  const float* cw = (dir ? cw1 : cw0) + d*4;   // [d][4] x 4 consecutive d
  const float* cb = (dir ? cb1 : cb0) + d;
  int l = row & 1023;
  int rb = row & ~1023;
  f32x4 cwv[4];
  #pragma unroll
  for (int j=0;j<4;j++) cwv[j] = *(const f32x4*)&cw[j*4];
  f32x4 acc = *(const f32x4*)cb;
  #pragma unroll
  for (int k=0;k<4;k++){
    int ll = l - 3 + k;
    if (ll >= 0){
      f32x4 xv = *(const f32x4*)&xz[(size_t)(rb + ll)*(2*DI) + d];
      acc.x = __fmaf_rn(cwv[0][k], xv.x, acc.x);
      acc.y = __fmaf_rn(cwv[1][k], xv.y, acc.y);
      acc.z = __fmaf_rn(cwv[2][k], xv.z, acc.z);
      acc.w = __fmaf_rn(cwv[3][k], xv.w, acc.w);
    }
  }
  f32x4 s;
  s.x = acc.x * sigmoidf_(acc.x);
  s.y = acc.y * sigmoidf_(acc.y);
  s.z = acc.z * sigmoidf_(acc.z);
  s.w = acc.w * sigmoidf_(acc.w);
  *(f32x4*)&u[(size_t)i*4] = s;
  ushort4_t o = { f2bf_(s.x), f2bf_(s.y), f2bf_(s.z), f2bf_(s.w) };
  *(ushort4_t*)((unsigned short*)ub + (size_t)i*4) = o;
}

// -------- chunked selective scan, thread-per-d, both dirs in one dispatch --------
// block bits: [1:0]=dblk, [6:2]=c, [9:7]=b8 (0..7; dir = b8>>2)

__global__ __launch_bounds__(256) void k_scan_part(
    const float* __restrict__ Alog0, const float* __restrict__ Alog1,
    const float* __restrict__ dy, const float* __restrict__ u,
    const float* __restrict__ xdbc,
    float* __restrict__ Hp, float* __restrict__ Pp){
  __shared__ alignas(16) float Bsh[CLEN*16];
  int t = threadIdx.x;
  int dblk = blockIdx.x & 3;
  int c = (blockIdx.x >> 2) & (NCH-1);
  int b8 = blockIdx.x >> 7;
  const float* A_log = (b8 >> 2) ? Alog1 : Alog0;
  int d = dblk*256 + t;
  size_t blbase = (size_t)b8*LSEQ + (size_t)c*CLEN;
  if (t < CLEN*4){
    int l = t >> 2, q = t & 3;
    *(f32x4*)&Bsh[l*16 + q*4] = *(const f32x4*)&xdbc[(blbase+l)*64 + 32 + q*4];
  }
  float Af[16];
  #pragma unroll
  for (int n=0; n<16; n+=4){
    f32x4 a = *(const f32x4*)&A_log[(size_t)d*16 + n];
    Af[n]   = -__expf(a.x); Af[n+1] = -__expf(a.y);
    Af[n+2] = -__expf(a.z); Af[n+3] = -__expf(a.w);
  }
  float h[16], P[16];
  #pragma unroll
  for (int n=0;n<16;n++){ h[n]=0.f; P[n]=1.f; }
  __syncthreads();
  float dv = dy[blbase*DI + d];
  float uv = u[blbase*DI + d];
  for (int l=0; l<CLEN; l++){
    float dvn = 0.f, uvn = 0.f;
    if (l+1 < CLEN){
      dvn = dy[(blbase+l+1)*DI + d];
      uvn = u[(blbase+l+1)*DI + d];
    }
    float duv = dv*uv;
    #pragma unroll
    for (int n=0;n<16;n++){
      float dA = __expf(dv*Af[n]);
      h[n] = __fmaf_rn(dA, h[n], duv*Bsh[l*16+n]);
      P[n] *= dA;
    }
    dv = dvn; uv = uvn;
  }
  size_t pb = (((size_t)(b8*NCH + c))*DI + d)*16;
  #pragma unroll
  for (int n=0;n<16;n+=4){
    *(f32x4*)&Hp[pb+n] = (f32x4){h[n],h[n+1],h[n+2],h[n+3]};
    *(f32x4*)&Pp[pb+n] = (f32x4){P[n],P[n+1],P[n+2],P[n+3]};
  }
}

// combine: h_in[c+1] = P[c]*h_in[c] + H[c]; writes h_in back into Pp (in place)
__global__ void k_scan_comb(float* __restrict__ Hp, float* __restrict__ Pp){
  int i = blockIdx.x*256 + threadIdx.x;   // (row8k)*16 + n
  if (i >= BL2*NST) return;
  int n = i & 15, row = i >> 4;
  int b8 = row >> 10, d = row & 1023;
  float hin = 0.f;
  #pragma unroll
  for (int c=0;c<NCH;c++){
    size_t idx = (((size_t)(b8*NCH + c))*DI + d)*16 + n;
    float P = Pp[idx], H = Hp[idx];
    Pp[idx] = hin;
    hin = __fmaf_rn(P, hin, H);
  }
}

// final pass: recompute chunk states from h_in, emit y fused with ygate -> yb (bf16)
__global__ __launch_bounds__(256) void k_scan_fin(
    const float* __restrict__ Alog0, const float* __restrict__ Alog1,
    const float* __restrict__ dy, const float* __restrict__ u,
    const float* __restrict__ xdbc,
    const float* __restrict__ Hin, const float* __restrict__ xz,
    const float* __restrict__ Dp0, const float* __restrict__ Dp1,
    __hip_bfloat16* __restrict__ yb){
  __shared__ alignas(16) float BCsh[CLEN*32];
  int t = threadIdx.x;
  int dblk = blockIdx.x & 3;
  int c = (blockIdx.x >> 2) & (NCH-1);
  int b8 = blockIdx.x >> 7;
  int dirb = b8 >> 2;
  const float* A_log = dirb ? Alog1 : Alog0;
  const float* Dp = dirb ? Dp1 : Dp0;
  int d = dblk*256 + t;
  size_t blbase = (size_t)b8*LSEQ + (size_t)c*CLEN;
  {
    int l = t >> 3, q = t & 7;   // 256 threads cover 32 rows x 8 quads
    *(f32x4*)&BCsh[l*32 + q*4] = *(const f32x4*)&xdbc[(blbase+l)*64 + 32 + q*4];
  }
  float Af[16];
  #pragma unroll
  for (int n=0; n<16; n+=4){
    f32x4 a = *(const f32x4*)&A_log[(size_t)d*16 + n];
    Af[n]   = -__expf(a.x); Af[n+1] = -__expf(a.y);
    Af[n+2] = -__expf(a.z); Af[n+3] = -__expf(a.w);
  }
  size_t pb = (((size_t)(b8*NCH + c))*DI + d)*16;
  float h[16];
  #pragma unroll
  for (int n=0;n<16;n+=4){
    f32x4 hv = *(const f32x4*)&Hin[pb+n];
    h[n]=hv.x; h[n+1]=hv.y; h[n+2]=hv.z; h[n+3]=hv.w;
  }
  float Dd = Dp[d];
  __syncthreads();
  float dv = dy[blbase*DI + d];
  float uv = u[blbase*DI + d];
  float zv = xz[blbase*(2*DI) + DI + d];
  for (int l=0; l<CLEN; l++){
    float dvn = 0.f, uvn = 0.f, zvn = 0.f;
    if (l+1 < CLEN){
      dvn = dy[(blbase+l+1)*DI + d];
      uvn = u[(blbase+l+1)*DI + d];
      zvn = xz[(blbase+l+1)*(2*DI) + DI + d];
    }
    float duv = dv*uv;
    float y = 0.f;
    #pragma unroll
    for (int n=0;n<16;n++){
      float dA = __expf(dv*Af[n]);
      h[n] = __fmaf_rn(dA, h[n], duv*BCsh[l*32+n]);
      y = __fmaf_rn(h[n], BCsh[l*32+16+n], y);
    }
    float g = zv * sigmoidf_(zv);
    float out = __fmaf_rn(uv, Dd, y) * g;
    yb[(blbase+l)*DI + d] = __float2bfloat16(out);
    dv = dvn; uv = uvn; zv = zvn;
  }
}

// ---------------- host ----------------

extern "C" void kernel_launch(void* const* d_in, const int* in_sizes, int n_in,
                              void* d_out, int out_size, void* d_ws, size_t ws_size,
                              hipStream_t stream){
  (void)in_sizes; (void)n_in; (void)out_size; (void)ws_size;
  const int*   x     = (const int*)d_in[0];
  const unsigned char* m = (const unsigned char*)d_in[2];
  const float* emb   = (const float*)d_in[3];
  const float* convw = (const float*)d_in[4];
  const float* convb = (const float*)d_in[5];
  const float* lng   = (const float*)d_in[6];
  const float* lnb   = (const float*)d_in[7];
  const float* projw = (const float*)d_in[8];
  const float* projb = (const float*)d_in[9];

  char* ws = (char*)d_ws;
  size_t off = 0;
  auto alloc = [&](size_t bytes)->char*{
    char* p = ws + off; off += (bytes + 255) & ~((size_t)255); return p;
  };
  auto wt_conv = (__hip_bfloat16*)alloc((size_t)3*CCH*CCH*5*2);
  // mamba weights contiguous per type: [dir0 | dir1]
  auto w_in2  = (__hip_bfloat16*)alloc((size_t)2*2*DI*CCH*2);
  auto w_x2   = (__hip_bfloat16*)alloc((size_t)2*64*DI*2);
  auto w_dt2  = (__hip_bfloat16*)alloc((size_t)2*DI*DTR*2);
  auto w_out2 = (__hip_bfloat16*)alloc((size_t)2*CCH*DI*2);
  auto w_proj = (__hip_bfloat16*)alloc((size_t)CCH*1024*2);
  auto dtbias2= (float*)alloc((size_t)2*DI*4);
  auto xpad0  = (__hip_bfloat16*)alloc((size_t)BSZ*(LSEQ+4)*CCH*2);
  auto xpad1  = (__hip_bfloat16*)alloc((size_t)BSZ*(LSEQ+4)*CCH*2);
  auto scr    = (float*)alloc((size_t)8*NCH*DI*NST*4);   // 16.78 MB: conv partial0 / scan Hp
  auto h_cat  = (__hip_bfloat16*)alloc((size_t)BL2*CCH*2);          // [h_enc | h_rev]
  auto xz2    = (float*)alloc((size_t)BL2*2*DI*4);
  auto u2     = (float*)alloc((size_t)BL2*DI*4);
  auto ub2    = (__hip_bfloat16*)alloc((size_t)BL2*DI*2);
  auto xdbc2  = (float*)alloc((size_t)BL2*64*4);
  auto dtb2   = (unsigned short*)alloc((size_t)BL2*DTR*2);
  auto dy2    = (float*)alloc((size_t)BL2*DI*4);   // conv partial1 (first 8.4MB) in encoder; delta in mamba
  auto yb2    = (__hip_bfloat16*)alloc((size_t)BL2*DI*2);
  auto fob    = (__hip_bfloat16*)alloc((size_t)BL*DI*2);
  auto Pp     = (float*)alloc((size_t)8*NCH*DI*NST*4);

  float* Hp = scr;   // 16.78 MB, dead outside scan

  auto nb = [](size_t n){ return (unsigned)((n + 255)/256); };

  // --- weight prep ---
  k_prep_convw<<<dim3(nb((size_t)3*CCH*CCH*5)), dim3(256), 0, stream>>>(convw, wt_conv);
  {
    CastArgs ca;
    unsigned acc = 0;
    auto put = [&](int k, const void* s, void* d, unsigned n4){
      ca.e[k].s = (const float*)s; ca.e[k].d = (unsigned short*)d;
      ca.e[k].n4 = n4; ca.e[k].acc = acc; acc += n4;
    };
    for (int dir=0; dir<2; dir++){
      int base = 10 + 9*dir;
      put(dir*4+0, d_in[base+0], (unsigned short*)w_in2  + (size_t)dir*2*DI*CCH, (2*DI*CCH)/4);
      put(dir*4+1, d_in[base+3], (unsigned short*)w_x2   + (size_t)dir*64*DI,    (64*DI)/4);
      put(dir*4+2, d_in[base+4], (unsigned short*)w_dt2  + (size_t)dir*DI*DTR,   (DI*DTR)/4);
      put(dir*4+3, d_in[base+8], (unsigned short*)w_out2 + (size_t)dir*CCH*DI,   (CCH*DI)/4);
    }
    put(8, projw, w_proj, (CCH*1024)/4);
    ca.total4 = acc;
    k_cast_all<<<dim3(nb(acc)), dim3(256), 0, stream>>>(ca);
  }
  hipMemcpyAsync(dtbias2,      d_in[15], DI*sizeof(float), hipMemcpyDeviceToDevice, stream);
  hipMemcpyAsync(dtbias2 + DI, d_in[24], DI*sizeof(float), hipMemcpyDeviceToDevice, stream);

  auto gemm_big = [&](const void* A, int lda, int padE, const void* W, size_t wStride,
                  void* C0, void* C1, int ldc, int coloff,
                  int M, int N, int Kc, int Kb, int ksplit,
                  const float* bias, int biasStride, int act,
                  const unsigned char* msk, int outRowSub, int dirColOff, bool outbf){
    int tiles_n = N/64;
    int baseBlocks = (M/64)*tiles_n;
    int blocks = baseBlocks * (ksplit ? 2 : 1);
    if (outbf)
      k_gemm_big<true><<<dim3(blocks), dim3(256), 0, stream>>>((const __hip_bfloat16*)A, lda, padE,
          (const __hip_bfloat16*)W, wStride, C0, C1, ldc, coloff, tiles_n, baseBlocks,
          Kc, Kb, bias, biasStride, act, msk, outRowSub, dirColOff);
    else
      k_gemm_big<false><<<dim3(blocks), dim3(256), 0, stream>>>((const __hip_bfloat16*)A, lda, padE,
          (const __hip_bfloat16*)W, wStride, C0, C1, ldc, coloff, tiles_n, baseBlocks,
          Kc, Kb, bias, biasStride, act, msk, outRowSub, dirColOff);
  };

  // --- encoder: embed(+pad-zero) + 3x (conv-as-GEMM in-dispatch K-split -> LN(sum)) ---
  k_embed<<<dim3(nb((size_t)BSZ*(LSEQ+4)*CCH + BSZ*4*CCH)), dim3(256), 0, stream>>>(x, emb, xpad0, xpad1);

  __hip_bfloat16* xp_in = xpad0;
  __hip_bfloat16* xp_out = xpad1;
  __hip_bfloat16* h_rev = h_cat + (size_t)BL*CCH;
  for (int layer=0; layer<3; layer++){
    const __hip_bfloat16* wt = wt_conv + (size_t)layer*CCH*CCH*5;
    gemm_big(xp_in, CCH, 4, wt, 0, scr, dy2, CCH, 0, BL, CCH, 1280, 2560, 1,
             convb + layer*CCH, 0, 0, nullptr, 0, 0, false);
    bool last = (layer==2);
    k_ln<<<dim3(BL), dim3(256), 0, stream>>>(scr, dy2, lng + layer*CCH, lnb + layer*CCH, m,
        last ? nullptr : xp_out, last ? h_cat : nullptr, last ? h_rev : nullptr);
    __hip_bfloat16* t2 = xp_in; xp_in = xp_out; xp_out = t2;
  }

  // --- bidirectional mamba, both directions batched (rows 0..8191, dir = row>>12) ---
  const float* Alog0 = (const float*)d_in[16];
  const float* Alog1 = (const float*)d_in[25];
  const float* Dp0   = (const float*)d_in[17];
  const float* Dp1   = (const float*)d_in[26];

  gemm_big(h_cat, CCH, 0, w_in2, (size_t)2*DI*CCH, xz2, xz2, 2*DI, 0,
           BL2, 2*DI, CCH, CCH, 0, nullptr, 0, 0, nullptr, 0, 0, false);
  k_dwconv<<<dim3(nb((size_t)BL2*DI/4)), dim3(256), 0, stream>>>(xz2,
      (const float*)d_in[11], (const float*)d_in[20],
      (const float*)d_in[12], (const float*)d_in[21], u2, ub2);
  k_gemm_ksplit<<<dim3(BL2/16), dim3(256), 0, stream>>>(ub2, DI, w_x2, (size_t)64*DI, xdbc2, 64, DI, dtb2);
  gemm_big(dtb2, DTR, 0, w_dt2, (size_t)DI*DTR, dy2, dy2, DI, 0,
           BL2, DI, DTR, DTR, 0, dtbias2, DI, 1, nullptr, 0, 0, false);
  k_scan_part<<<dim3(1024), dim3(256), 0, stream>>>(Alog0, Alog1, dy2, u2, xdbc2, Hp, Pp);
  k_scan_comb<<<dim3(nb((size_t)BL2*NST)), dim3(256), 0, stream>>>(Hp, Pp);
  k_scan_fin<<<dim3(1024), dim3(256), 0, stream>>>(Alog0, Alog1, dy2, u2, xdbc2, Pp, xz2, Dp0, Dp1, yb2);
  gemm_big(yb2, DI, 0, w_out2, (size_t)CCH*DI, fob, fob, DI, 0,
           BL2, CCH, DI, DI, 0, nullptr, 0, 0, nullptr, BL, 512, true);

  // --- final projection + bias + mask -> d_out (f32) ---
  gemm_big(fob, DI, 0, w_proj, 0, d_out, d_out, CCH, 0,
           BL, CCH, DI, DI, 0, projb, 0, 0, m, 0, 0, false);
}